// Round 4
// baseline (793.204 us; speedup 1.0000x reference)
//
#include <hip/hip_runtime.h>
#include <cmath>

// ---------------------------------------------------------------------------
// InvariantSlotAttention forward. R19 = R16 (R1 champion, 486us) + last-block
// fusion: the 64 blocks of each batch b count down via device-scope atomics;
// the last block runs the GRU (mode 0) or the final heads (mode 1) in-kernel.
// Eliminates 3x k_gru + 1x k_final launches. Cross-block reads of upd/accF
// use atomicAdd(p, 0.f) (device-scope) to avoid per-XCD L2 staleness.
// R18's cooperative launch reverted (harness rejected it -> output never ran).
// B=16, S=7, E=HID=64, D=4096, N_ITER=3, TSOFT=0.125
// ---------------------------------------------------------------------------

#define RLOW_F 0.1f
#define RHIGH_F 0.22360679774997896f
#define W0CONST 1.00004096f      /* sum_d wts = 1 + 4096e-8 exactly */
#define SR2 704.3386243f         /* sum_d (gx^2+gy^2) */

typedef __attribute__((ext_vector_type(8))) __bf16 bf16x8;
typedef __attribute__((ext_vector_type(4))) float f32x4;

__device__ __forceinline__ float wsum64(float v){
  #pragma unroll
  for (int off = 32; off > 0; off >>= 1) v += __shfl_xor(v, off, 64);
  return v;
}
__device__ __forceinline__ float rdlane(float v, int l){
  return __int_as_float(__builtin_amdgcn_readlane(__float_as_int(v), l));
}
__device__ __forceinline__ unsigned short bf16bits(float v){
  __bf16 h = (__bf16)v;
  return *reinterpret_cast<unsigned short*>(&h);
}
__device__ __forceinline__ float aread(float* p){
  return atomicAdd(p, 0.f);      // device-scope coherent read
}

// ---- phase prep core: one full wave (lanes 0..63), e = lane ---------------
__device__ __forceinline__ void pp_core(int row, int e, float qv,
    float px, float py, float sc,
    const float* __restrict__ qg_, const float* __restrict__ qb_,
    const float* __restrict__ dw, const float* __restrict__ db,
    const float* __restrict__ mlp2w, const float* __restrict__ mlp2b,
    float* __restrict__ absc, float* __restrict__ w2qc){
  float m = wsum64(qv) * (1.f/64.f);
  float d = qv - m;
  float var = wsum64(d*d) * (1.f/64.f);
  float qlnv = d * (1.0f/sqrtf(var + 1e-5f)) * qg_[e] + qb_[e];
  float A  = dw[e]      / sc;
  float Bv = dw[64 + e] / sc;
  absc[row*192 + e]       = A;
  absc[row*192 + 64 + e]  = Bv;
  absc[row*192 + 128 + e] = db[e] - px*A - py*Bv;
  float acc = 0.f;
  const float* wrow = mlp2w + e*64;
  for (int j = 0; j < 64; j++) acc = fmaf(wrow[j], rdlane(qlnv, j), acc);
  w2qc[row*68 + e] = acc;
  float c2 = wsum64(mlp2b[e] * qlnv);
  if (e == 0) w2qc[row*68 + 64] = c2;
}

// ---------------- bundled: weight packing + phase-0 prep -------------------
__global__ void k_packall(const float* __restrict__ mlp1_w, const float* __restrict__ toK_w,
                          const float* __restrict__ toV_w, const float* __restrict__ conv1_w,
                          const float* __restrict__ conv2_w,
                          unsigned short* __restrict__ w1pack, unsigned short* __restrict__ kpack,
                          unsigned short* __restrict__ vpack, unsigned short* __restrict__ wp1,
                          unsigned short* __restrict__ wp2,
                          const float* __restrict__ noise, const float* __restrict__ prand,
                          const float* __restrict__ mu, const float* __restrict__ logsig,
                          const float* __restrict__ qg_, const float* __restrict__ qb_,
                          const float* __restrict__ dw, const float* __restrict__ db,
                          const float* __restrict__ mlp2w, const float* __restrict__ mlp2b,
                          float* __restrict__ queries, float* __restrict__ ps,
                          float* __restrict__ absc, float* __restrict__ w2qc,
                          float* __restrict__ accF, float* __restrict__ upd,
                          unsigned int* __restrict__ cnt){
  int bi = blockIdx.x; int t = threadIdx.x;
  if (bi < 48){
    const float* src = (bi < 16) ? mlp1_w : ((bi < 32) ? toK_w : toV_w);
    unsigned short* dst = (bi < 16) ? w1pack : ((bi < 32) ? kpack : vpack);
    int idx = (bi & 15)*256 + t;
    int jj = idx & 7;
    int lane = (idx >> 3) & 63;
    int frag = idx >> 9;
    int ks = frag >> 2, nt = frag & 3;
    int q = lane >> 4, cr = lane & 15;
    int k = ks*32 + q*8 + jj;
    int n = nt*16 + cr;
    dst[idx] = bf16bits(src[k*64 + n]);
  } else if (bi < 848){
    int rb = bi - 48;
    const float* src = (rb < 400) ? conv1_w : conv2_w;
    unsigned short* dst = (rb < 400) ? wp1 : wp2;
    int idx = (rb % 400)*256 + t;
    int j = idx & 7;
    int l = (idx >> 3) & 63;
    int frag = idx >> 9;
    int nt = frag & 3;
    int ks = (frag >> 2) % 10;
    int dy = frag / 40;
    int q = l >> 4, cr = l & 15;
    int k = ks*32 + q*8 + j;
    int kx = k >> 6, ch = k & 63;
    int n = nt*16 + cr;
    dst[idx] = bf16bits(src[((n*64 + ch)*5 + dy)*5 + kx]);
  } else {
    int row = bi - 848;           // 112 rows
    if (bi == 848 && t >= 64 && t < 80) cnt[t - 64] = 0u;
    if (t >= 64) return;
    int e = t;
    int s = row % 7;
    float qv = mu[e] + expf(logsig[e]) * noise[row*64 + e];
    queries[row*64 + e] = qv;
    upd[row*128 + e] = 0.f;
    upd[row*128 + 64 + e] = 0.f;
    if (e < 4) accF[row*4 + e] = 0.f;
    float pv = 0.f;
    if (e < 3){
      float pr = prand[row*3 + e];
      if (s < 2)       pv = pr - 0.5f;
      else if (s == 6) pv = (RLOW_F - RHIGH_F)*pr + RHIGH_F;
      else             pv = pr;
      ps[row*3 + e] = pv;
    }
    float px = rdlane(pv, 0), py = rdlane(pv, 1), sc = rdlane(pv, 2);
    pp_core(row, e, qv, px, py, sc, qg_, qb_, dw, db, mlp2w, mlp2b, absc, w2qc);
  }
}

// ---------------- conv0: 1->64 channels, 5x5 same, relu, NHWC bf16 out -----
__global__ __launch_bounds__(256) void k_conv0(const float* __restrict__ in,
                        const float* __restrict__ w, const float* __restrict__ bias,
                        unsigned short* __restrict__ out){
  int bi = blockIdx.x; int b = bi >> 6; int y = bi & 63;   // 1024 blocks
  int t = threadIdx.x; int lane = t & 63; int xg = t >> 6;
  __shared__ float s_in[5*68];
  __shared__ float s_w[64*25];
  __shared__ float s_out[64*65];
  for (int i = t; i < 1600; i += 256) s_w[i] = w[i];
  for (int i = t; i < 340; i += 256){
    int r = i / 68, cx = i % 68;
    int yy = y + r - 2, gx = cx - 2;
    float v = 0.f;
    if (yy >= 0 && yy < 64 && gx >= 0 && gx < 64) v = in[(b*64 + yy)*64 + gx];
    s_in[r*68 + cx] = v;
  }
  __syncthreads();
  int o = lane;
  float bvv = bias[o];
  float acc[16];
  #pragma unroll
  for (int k = 0; k < 16; k++) acc[k] = bvv;
  #pragma unroll
  for (int ky = 0; ky < 5; ky++){
    float rv[20];
    const float4* p = reinterpret_cast<const float4*>(&s_in[ky*68 + xg*16]);
    #pragma unroll
    for (int q = 0; q < 5; q++){ float4 f = p[q]; rv[q*4]=f.x; rv[q*4+1]=f.y; rv[q*4+2]=f.z; rv[q*4+3]=f.w; }
    #pragma unroll
    for (int kx = 0; kx < 5; kx++){
      float wv = s_w[o*25 + ky*5 + kx];
      #pragma unroll
      for (int k = 0; k < 16; k++) acc[k] = fmaf(rv[k+kx], wv, acc[k]);
    }
  }
  #pragma unroll
  for (int k = 0; k < 16; k++) s_out[o*65 + xg*16 + k] = fmaxf(acc[k], 0.f);
  __syncthreads();
  for (int i = t; i < 4096; i += 256){
    int px = i >> 6, ch = i & 63;
    out[((size_t)(b*64 + y)*64 + px)*64 + ch] = bf16bits(s_out[ch*65 + px]);
  }
}

// ---------------- conv1/conv2 bf16 MFMA implicit GEMM (512 blocks) ---------
__global__ __launch_bounds__(256) void k_convm(const unsigned short* __restrict__ in_bf,
                        const unsigned short* __restrict__ wpack,
                        const float* __restrict__ bias,
                        const float* __restrict__ lng, const float* __restrict__ lnb,
                        unsigned short* __restrict__ out_bf, int mode){
  int bi = blockIdx.x;                  // 512 = 16 b * 16 yg * 2 xh
  int b = bi >> 5; int yg = (bi >> 1) & 15; int xh = bi & 1;
  int t = threadIdx.x; int wv = t >> 6; int l = t & 63;
  int q = l >> 4, cr = l & 15;
  int yr = wv >> 1, ph = wv & 1;
  int p0 = ph*16;

  __shared__ char lds[8*36*144];

  for (int ri = 0; ri < 8; ri++){
    int yy = yg*4 + ri - 2;
    bool rok = (yy >= 0 && yy < 64);
    const uint4* src = reinterpret_cast<const uint4*>(in_bf + (size_t)(b*64 + yy)*64*64);
    for (int i = t; i < 288; i += 256){
      int px = i >> 3, c8 = i & 7;
      uint4 v = {0u,0u,0u,0u};
      int gx = xh*32 + px - 2;
      if (rok && gx >= 0 && gx < 64) v = src[gx*8 + c8];
      *reinterpret_cast<uint4*>(&lds[ri*5184 + px*144 + c8*16]) = v;
    }
  }
  __syncthreads();

  f32x4 acc[2][4];
  #pragma unroll
  for (int r = 0; r < 2; r++)
    #pragma unroll
    for (int nt = 0; nt < 4; nt++) acc[r][nt] = (f32x4){0.f,0.f,0.f,0.f};

  const bf16x8* wp = reinterpret_cast<const bf16x8*>(wpack);
  for (int dy = 0; dy < 5; dy++){
    for (int ks = 0; ks < 10; ks++){
      bf16x8 Bf[4];
      int fbase = (dy*10 + ks)*4;
      #pragma unroll
      for (int nt = 0; nt < 4; nt++) Bf[nt] = wp[(fbase + nt)*64 + l];
      int aoff = (p0 + cr + (ks >> 1))*144 + (ks & 1)*64 + q*16;
      #pragma unroll
      for (int r = 0; r < 2; r++){
        int ri = yr*2 + r + dy;
        bf16x8 a = *reinterpret_cast<const bf16x8*>(&lds[ri*5184 + aoff]);
        #pragma unroll
        for (int nt = 0; nt < 4; nt++)
          acc[r][nt] = __builtin_amdgcn_mfma_f32_16x16x32_bf16(a, Bf[nt], acc[r][nt], 0, 0, 0);
      }
    }
  }

  float bvv[4];
  #pragma unroll
  for (int nt = 0; nt < 4; nt++) bvv[nt] = bias[nt*16 + cr];

  if (mode == 0){
    #pragma unroll
    for (int r = 0; r < 2; r++){
      int y = yg*4 + yr*2 + r;
      #pragma unroll
      for (int reg = 0; reg < 4; reg++){
        int p = xh*32 + p0 + q*4 + reg;
        size_t base = ((size_t)(b*64 + y)*64 + p)*64;
        #pragma unroll
        for (int nt = 0; nt < 4; nt++)
          out_bf[base + nt*16 + cr] = bf16bits(fmaxf(acc[r][nt][reg] + bvv[nt], 0.f));
      }
    }
  } else {
    float gv[4], bb[4];
    #pragma unroll
    for (int nt = 0; nt < 4; nt++){ gv[nt] = lng[nt*16 + cr]; bb[nt] = lnb[nt*16 + cr]; }
    #pragma unroll
    for (int r = 0; r < 2; r++){
      int y = yg*4 + yr*2 + r;
      #pragma unroll
      for (int reg = 0; reg < 4; reg++){
        int p = xh*32 + p0 + q*4 + reg;
        float v[4]; float s1 = 0.f, s2 = 0.f;
        #pragma unroll
        for (int nt = 0; nt < 4; nt++){
          v[nt] = fmaxf(acc[r][nt][reg] + bvv[nt], 0.f);
          s1 += v[nt]; s2 += v[nt]*v[nt];
        }
        #pragma unroll
        for (int m = 1; m < 16; m <<= 1){ s1 += __shfl_xor(s1, m, 64); s2 += __shfl_xor(s2, m, 64); }
        float mean = s1 * (1.f/64.f);
        float var  = s2 * (1.f/64.f) - mean*mean;
        float rstd = 1.0f/sqrtf(var + 1e-5f);
        size_t base = ((size_t)b*4096 + y*64 + p)*64;
        #pragma unroll
        for (int nt = 0; nt < 4; nt++)
          out_bf[base + nt*16 + cr] = bf16bits((v[nt] - mean)*rstd*gv[nt] + bb[nt]);
      }
    }
  }
}

// ---------------- K/V projection: enc(bf16) @ toK_w, toV_w -> bf16 ---------
__global__ __launch_bounds__(256) void k_projm(const unsigned short* __restrict__ enc,
                       const unsigned short* __restrict__ kpack, const float* __restrict__ bk,
                       const unsigned short* __restrict__ vpack, const float* __restrict__ bvp,
                       unsigned short* __restrict__ K, unsigned short* __restrict__ V){
  int bi = blockIdx.x; int b = bi >> 6; int tile = bi & 63;  // 1024 blocks
  int t = threadIdx.x; int wv = t >> 6; int l = t & 63;
  int q = l >> 4, cr = l & 15;
  int d0 = tile*64 + wv*16;

  const bf16x8* kp = reinterpret_cast<const bf16x8*>(kpack);
  const bf16x8* vp = reinterpret_cast<const bf16x8*>(vpack);
  bf16x8 KB[8], VB[8];
  #pragma unroll
  for (int f = 0; f < 8; f++){ KB[f] = kp[f*64 + l]; VB[f] = vp[f*64 + l]; }

  const unsigned short* er = enc + (size_t)(b*4096 + d0 + cr)*64;
  bf16x8 a0 = *reinterpret_cast<const bf16x8*>(er + q*8);
  bf16x8 a1 = *reinterpret_cast<const bf16x8*>(er + 32 + q*8);

  f32x4 zero = {0.f,0.f,0.f,0.f};
  f32x4 aK[4], aV[4];
  #pragma unroll
  for (int nt = 0; nt < 4; nt++){
    aK[nt] = __builtin_amdgcn_mfma_f32_16x16x32_bf16(a0, KB[nt],     zero,   0, 0, 0);
    aK[nt] = __builtin_amdgcn_mfma_f32_16x16x32_bf16(a1, KB[4 + nt], aK[nt], 0, 0, 0);
    aV[nt] = __builtin_amdgcn_mfma_f32_16x16x32_bf16(a0, VB[nt],     zero,   0, 0, 0);
    aV[nt] = __builtin_amdgcn_mfma_f32_16x16x32_bf16(a1, VB[4 + nt], aV[nt], 0, 0, 0);
  }
  #pragma unroll
  for (int nt = 0; nt < 4; nt++){
    float bkv = bk[nt*16 + cr], bvv = bvp[nt*16 + cr];
    #pragma unroll
    for (int reg = 0; reg < 4; reg++){
      size_t base = ((size_t)b*4096 + d0 + q*4 + reg)*64 + nt*16 + cr;
      K[base] = bf16bits(aK[nt][reg] + bkv);
      V[base] = bf16bits(aV[nt][reg] + bvv);
    }
  }
}

// ---------------- fused attention + last-block GRU / final heads -----------
// mode 0 (iters 0-2): K logits + softmax + frames + V reduce; last block per
//   b (via cnt) runs the GRU for its 7 slots and preps the next phase.
// mode 1 (iter 3): K logits + softmax(att->out) + frames; last block per b
//   computes the final heads (slot_feat, alpha, queries copy).
__global__ __launch_bounds__(256) void k_attn(const unsigned short* __restrict__ encK,
     const unsigned short* __restrict__ encV,
     const unsigned short* __restrict__ w1pack, const float* __restrict__ mlp1b,
     float* __restrict__ absc, const float* __restrict__ qg_,
     const float* __restrict__ qb_, float* __restrict__ w2qc,
     float* __restrict__ attOut, float* __restrict__ accF,
     float* __restrict__ upd, int mode, unsigned int* __restrict__ cnt,
     float* __restrict__ queries, float* __restrict__ ps,
     const float* __restrict__ wih, const float* __restrict__ whh,
     const float* __restrict__ bih, const float* __restrict__ bhh,
     const float* __restrict__ mlp2w, const float* __restrict__ mlp2b,
     const float* __restrict__ dw, const float* __restrict__ db,
     const float* __restrict__ a1w, const float* __restrict__ a1b,
     const float* __restrict__ a2w, const float* __restrict__ a2b,
     const float* __restrict__ f1w, const float* __restrict__ f1b,
     const float* __restrict__ f2w, const float* __restrict__ f2b,
     float* __restrict__ outq){
  int bi = blockIdx.x;                 // 1024 = 16 b * 64 tiles
  int b = bi >> 6, tile = bi & 63;
  int t = threadIdx.x; int wv = t >> 6; int l = t & 63;
  int q = l >> 4, cr = l & 15;
  int m0 = tile*64 + wv*16;
  int drow = m0 + cr;

  __shared__ float s_log[7*64];
  __shared__ float s_absc[7*192];
  __shared__ float s_wq[7*68];
  __shared__ float s_upd[7*128];
  __shared__ unsigned short s_w1[4096];
  // tail-phase scratch (used only by the last block per b)
  __shared__ float G_us[7][64], G_hs[7][64], G_xs[7][64];
  __shared__ float G_gi[7][192], G_gh[7][192];
  __shared__ float G_af[28], G_p3[7][3];
  __shared__ unsigned s_last;

  for (int i = t; i < 1344; i += 256) s_absc[i] = absc[b*7*192 + i];
  for (int i = t; i < 476;  i += 256) s_wq[i]   = w2qc[b*7*68 + i];
  if (mode == 0)
    for (int i = t; i < 896; i += 256) s_upd[i] = 0.f;
  {
    const uint4* g = reinterpret_cast<const uint4*>(w1pack);
    uint4* d = reinterpret_cast<uint4*>(s_w1);
    for (int i = t; i < 512; i += 256) d[i] = g[i];
  }

  const unsigned short* er = encK + (size_t)(b*4096 + drow)*64;
  float gx = -0.5f + (float)(drow & 63) * (1.f/63.f);
  float gy = -0.5f + (float)((drow >> 6) & 63) * (1.f/63.f);
  float xb[16], gq[16], bq[16];
  {
    bf16x8 ea = *reinterpret_cast<const bf16x8*>(er + q*8);
    bf16x8 eb = *reinterpret_cast<const bf16x8*>(er + 32 + q*8);
    #pragma unroll
    for (int i = 0; i < 8; i++){ xb[i] = (float)ea[i]; xb[8+i] = (float)eb[i]; }
  }
  bf16x8 vb0, vb1;                     // encV row held bf16 until V loop
  if (mode == 0){
    const unsigned short* ev = encV + (size_t)(b*4096 + drow)*64;
    vb0 = *reinterpret_cast<const bf16x8*>(ev + q*8);
    vb1 = *reinterpret_cast<const bf16x8*>(ev + 32 + q*8);
  }
  #pragma unroll
  for (int h = 0; h < 2; h++){
    int fb = h ? (32 + q*8) : (q*8);
    const float4* g4 = reinterpret_cast<const float4*>(qg_ + fb);
    const float4* b4 = reinterpret_cast<const float4*>(qb_ + fb);
    #pragma unroll
    for (int p = 0; p < 2; p++){
      float4 gg = g4[p], bb = b4[p];
      int o = h*8 + p*4;
      gq[o+0]=gg.x; gq[o+1]=gg.y; gq[o+2]=gg.z; gq[o+3]=gg.w;
      bq[o+0]=bb.x; bq[o+1]=bb.y; bq[o+2]=bb.z; bq[o+3]=bb.w;
    }
  }
  float b1v[4];
  #pragma unroll
  for (int nt = 0; nt < 4; nt++) b1v[nt] = mlp1b[nt*16 + cr];
  __syncthreads();

  const bf16x8* wl = reinterpret_cast<const bf16x8*>(s_w1);
  f32x4 zero = {0.f, 0.f, 0.f, 0.f};

  // ---- K loop: logits for all 7 slots (slot-paired) ----
  for (int sp = 0; sp < 4; sp++){
    int s0 = sp*2;
    int np = (sp == 3) ? 1 : 2;
    int sB = (np == 2) ? s0 + 1 : s0;
    float x0[16], x1[16];
    float s1a = 0.f, s2a = 0.f, s1b = 0.f, s2b = 0.f;
    {
      const float* Ac = s_absc + s0*192;
      #pragma unroll
      for (int h = 0; h < 2; h++){
        int fb = h ? (32 + q*8) : (q*8);
        const float4* A4 = reinterpret_cast<const float4*>(Ac + fb);
        const float4* B4 = reinterpret_cast<const float4*>(Ac + 64 + fb);
        const float4* C4 = reinterpret_cast<const float4*>(Ac + 128 + fb);
        #pragma unroll
        for (int pp = 0; pp < 2; pp++){
          float4 Av = A4[pp], Bv = B4[pp], Cv = C4[pp];
          int o = h*8 + pp*4;
          x0[o+0] = xb[o+0] + gx*Av.x + gy*Bv.x + Cv.x;
          x0[o+1] = xb[o+1] + gx*Av.y + gy*Bv.y + Cv.y;
          x0[o+2] = xb[o+2] + gx*Av.z + gy*Bv.z + Cv.z;
          x0[o+3] = xb[o+3] + gx*Av.w + gy*Bv.w + Cv.w;
        }
      }
      #pragma unroll
      for (int k = 0; k < 16; k++){ s1a += x0[k]; s2a = fmaf(x0[k], x0[k], s2a); }
    }
    {
      const float* Ac = s_absc + sB*192;
      #pragma unroll
      for (int h = 0; h < 2; h++){
        int fb = h ? (32 + q*8) : (q*8);
        const float4* A4 = reinterpret_cast<const float4*>(Ac + fb);
        const float4* B4 = reinterpret_cast<const float4*>(Ac + 64 + fb);
        const float4* C4 = reinterpret_cast<const float4*>(Ac + 128 + fb);
        #pragma unroll
        for (int pp = 0; pp < 2; pp++){
          float4 Av = A4[pp], Bv = B4[pp], Cv = C4[pp];
          int o = h*8 + pp*4;
          x1[o+0] = xb[o+0] + gx*Av.x + gy*Bv.x + Cv.x;
          x1[o+1] = xb[o+1] + gx*Av.y + gy*Bv.y + Cv.y;
          x1[o+2] = xb[o+2] + gx*Av.z + gy*Bv.z + Cv.z;
          x1[o+3] = xb[o+3] + gx*Av.w + gy*Bv.w + Cv.w;
        }
      }
      #pragma unroll
      for (int k = 0; k < 16; k++){ s1b += x1[k]; s2b = fmaf(x1[k], x1[k], s2b); }
    }
    s1a += __shfl_xor(s1a, 16, 64); s2a += __shfl_xor(s2a, 16, 64);
    s1b += __shfl_xor(s1b, 16, 64); s2b += __shfl_xor(s2b, 16, 64);
    s1a += __shfl_xor(s1a, 32, 64); s2a += __shfl_xor(s2a, 32, 64);
    s1b += __shfl_xor(s1b, 32, 64); s2b += __shfl_xor(s2b, 32, 64);
    float mA = s1a*(1.f/64.f);
    float rA = 1.0f/sqrtf(s2a*(1.f/64.f) - mA*mA + 1e-5f);
    float mB = s1b*(1.f/64.f);
    float rB = 1.0f/sqrtf(s2b*(1.f/64.f) - mB*mB + 1e-5f);

    bf16x8 a00, a01, a10, a11;
    #pragma unroll
    for (int k = 0; k < 8; k++){
      a00[k] = (__bf16)((x0[k]    - mA)*rA*gq[k]   + bq[k]);
      a01[k] = (__bf16)((x0[8+k]  - mA)*rA*gq[8+k] + bq[8+k]);
      a10[k] = (__bf16)((x1[k]    - mB)*rB*gq[k]   + bq[k]);
      a11[k] = (__bf16)((x1[8+k]  - mB)*rB*gq[8+k] + bq[8+k]);
    }

    f32x4 acc0[4], acc1[4];
    #pragma unroll
    for (int nt = 0; nt < 4; nt++){
      bf16x8 w0 = wl[nt*64 + l];
      bf16x8 w1f = wl[(4 + nt)*64 + l];
      acc0[nt] = __builtin_amdgcn_mfma_f32_16x16x32_bf16(a00, w0,  zero,     0, 0, 0);
      acc0[nt] = __builtin_amdgcn_mfma_f32_16x16x32_bf16(a01, w1f, acc0[nt], 0, 0, 0);
      acc1[nt] = __builtin_amdgcn_mfma_f32_16x16x32_bf16(a10, w0,  zero,     0, 0, 0);
      acc1[nt] = __builtin_amdgcn_mfma_f32_16x16x32_bf16(a11, w1f, acc1[nt], 0, 0, 0);
    }

    float p0[4] = {0.f,0.f,0.f,0.f}, p1[4] = {0.f,0.f,0.f,0.f};
    #pragma unroll
    for (int nt = 0; nt < 4; nt++){
      float wq0 = s_wq[s0*68 + nt*16 + cr];
      float wq1 = s_wq[sB*68 + nt*16 + cr];
      #pragma unroll
      for (int reg = 0; reg < 4; reg++){
        p0[reg] = fmaf(fmaxf(acc0[nt][reg] + b1v[nt], 0.f), wq0, p0[reg]);
        p1[reg] = fmaf(fmaxf(acc1[nt][reg] + b1v[nt], 0.f), wq1, p1[reg]);
      }
    }
    #pragma unroll
    for (int off = 1; off < 16; off <<= 1){
      #pragma unroll
      for (int reg = 0; reg < 4; reg++){
        p0[reg] += __shfl_xor(p0[reg], off, 64);
        p1[reg] += __shfl_xor(p1[reg], off, 64);
      }
    }
    if (cr == 0){
      float c20 = s_wq[s0*68 + 64];
      float c21 = s_wq[sB*68 + 64];
      #pragma unroll
      for (int reg = 0; reg < 4; reg++){
        s_log[s0*64 + wv*16 + q*4 + reg] = (p0[reg] + c20) * 0.125f;
        if (np == 2) s_log[sB*64 + wv*16 + q*4 + reg] = (p1[reg] + c21) * 0.125f;
      }
    }
  }
  __syncthreads();

  // softmax over slots (per d column); att stays in s_log
  if (t < 64){
    float lv[7];
    #pragma unroll
    for (int s = 0; s < 7; s++) lv[s] = s_log[s*64 + t];
    float mx = lv[0];
    #pragma unroll
    for (int s = 1; s < 7; s++) mx = fmaxf(mx, lv[s]);
    float sm = 0.f;
    #pragma unroll
    for (int s = 0; s < 7; s++){ lv[s] = expf(lv[s] - mx); sm += lv[s]; }
    float inv = 1.0f / sm;
    #pragma unroll
    for (int s = 0; s < 7; s++){
      float a = lv[s] * inv;
      s_log[s*64 + t] = a;
      if (mode == 1) attOut[(size_t)(b*7+s)*4096 + tile*64 + t] = a;
    }
  }
  __syncthreads();

  // frames partials: thread (s, r) covers columns r and r+32
  if (t < 224){
    int s = t >> 5, r = t & 31;
    float a1 = s_log[s*64 + r];
    float a2 = s_log[s*64 + r + 32];
    float gx1 = -0.5f + (float)r * (1.f/63.f);
    float gx2 = -0.5f + (float)(r + 32) * (1.f/63.f);
    float gyc = -0.5f + (float)tile * (1.f/63.f);
    float gy2c = gyc*gyc;
    float w0 = a1 + a2;
    float w1 = a1*gx1 + a2*gx2;
    float w2 = w0*gyc;
    float w3 = a1*(gx1*gx1 + gy2c) + a2*(gx2*gx2 + gy2c);
    #pragma unroll
    for (int m = 1; m < 32; m <<= 1){
      w0 += __shfl_xor(w0, m, 64);
      w1 += __shfl_xor(w1, m, 64);
      w2 += __shfl_xor(w2, m, 64);
      w3 += __shfl_xor(w3, m, 64);
    }
    if (r == 0){
      atomicAdd(&accF[(b*7+s)*4 + 0], w0);
      atomicAdd(&accF[(b*7+s)*4 + 1], w1);
      atomicAdd(&accF[(b*7+s)*4 + 2], w2);
      atomicAdd(&accF[(b*7+s)*4 + 3], w3);
    }
  }

  // ---- V loop: weighted reduce into s_upd (U1, U2) ----
  if (mode == 0){
    float xbv[16];
    #pragma unroll
    for (int i = 0; i < 8; i++){ xbv[i] = (float)vb0[i]; xbv[8+i] = (float)vb1[i]; }
    for (int sp = 0; sp < 4; sp++){
      int s0 = sp*2;
      int np = (sp == 3) ? 1 : 2;
      int sB = (np == 2) ? s0 + 1 : s0;
      float x0[16], x1[16];
      float s1a = 0.f, s2a = 0.f, s1b = 0.f, s2b = 0.f;
      {
        const float* Ac = s_absc + s0*192;
        #pragma unroll
        for (int h = 0; h < 2; h++){
          int fb = h ? (32 + q*8) : (q*8);
          const float4* A4 = reinterpret_cast<const float4*>(Ac + fb);
          const float4* B4 = reinterpret_cast<const float4*>(Ac + 64 + fb);
          const float4* C4 = reinterpret_cast<const float4*>(Ac + 128 + fb);
          #pragma unroll
          for (int pp = 0; pp < 2; pp++){
            float4 Av = A4[pp], Bv = B4[pp], Cv = C4[pp];
            int o = h*8 + pp*4;
            x0[o+0] = xbv[o+0] + gx*Av.x + gy*Bv.x + Cv.x;
            x0[o+1] = xbv[o+1] + gx*Av.y + gy*Bv.y + Cv.y;
            x0[o+2] = xbv[o+2] + gx*Av.z + gy*Bv.z + Cv.z;
            x0[o+3] = xbv[o+3] + gx*Av.w + gy*Bv.w + Cv.w;
          }
        }
        #pragma unroll
        for (int k = 0; k < 16; k++){ s1a += x0[k]; s2a = fmaf(x0[k], x0[k], s2a); }
      }
      {
        const float* Ac = s_absc + sB*192;
        #pragma unroll
        for (int h = 0; h < 2; h++){
          int fb = h ? (32 + q*8) : (q*8);
          const float4* A4 = reinterpret_cast<const float4*>(Ac + fb);
          const float4* B4 = reinterpret_cast<const float4*>(Ac + 64 + fb);
          const float4* C4 = reinterpret_cast<const float4*>(Ac + 128 + fb);
          #pragma unroll
          for (int pp = 0; pp < 2; pp++){
            float4 Av = A4[pp], Bv = B4[pp], Cv = C4[pp];
            int o = h*8 + pp*4;
            x1[o+0] = xbv[o+0] + gx*Av.x + gy*Bv.x + Cv.x;
            x1[o+1] = xbv[o+1] + gx*Av.y + gy*Bv.y + Cv.y;
            x1[o+2] = xbv[o+2] + gx*Av.z + gy*Bv.z + Cv.z;
            x1[o+3] = xbv[o+3] + gx*Av.w + gy*Bv.w + Cv.w;
          }
        }
        #pragma unroll
        for (int k = 0; k < 16; k++){ s1b += x1[k]; s2b = fmaf(x1[k], x1[k], s2b); }
      }
      s1a += __shfl_xor(s1a, 16, 64); s2a += __shfl_xor(s2a, 16, 64);
      s1b += __shfl_xor(s1b, 16, 64); s2b += __shfl_xor(s2b, 16, 64);
      s1a += __shfl_xor(s1a, 32, 64); s2a += __shfl_xor(s2a, 32, 64);
      s1b += __shfl_xor(s1b, 32, 64); s2b += __shfl_xor(s2b, 32, 64);
      float mA = s1a*(1.f/64.f);
      float rA = 1.0f/sqrtf(s2a*(1.f/64.f) - mA*mA + 1e-5f);
      float mB = s1b*(1.f/64.f);
      float rB = 1.0f/sqrtf(s2b*(1.f/64.f) - mB*mB + 1e-5f);

      bf16x8 a00, a01, a10, a11;
      #pragma unroll
      for (int k = 0; k < 8; k++){
        a00[k] = (__bf16)((x0[k]    - mA)*rA*gq[k]   + bq[k]);
        a01[k] = (__bf16)((x0[8+k]  - mA)*rA*gq[8+k] + bq[8+k]);
        a10[k] = (__bf16)((x1[k]    - mB)*rB*gq[k]   + bq[k]);
        a11[k] = (__bf16)((x1[8+k]  - mB)*rB*gq[8+k] + bq[8+k]);
      }

      f32x4 acc0[4], acc1[4];
      #pragma unroll
      for (int nt = 0; nt < 4; nt++){
        bf16x8 w0 = wl[nt*64 + l];
        bf16x8 w1f = wl[(4 + nt)*64 + l];
        acc0[nt] = __builtin_amdgcn_mfma_f32_16x16x32_bf16(a00, w0,  zero,     0, 0, 0);
        acc0[nt] = __builtin_amdgcn_mfma_f32_16x16x32_bf16(a01, w1f, acc0[nt], 0, 0, 0);
        acc1[nt] = __builtin_amdgcn_mfma_f32_16x16x32_bf16(a10, w0,  zero,     0, 0, 0);
        acc1[nt] = __builtin_amdgcn_mfma_f32_16x16x32_bf16(a11, w1f, acc1[nt], 0, 0, 0);
      }

      float wr0[4], wr1[4];
      #pragma unroll
      for (int reg = 0; reg < 4; reg++){
        wr0[reg] = s_log[s0*64 + wv*16 + q*4 + reg];
        wr1[reg] = s_log[sB*64 + wv*16 + q*4 + reg];
      }
      float pa0[4], pa1[4], pu0[4], pu1[4];
      #pragma unroll
      for (int nt = 0; nt < 4; nt++){
        pa0[nt] = 0.f; pa1[nt] = 0.f; pu0[nt] = 0.f; pu1[nt] = 0.f;
        #pragma unroll
        for (int reg = 0; reg < 4; reg++){
          float v0 = fmaxf(acc0[nt][reg] + b1v[nt], 0.f);
          float v1 = fmaxf(acc1[nt][reg] + b1v[nt], 0.f);
          pa0[nt] = fmaf(wr0[reg], v0, pa0[nt]); pu0[nt] += v0;
          pa1[nt] = fmaf(wr1[reg], v1, pa1[nt]); pu1[nt] += v1;
        }
      }
      #pragma unroll
      for (int nt = 0; nt < 4; nt++){
        pa0[nt] += __shfl_xor(pa0[nt], 16, 64); pa0[nt] += __shfl_xor(pa0[nt], 32, 64);
        pu0[nt] += __shfl_xor(pu0[nt], 16, 64); pu0[nt] += __shfl_xor(pu0[nt], 32, 64);
        pa1[nt] += __shfl_xor(pa1[nt], 16, 64); pa1[nt] += __shfl_xor(pa1[nt], 32, 64);
        pu1[nt] += __shfl_xor(pu1[nt], 16, 64); pu1[nt] += __shfl_xor(pu1[nt], 32, 64);
      }
      if (q == 0){
        #pragma unroll
        for (int nt = 0; nt < 4; nt++){
          atomicAdd(&s_upd[s0*128 + nt*16 + cr], pa0[nt]);
          atomicAdd(&s_upd[s0*128 + 64 + nt*16 + cr], pu0[nt]);
          if (np == 2){
            atomicAdd(&s_upd[sB*128 + nt*16 + cr], pa1[nt]);
            atomicAdd(&s_upd[sB*128 + 64 + nt*16 + cr], pu1[nt]);
          }
        }
      }
    }
    __syncthreads();
    for (int i = t; i < 896; i += 256)
      atomicAdd(&upd[b*896 + i], s_upd[i]);
  }

  // ---- last-block election for batch b ----
  __threadfence();
  __syncthreads();
  if (t == 0) s_last = (atomicAdd(&cnt[b], 1u) == 63u) ? 1u : 0u;
  __syncthreads();
  if (!s_last) return;
  if (t == 0) atomicExch(&cnt[b], 0u);   // reset for next launch

  if (mode == 0){
    // ================= fused GRU for rows b*7 .. b*7+6 =================
    if (t < 28) G_af[t] = aread(&accF[b*28 + t]);
    __syncthreads();
    for (int i = t; i < 448; i += 256){
      int r = i >> 6, e = i & 63; int row = b*7 + r;
      float isa0 = 1.0f / G_af[r*4];
      float u1 = aread(&upd[row*128 + e]);
      float u2 = aread(&upd[row*128 + 64 + e]);
      G_us[r][e] = u1*isa0 + 1e-8f*u2;
      G_hs[r][e] = queries[row*64 + e];
    }
    if (t < 7){
      float sa = G_af[t*4], ax = G_af[t*4+1], ay = G_af[t*4+2], ar2 = G_af[t*4+3];
      float isa = 1.0f/sa;
      float Wx = ax*isa, Wy = ay*isa;
      float Wg = ar2*isa + 1e-8f*SR2;
      float s2 = Wg - (Wx*Wx + Wy*Wy)*(2.f - W0CONST);
      G_p3[t][0] = Wx; G_p3[t][1] = Wy; G_p3[t][2] = sqrtf(fmaxf(s2, 0.f));
    }
    __syncthreads();
    for (int i = t; i < 448; i += 256){
      int r = i >> 6, e = i & 63;
      float a = W0CONST * mlp2b[e];
      for (int j = 0; j < 64; j++) a = fmaf(G_us[r][j], mlp2w[j*64 + e], a);
      G_xs[r][e] = a;
    }
    __syncthreads();
    for (int i = t; i < 1344; i += 256){
      int r = i / 192, tt = i % 192;
      float gi = bih[tt], gh = bhh[tt];
      for (int e = 0; e < 64; e++){
        gi = fmaf(wih[tt*64 + e], G_xs[r][e], gi);
        gh = fmaf(whh[tt*64 + e], G_hs[r][e], gh);
      }
      G_gi[r][tt] = gi; G_gh[r][tt] = gh;
    }
    __syncthreads();
    for (int i = t; i < 448; i += 256){
      int r = i >> 6, e = i & 63; int row = b*7 + r;
      float rr = 1.0f/(1.0f + expf(-(G_gi[r][e]      + G_gh[r][e])));
      float z  = 1.0f/(1.0f + expf(-(G_gi[r][64+e]   + G_gh[r][64+e])));
      float n  = tanhf(G_gi[r][128+e] + rr*G_gh[r][128+e]);
      float newq = (1.0f - z)*n + z*G_hs[r][e];
      G_us[r][e] = newq;                 // reuse as newq store
      queries[row*64 + e] = newq;
      upd[row*128 + e] = 0.f;
      upd[row*128 + 64 + e] = 0.f;
    }
    if (t < 28) accF[b*28 + t] = 0.f;
    if (t < 21) ps[b*21 + t] = G_p3[t/3][t%3];
    __syncthreads();
    // next-phase prep: wave wv handles rows wv, wv+4
    for (int rr = wv; rr < 7; rr += 4){
      int row = b*7 + rr;
      pp_core(row, l, G_us[rr][l], G_p3[rr][0], G_p3[rr][1], G_p3[rr][2],
              qg_, qb_, dw, db, mlp2w, mlp2b, absc, w2qc);
    }
  } else {
    // ================= fused final heads for rows b*7 .. b*7+6 =========
    if (t < 28) G_af[t] = aread(&accF[b*28 + t]);
    for (int i = t; i < 448; i += 256){
      int r = i >> 6, e = i & 63; int row = b*7 + r;
      float qv = queries[row*64 + e];
      G_us[r][e] = qv;
      outq[row*64 + e] = qv;
    }
    __syncthreads();
    for (int i = t; i < 448; i += 256){
      int r = i >> 6, e = i & 63;
      float a = f1b[e];
      for (int j = 0; j < 64; j++) a = fmaf(G_us[r][j], f1w[j*64 + e], a);
      G_hs[r][e] = fmaxf(a, 0.f);
    }
    for (int i = t; i < 224; i += 256){
      int r = i >> 5, e = i & 31;
      float a = a1b[e];
      for (int j = 0; j < 64; j++) a = fmaf(G_us[r][j], a1w[j*32 + e], a);
      G_xs[0][r*32 + e] = fmaxf(a, 0.f);
    }
    __syncthreads();
    if (t < 21){
      int r = t / 3, e = t % 3; int row = b*7 + r;
      float sf = f2b[e];
      for (int o = 0; o < 64; o++) sf = fmaf(G_hs[r][o], f2w[o*3 + e], sf);
      float sa = G_af[r*4], ax = G_af[r*4+1], ay = G_af[r*4+2], ar2 = G_af[r*4+3];
      float isa = 1.0f/sa;
      float Wx = ax*isa, Wy = ay*isa;
      float Wg = ar2*isa + 1e-8f*SR2;
      float s2 = Wg - (Wx*Wx + Wy*Wy)*(2.f - W0CONST);
      float nv = (e == 0) ? Wx : ((e == 1) ? Wy : sqrtf(fmaxf(s2, 0.f)));
      outq[465920 + row*3 + e] = sf + nv;
    }
    if (t >= 32 && t < 39){
      int r = t - 32; int row = b*7 + r;
      float al = a2b[0];
      for (int o = 0; o < 32; o++) al = fmaf(G_xs[0][r*32 + o], a2w[o], al);
      outq[466256 + row] = 1.0f/(1.0f + expf(-al));
    }
  }
}

// ---------------------------------------------------------------------------
extern "C" void kernel_launch(void* const* d_in, const int* in_sizes, int n_in,
                              void* d_out, int out_size, void* d_ws, size_t ws_size,
                              hipStream_t stream){
  const float* data        = (const float*)d_in[0];
  const float* slot_noise  = (const float*)d_in[1];
  const float* pos_rand    = (const float*)d_in[2];
  const float* conv0_w     = (const float*)d_in[3];
  const float* conv0_b     = (const float*)d_in[4];
  const float* conv1_w     = (const float*)d_in[5];
  const float* conv1_b     = (const float*)d_in[6];
  const float* conv2_w     = (const float*)d_in[7];
  const float* conv2_b     = (const float*)d_in[8];
  const float* dataN_g     = (const float*)d_in[9];
  const float* dataN_b     = (const float*)d_in[10];
  const float* queryN_g    = (const float*)d_in[11];
  const float* queryN_b    = (const float*)d_in[12];
  const float* toK_w       = (const float*)d_in[13];
  const float* toK_b       = (const float*)d_in[14];
  const float* toV_w       = (const float*)d_in[15];
  const float* toV_b       = (const float*)d_in[16];
  const float* dense_w     = (const float*)d_in[17];
  const float* dense_b     = (const float*)d_in[18];
  const float* mlp1_w      = (const float*)d_in[19];
  const float* mlp1_b      = (const float*)d_in[20];
  const float* mlp2_w      = (const float*)d_in[21];
  const float* mlp2_b      = (const float*)d_in[22];
  const float* gru_wih     = (const float*)d_in[23];
  const float* gru_whh     = (const float*)d_in[24];
  const float* gru_bih     = (const float*)d_in[25];
  const float* gru_bhh     = (const float*)d_in[26];
  const float* alpha1_w    = (const float*)d_in[27];
  const float* alpha1_b    = (const float*)d_in[28];
  const float* alpha2_w    = (const float*)d_in[29];
  const float* alpha2_b    = (const float*)d_in[30];
  const float* final1_w    = (const float*)d_in[31];
  const float* final1_b    = (const float*)d_in[32];
  const float* final2_w    = (const float*)d_in[33];
  const float* final2_b    = (const float*)d_in[34];
  const float* slots_mu    = (const float*)d_in[35];
  const float* slots_lsig  = (const float*)d_in[36];

  float* ws   = (float*)d_ws;
  float* bufA = ws;                    // c0_bf (bf16) then encK (bf16)
  float* bufB = bufA + 4194304;        // enc bf16
  float* bufC = bufB + 4194304;        // c1_bf (bf16) then encV (bf16)
  float* queries = bufC + 4194304;     // 7,168
  float* ps   = queries + 7168;        // 512 ([112][3], 336 used)
  float* absc = ps + 512;              // 21,504 (A/B/cc per (b,s))
  float* accF = absc + 21504;          // 512 ([112][4]: sa, ax, ay, ar2)
  float* upd  = accF + 512;            // 14,336 ([112][128]: U1 | U2)
  float* w2qc = upd + 14336;           // 7,616 ([112][68])
  unsigned short* w1pack = (unsigned short*)(w2qc + 7616);   // 4096 bf16
  unsigned short* kpack  = w1pack + 4096;                    // 4096
  unsigned short* vpack  = kpack + 4096;                     // 4096
  unsigned short* wp1    = vpack + 4096;                     // 102,400
  unsigned short* wp2    = wp1 + 102400;                     // 102,400
  unsigned int*   cnt    = (unsigned int*)(wp2 + 102400);    // 16

  unsigned short* c0_bf = (unsigned short*)bufA;   // conv0 out, NHWC bf16
  unsigned short* c1_bf = (unsigned short*)bufC;   // conv1 out, NHWC bf16
  unsigned short* enc   = (unsigned short*)bufB;   // LN(conv2) bf16
  unsigned short* encK  = (unsigned short*)bufA;   // overwrites c0_bf (done)
  unsigned short* encV  = (unsigned short*)bufC;   // overwrites c1_bf (done)

  float* outq   = (float*)d_out;       // queries [7168]
  float* outatt = outq + 7168;         // att [458752]

  k_packall<<<960, 256, 0, stream>>>(mlp1_w, toK_w, toV_w, conv1_w, conv2_w,
                                     w1pack, kpack, vpack, wp1, wp2,
                                     slot_noise, pos_rand, slots_mu, slots_lsig,
                                     queryN_g, queryN_b, dense_w, dense_b, mlp2_w, mlp2_b,
                                     queries, ps, absc, w2qc, accF, upd, cnt);
  k_conv0<<<1024, 256, 0, stream>>>(data, conv0_w, conv0_b, c0_bf);
  k_convm<<<512, 256, 0, stream>>>(c0_bf, wp1, conv1_b, nullptr, nullptr, c1_bf, 0);
  k_convm<<<512, 256, 0, stream>>>(c1_bf, wp2, conv2_b, dataN_g, dataN_b, enc, 1);
  k_projm<<<1024, 256, 0, stream>>>(enc, kpack, toK_b, vpack, toV_b, encK, encV);

  for (int p = 0; p < 4; p++){
    k_attn<<<1024, 256, 0, stream>>>(encK, encV, w1pack, mlp1_b, absc,
                                     queryN_g, queryN_b, w2qc, outatt, accF, upd,
                                     (p < 3) ? 0 : 1, cnt, queries, ps,
                                     gru_wih, gru_whh, gru_bih, gru_bhh,
                                     mlp2_w, mlp2_b, dense_w, dense_b,
                                     alpha1_w, alpha1_b, alpha2_w, alpha2_b,
                                     final1_w, final1_b, final2_w, final2_b, outq);
  }
}

// Round 5
// 681.160 us; speedup vs baseline: 1.1645x; 1.1645x over previous
//
#include <hip/hip_runtime.h>
#include <cmath>

// ---------------------------------------------------------------------------
// InvariantSlotAttention forward. R20 = R16 (R1 champion, 486us) with k_attn
// re-gridded: 2048 blocks x 32 d-rows (was 1024 x 64). Waves split as
// (rowHalf = wv&1, slotGroup = wv>>1): each wave runs 2 slot-pair iterations
// over 16 rows (was 4 over 16) -> half the serial chain, ~20 waves/CU
// resident (was 16). k_gru/k_final separate launches (R19 in-kernel tail
// fusion reverted: 16-block tail serialization cost 3x).
// B=16, S=7, E=HID=64, D=4096, N_ITER=3, TSOFT=0.125
// ---------------------------------------------------------------------------

#define RLOW_F 0.1f
#define RHIGH_F 0.22360679774997896f
#define W0CONST 1.00004096f      /* sum_d wts = 1 + 4096e-8 exactly */
#define SR2 704.3386243f         /* sum_d (gx^2+gy^2) */

typedef __attribute__((ext_vector_type(8))) __bf16 bf16x8;
typedef __attribute__((ext_vector_type(4))) float f32x4;

__device__ __forceinline__ float wsum64(float v){
  #pragma unroll
  for (int off = 32; off > 0; off >>= 1) v += __shfl_xor(v, off, 64);
  return v;
}
__device__ __forceinline__ float rdlane(float v, int l){
  return __int_as_float(__builtin_amdgcn_readlane(__float_as_int(v), l));
}
__device__ __forceinline__ unsigned short bf16bits(float v){
  __bf16 h = (__bf16)v;
  return *reinterpret_cast<unsigned short*>(&h);
}

// ---- phase prep core: one full wave (lanes 0..63), e = lane ---------------
__device__ __forceinline__ void pp_core(int row, int e, float qv,
    float px, float py, float sc,
    const float* __restrict__ qg_, const float* __restrict__ qb_,
    const float* __restrict__ dw, const float* __restrict__ db,
    const float* __restrict__ mlp2w, const float* __restrict__ mlp2b,
    float* __restrict__ absc, float* __restrict__ w2qc){
  float m = wsum64(qv) * (1.f/64.f);
  float d = qv - m;
  float var = wsum64(d*d) * (1.f/64.f);
  float qlnv = d * (1.0f/sqrtf(var + 1e-5f)) * qg_[e] + qb_[e];
  float A  = dw[e]      / sc;
  float Bv = dw[64 + e] / sc;
  absc[row*192 + e]       = A;
  absc[row*192 + 64 + e]  = Bv;
  absc[row*192 + 128 + e] = db[e] - px*A - py*Bv;
  float acc = 0.f;
  const float* wrow = mlp2w + e*64;
  for (int j = 0; j < 64; j++) acc = fmaf(wrow[j], rdlane(qlnv, j), acc);
  w2qc[row*68 + e] = acc;
  float c2 = wsum64(mlp2b[e] * qlnv);
  if (e == 0) w2qc[row*68 + 64] = c2;
}

// ---------------- bundled: weight packing + phase-0 prep -------------------
// blocks 0-15: w1pack; 16-31: kpack; 32-47: vpack; 48-447: wp1; 448-847: wp2;
// 848-959: prep (row = bi-848, threads 0-63 active).
__global__ void k_packall(const float* __restrict__ mlp1_w, const float* __restrict__ toK_w,
                          const float* __restrict__ toV_w, const float* __restrict__ conv1_w,
                          const float* __restrict__ conv2_w,
                          unsigned short* __restrict__ w1pack, unsigned short* __restrict__ kpack,
                          unsigned short* __restrict__ vpack, unsigned short* __restrict__ wp1,
                          unsigned short* __restrict__ wp2,
                          const float* __restrict__ noise, const float* __restrict__ prand,
                          const float* __restrict__ mu, const float* __restrict__ logsig,
                          const float* __restrict__ qg_, const float* __restrict__ qb_,
                          const float* __restrict__ dw, const float* __restrict__ db,
                          const float* __restrict__ mlp2w, const float* __restrict__ mlp2b,
                          float* __restrict__ queries, float* __restrict__ ps,
                          float* __restrict__ absc, float* __restrict__ w2qc,
                          float* __restrict__ accF, float* __restrict__ upd){
  int bi = blockIdx.x; int t = threadIdx.x;
  if (bi < 48){
    const float* src = (bi < 16) ? mlp1_w : ((bi < 32) ? toK_w : toV_w);
    unsigned short* dst = (bi < 16) ? w1pack : ((bi < 32) ? kpack : vpack);
    int idx = (bi & 15)*256 + t;
    int jj = idx & 7;
    int lane = (idx >> 3) & 63;
    int frag = idx >> 9;
    int ks = frag >> 2, nt = frag & 3;
    int q = lane >> 4, cr = lane & 15;
    int k = ks*32 + q*8 + jj;
    int n = nt*16 + cr;
    dst[idx] = bf16bits(src[k*64 + n]);
  } else if (bi < 848){
    int rb = bi - 48;
    const float* src = (rb < 400) ? conv1_w : conv2_w;
    unsigned short* dst = (rb < 400) ? wp1 : wp2;
    int idx = (rb % 400)*256 + t;
    int j = idx & 7;
    int l = (idx >> 3) & 63;
    int frag = idx >> 9;
    int nt = frag & 3;
    int ks = (frag >> 2) % 10;
    int dy = frag / 40;
    int q = l >> 4, cr = l & 15;
    int k = ks*32 + q*8 + j;
    int kx = k >> 6, ch = k & 63;
    int n = nt*16 + cr;
    dst[idx] = bf16bits(src[((n*64 + ch)*5 + dy)*5 + kx]);
  } else {
    if (t >= 64) return;
    int row = bi - 848;           // 112 rows
    int e = t;
    int s = row % 7;
    float qv = mu[e] + expf(logsig[e]) * noise[row*64 + e];
    queries[row*64 + e] = qv;
    upd[row*128 + e] = 0.f;
    upd[row*128 + 64 + e] = 0.f;
    if (e < 4) accF[row*4 + e] = 0.f;
    float pv = 0.f;
    if (e < 3){
      float pr = prand[row*3 + e];
      if (s < 2)       pv = pr - 0.5f;
      else if (s == 6) pv = (RLOW_F - RHIGH_F)*pr + RHIGH_F;
      else             pv = pr;
      ps[row*3 + e] = pv;
    }
    float px = rdlane(pv, 0), py = rdlane(pv, 1), sc = rdlane(pv, 2);
    pp_core(row, e, qv, px, py, sc, qg_, qb_, dw, db, mlp2w, mlp2b, absc, w2qc);
  }
}

// ---------------- conv0: 1->64 channels, 5x5 same, relu, NHWC bf16 out -----
__global__ __launch_bounds__(256) void k_conv0(const float* __restrict__ in,
                        const float* __restrict__ w, const float* __restrict__ bias,
                        unsigned short* __restrict__ out){
  int bi = blockIdx.x; int b = bi >> 6; int y = bi & 63;   // 1024 blocks
  int t = threadIdx.x; int lane = t & 63; int xg = t >> 6;
  __shared__ float s_in[5*68];
  __shared__ float s_w[64*25];
  __shared__ float s_out[64*65];
  for (int i = t; i < 1600; i += 256) s_w[i] = w[i];
  for (int i = t; i < 340; i += 256){
    int r = i / 68, cx = i % 68;
    int yy = y + r - 2, gx = cx - 2;
    float v = 0.f;
    if (yy >= 0 && yy < 64 && gx >= 0 && gx < 64) v = in[(b*64 + yy)*64 + gx];
    s_in[r*68 + cx] = v;
  }
  __syncthreads();
  int o = lane;
  float bvv = bias[o];
  float acc[16];
  #pragma unroll
  for (int k = 0; k < 16; k++) acc[k] = bvv;
  #pragma unroll
  for (int ky = 0; ky < 5; ky++){
    float rv[20];
    const float4* p = reinterpret_cast<const float4*>(&s_in[ky*68 + xg*16]);
    #pragma unroll
    for (int q = 0; q < 5; q++){ float4 f = p[q]; rv[q*4]=f.x; rv[q*4+1]=f.y; rv[q*4+2]=f.z; rv[q*4+3]=f.w; }
    #pragma unroll
    for (int kx = 0; kx < 5; kx++){
      float wv = s_w[o*25 + ky*5 + kx];
      #pragma unroll
      for (int k = 0; k < 16; k++) acc[k] = fmaf(rv[k+kx], wv, acc[k]);
    }
  }
  #pragma unroll
  for (int k = 0; k < 16; k++) s_out[o*65 + xg*16 + k] = fmaxf(acc[k], 0.f);
  __syncthreads();
  for (int i = t; i < 4096; i += 256){
    int px = i >> 6, ch = i & 63;
    out[((size_t)(b*64 + y)*64 + px)*64 + ch] = bf16bits(s_out[ch*65 + px]);
  }
}

// ---------------- conv1/conv2 bf16 MFMA implicit GEMM (512 blocks) ---------
__global__ __launch_bounds__(256) void k_convm(const unsigned short* __restrict__ in_bf,
                        const unsigned short* __restrict__ wpack,
                        const float* __restrict__ bias,
                        const float* __restrict__ lng, const float* __restrict__ lnb,
                        unsigned short* __restrict__ out_bf, int mode){
  int bi = blockIdx.x;                  // 512 = 16 b * 16 yg * 2 xh
  int b = bi >> 5; int yg = (bi >> 1) & 15; int xh = bi & 1;
  int t = threadIdx.x; int wv = t >> 6; int l = t & 63;
  int q = l >> 4, cr = l & 15;
  int yr = wv >> 1, ph = wv & 1;
  int p0 = ph*16;

  __shared__ char lds[8*36*144];

  for (int ri = 0; ri < 8; ri++){
    int yy = yg*4 + ri - 2;
    bool rok = (yy >= 0 && yy < 64);
    const uint4* src = reinterpret_cast<const uint4*>(in_bf + (size_t)(b*64 + yy)*64*64);
    for (int i = t; i < 288; i += 256){
      int px = i >> 3, c8 = i & 7;
      uint4 v = {0u,0u,0u,0u};
      int gx = xh*32 + px - 2;
      if (rok && gx >= 0 && gx < 64) v = src[gx*8 + c8];
      *reinterpret_cast<uint4*>(&lds[ri*5184 + px*144 + c8*16]) = v;
    }
  }
  __syncthreads();

  f32x4 acc[2][4];
  #pragma unroll
  for (int r = 0; r < 2; r++)
    #pragma unroll
    for (int nt = 0; nt < 4; nt++) acc[r][nt] = (f32x4){0.f,0.f,0.f,0.f};

  const bf16x8* wp = reinterpret_cast<const bf16x8*>(wpack);
  for (int dy = 0; dy < 5; dy++){
    for (int ks = 0; ks < 10; ks++){
      bf16x8 Bf[4];
      int fbase = (dy*10 + ks)*4;
      #pragma unroll
      for (int nt = 0; nt < 4; nt++) Bf[nt] = wp[(fbase + nt)*64 + l];
      int aoff = (p0 + cr + (ks >> 1))*144 + (ks & 1)*64 + q*16;
      #pragma unroll
      for (int r = 0; r < 2; r++){
        int ri = yr*2 + r + dy;
        bf16x8 a = *reinterpret_cast<const bf16x8*>(&lds[ri*5184 + aoff]);
        #pragma unroll
        for (int nt = 0; nt < 4; nt++)
          acc[r][nt] = __builtin_amdgcn_mfma_f32_16x16x32_bf16(a, Bf[nt], acc[r][nt], 0, 0, 0);
      }
    }
  }

  float bvv[4];
  #pragma unroll
  for (int nt = 0; nt < 4; nt++) bvv[nt] = bias[nt*16 + cr];

  if (mode == 0){
    #pragma unroll
    for (int r = 0; r < 2; r++){
      int y = yg*4 + yr*2 + r;
      #pragma unroll
      for (int reg = 0; reg < 4; reg++){
        int p = xh*32 + p0 + q*4 + reg;
        size_t base = ((size_t)(b*64 + y)*64 + p)*64;
        #pragma unroll
        for (int nt = 0; nt < 4; nt++)
          out_bf[base + nt*16 + cr] = bf16bits(fmaxf(acc[r][nt][reg] + bvv[nt], 0.f));
      }
    }
  } else {
    float gv[4], bb[4];
    #pragma unroll
    for (int nt = 0; nt < 4; nt++){ gv[nt] = lng[nt*16 + cr]; bb[nt] = lnb[nt*16 + cr]; }
    #pragma unroll
    for (int r = 0; r < 2; r++){
      int y = yg*4 + yr*2 + r;
      #pragma unroll
      for (int reg = 0; reg < 4; reg++){
        int p = xh*32 + p0 + q*4 + reg;
        float v[4]; float s1 = 0.f, s2 = 0.f;
        #pragma unroll
        for (int nt = 0; nt < 4; nt++){
          v[nt] = fmaxf(acc[r][nt][reg] + bvv[nt], 0.f);
          s1 += v[nt]; s2 += v[nt]*v[nt];
        }
        #pragma unroll
        for (int m = 1; m < 16; m <<= 1){ s1 += __shfl_xor(s1, m, 64); s2 += __shfl_xor(s2, m, 64); }
        float mean = s1 * (1.f/64.f);
        float var  = s2 * (1.f/64.f) - mean*mean;
        float rstd = 1.0f/sqrtf(var + 1e-5f);
        size_t base = ((size_t)b*4096 + y*64 + p)*64;
        #pragma unroll
        for (int nt = 0; nt < 4; nt++)
          out_bf[base + nt*16 + cr] = bf16bits((v[nt] - mean)*rstd*gv[nt] + bb[nt]);
      }
    }
  }
}

// ---------------- K/V projection: enc(bf16) @ toK_w, toV_w -> bf16 ---------
__global__ __launch_bounds__(256) void k_projm(const unsigned short* __restrict__ enc,
                       const unsigned short* __restrict__ kpack, const float* __restrict__ bk,
                       const unsigned short* __restrict__ vpack, const float* __restrict__ bvp,
                       unsigned short* __restrict__ K, unsigned short* __restrict__ V){
  int bi = blockIdx.x; int b = bi >> 6; int tile = bi & 63;  // 1024 blocks
  int t = threadIdx.x; int wv = t >> 6; int l = t & 63;
  int q = l >> 4, cr = l & 15;
  int d0 = tile*64 + wv*16;

  const bf16x8* kp = reinterpret_cast<const bf16x8*>(kpack);
  const bf16x8* vp = reinterpret_cast<const bf16x8*>(vpack);
  bf16x8 KB[8], VB[8];
  #pragma unroll
  for (int f = 0; f < 8; f++){ KB[f] = kp[f*64 + l]; VB[f] = vp[f*64 + l]; }

  const unsigned short* er = enc + (size_t)(b*4096 + d0 + cr)*64;
  bf16x8 a0 = *reinterpret_cast<const bf16x8*>(er + q*8);
  bf16x8 a1 = *reinterpret_cast<const bf16x8*>(er + 32 + q*8);

  f32x4 zero = {0.f,0.f,0.f,0.f};
  f32x4 aK[4], aV[4];
  #pragma unroll
  for (int nt = 0; nt < 4; nt++){
    aK[nt] = __builtin_amdgcn_mfma_f32_16x16x32_bf16(a0, KB[nt],     zero,   0, 0, 0);
    aK[nt] = __builtin_amdgcn_mfma_f32_16x16x32_bf16(a1, KB[4 + nt], aK[nt], 0, 0, 0);
    aV[nt] = __builtin_amdgcn_mfma_f32_16x16x32_bf16(a0, VB[nt],     zero,   0, 0, 0);
    aV[nt] = __builtin_amdgcn_mfma_f32_16x16x32_bf16(a1, VB[4 + nt], aV[nt], 0, 0, 0);
  }
  #pragma unroll
  for (int nt = 0; nt < 4; nt++){
    float bkv = bk[nt*16 + cr], bvv = bvp[nt*16 + cr];
    #pragma unroll
    for (int reg = 0; reg < 4; reg++){
      size_t base = ((size_t)b*4096 + d0 + q*4 + reg)*64 + nt*16 + cr;
      K[base] = bf16bits(aK[nt][reg] + bkv);
      V[base] = bf16bits(aV[nt][reg] + bvv);
    }
  }
}

// ---------------- fused attention: K logits + softmax + frames + V reduce --
// 2048 blocks x 32 d-rows. wave wv: rowHalf = wv&1 (16 rows), spg = wv>>1
// (slot-pairs spg*2 .. spg*2+1). mode 0: V path accumulates U1/U2 into upd.
// mode 1 (iter 3): write att to global, skip V.
__global__ __launch_bounds__(256) void k_attn(const unsigned short* __restrict__ encK,
     const unsigned short* __restrict__ encV,
     const unsigned short* __restrict__ w1pack, const float* __restrict__ mlp1b,
     const float* __restrict__ absc, const float* __restrict__ qg_,
     const float* __restrict__ qb_, const float* __restrict__ w2qc,
     float* __restrict__ attOut, float* __restrict__ accF,
     float* __restrict__ upd, int mode){
  int bi = blockIdx.x;                 // 2048 = 16 b * 128 tiles (32 rows each)
  int b = bi >> 7, tile = bi & 127;
  int t = threadIdx.x; int wv = t >> 6; int l = t & 63;
  int q = l >> 4, cr = l & 15;
  int rowHalf = wv & 1, spg = wv >> 1;
  int m0 = tile*32 + rowHalf*16;
  int drow = m0 + cr;

  __shared__ float s_log[7*32];
  __shared__ float s_absc[7*192];
  __shared__ float s_wq[7*68];
  __shared__ float s_upd[7*128];
  __shared__ unsigned short s_w1[4096];
  for (int i = t; i < 1344; i += 256) s_absc[i] = absc[b*7*192 + i];
  for (int i = t; i < 476;  i += 256) s_wq[i]   = w2qc[b*7*68 + i];
  if (mode == 0)
    for (int i = t; i < 896; i += 256) s_upd[i] = 0.f;
  {
    const uint4* g = reinterpret_cast<const uint4*>(w1pack);
    uint4* d = reinterpret_cast<uint4*>(s_w1);
    for (int i = t; i < 512; i += 256) d[i] = g[i];
  }

  const unsigned short* er = encK + (size_t)(b*4096 + drow)*64;
  float gx = -0.5f + (float)(drow & 63) * (1.f/63.f);
  float gy = -0.5f + (float)((drow >> 6) & 63) * (1.f/63.f);
  float xb[16], gq[16], bq[16];
  {
    bf16x8 ea = *reinterpret_cast<const bf16x8*>(er + q*8);
    bf16x8 eb = *reinterpret_cast<const bf16x8*>(er + 32 + q*8);
    #pragma unroll
    for (int i = 0; i < 8; i++){ xb[i] = (float)ea[i]; xb[8+i] = (float)eb[i]; }
  }
  bf16x8 vb0, vb1;                     // encV row held bf16 until V loop
  if (mode == 0){
    const unsigned short* ev = encV + (size_t)(b*4096 + drow)*64;
    vb0 = *reinterpret_cast<const bf16x8*>(ev + q*8);
    vb1 = *reinterpret_cast<const bf16x8*>(ev + 32 + q*8);
  }
  #pragma unroll
  for (int h = 0; h < 2; h++){
    int fb = h ? (32 + q*8) : (q*8);
    const float4* g4 = reinterpret_cast<const float4*>(qg_ + fb);
    const float4* b4 = reinterpret_cast<const float4*>(qb_ + fb);
    #pragma unroll
    for (int p = 0; p < 2; p++){
      float4 gg = g4[p], bb = b4[p];
      int o = h*8 + p*4;
      gq[o+0]=gg.x; gq[o+1]=gg.y; gq[o+2]=gg.z; gq[o+3]=gg.w;
      bq[o+0]=bb.x; bq[o+1]=bb.y; bq[o+2]=bb.z; bq[o+3]=bb.w;
    }
  }
  float b1v[4];
  #pragma unroll
  for (int nt = 0; nt < 4; nt++) b1v[nt] = mlp1b[nt*16 + cr];
  __syncthreads();

  const bf16x8* wl = reinterpret_cast<const bf16x8*>(s_w1);
  f32x4 zero = {0.f, 0.f, 0.f, 0.f};

  // ---- K loop: this wave's 2 slot-pairs over its 16 rows ----
  for (int spi = 0; spi < 2; spi++){
    int sp = spg*2 + spi;
    int s0 = sp*2;
    int np = (sp == 3) ? 1 : 2;
    int sB = (np == 2) ? s0 + 1 : s0;
    float x0[16], x1[16];
    float s1a = 0.f, s2a = 0.f, s1b = 0.f, s2b = 0.f;
    {
      const float* Ac = s_absc + s0*192;
      #pragma unroll
      for (int h = 0; h < 2; h++){
        int fb = h ? (32 + q*8) : (q*8);
        const float4* A4 = reinterpret_cast<const float4*>(Ac + fb);
        const float4* B4 = reinterpret_cast<const float4*>(Ac + 64 + fb);
        const float4* C4 = reinterpret_cast<const float4*>(Ac + 128 + fb);
        #pragma unroll
        for (int pp = 0; pp < 2; pp++){
          float4 Av = A4[pp], Bv = B4[pp], Cv = C4[pp];
          int o = h*8 + pp*4;
          x0[o+0] = xb[o+0] + gx*Av.x + gy*Bv.x + Cv.x;
          x0[o+1] = xb[o+1] + gx*Av.y + gy*Bv.y + Cv.y;
          x0[o+2] = xb[o+2] + gx*Av.z + gy*Bv.z + Cv.z;
          x0[o+3] = xb[o+3] + gx*Av.w + gy*Bv.w + Cv.w;
        }
      }
      #pragma unroll
      for (int k = 0; k < 16; k++){ s1a += x0[k]; s2a = fmaf(x0[k], x0[k], s2a); }
    }
    {
      const float* Ac = s_absc + sB*192;
      #pragma unroll
      for (int h = 0; h < 2; h++){
        int fb = h ? (32 + q*8) : (q*8);
        const float4* A4 = reinterpret_cast<const float4*>(Ac + fb);
        const float4* B4 = reinterpret_cast<const float4*>(Ac + 64 + fb);
        const float4* C4 = reinterpret_cast<const float4*>(Ac + 128 + fb);
        #pragma unroll
        for (int pp = 0; pp < 2; pp++){
          float4 Av = A4[pp], Bv = B4[pp], Cv = C4[pp];
          int o = h*8 + pp*4;
          x1[o+0] = xb[o+0] + gx*Av.x + gy*Bv.x + Cv.x;
          x1[o+1] = xb[o+1] + gx*Av.y + gy*Bv.y + Cv.y;
          x1[o+2] = xb[o+2] + gx*Av.z + gy*Bv.z + Cv.z;
          x1[o+3] = xb[o+3] + gx*Av.w + gy*Bv.w + Cv.w;
        }
      }
      #pragma unroll
      for (int k = 0; k < 16; k++){ s1b += x1[k]; s2b = fmaf(x1[k], x1[k], s2b); }
    }
    s1a += __shfl_xor(s1a, 16, 64); s2a += __shfl_xor(s2a, 16, 64);
    s1b += __shfl_xor(s1b, 16, 64); s2b += __shfl_xor(s2b, 16, 64);
    s1a += __shfl_xor(s1a, 32, 64); s2a += __shfl_xor(s2a, 32, 64);
    s1b += __shfl_xor(s1b, 32, 64); s2b += __shfl_xor(s2b, 32, 64);
    float mA = s1a*(1.f/64.f);
    float rA = 1.0f/sqrtf(s2a*(1.f/64.f) - mA*mA + 1e-5f);
    float mB = s1b*(1.f/64.f);
    float rB = 1.0f/sqrtf(s2b*(1.f/64.f) - mB*mB + 1e-5f);

    bf16x8 a00, a01, a10, a11;
    #pragma unroll
    for (int k = 0; k < 8; k++){
      a00[k] = (__bf16)((x0[k]    - mA)*rA*gq[k]   + bq[k]);
      a01[k] = (__bf16)((x0[8+k]  - mA)*rA*gq[8+k] + bq[8+k]);
      a10[k] = (__bf16)((x1[k]    - mB)*rB*gq[k]   + bq[k]);
      a11[k] = (__bf16)((x1[8+k]  - mB)*rB*gq[8+k] + bq[8+k]);
    }

    f32x4 acc0[4], acc1[4];
    #pragma unroll
    for (int nt = 0; nt < 4; nt++){
      bf16x8 w0 = wl[nt*64 + l];
      bf16x8 w1f = wl[(4 + nt)*64 + l];
      acc0[nt] = __builtin_amdgcn_mfma_f32_16x16x32_bf16(a00, w0,  zero,     0, 0, 0);
      acc0[nt] = __builtin_amdgcn_mfma_f32_16x16x32_bf16(a01, w1f, acc0[nt], 0, 0, 0);
      acc1[nt] = __builtin_amdgcn_mfma_f32_16x16x32_bf16(a10, w0,  zero,     0, 0, 0);
      acc1[nt] = __builtin_amdgcn_mfma_f32_16x16x32_bf16(a11, w1f, acc1[nt], 0, 0, 0);
    }

    float p0[4] = {0.f,0.f,0.f,0.f}, p1[4] = {0.f,0.f,0.f,0.f};
    #pragma unroll
    for (int nt = 0; nt < 4; nt++){
      float wq0 = s_wq[s0*68 + nt*16 + cr];
      float wq1 = s_wq[sB*68 + nt*16 + cr];
      #pragma unroll
      for (int reg = 0; reg < 4; reg++){
        p0[reg] = fmaf(fmaxf(acc0[nt][reg] + b1v[nt], 0.f), wq0, p0[reg]);
        p1[reg] = fmaf(fmaxf(acc1[nt][reg] + b1v[nt], 0.f), wq1, p1[reg]);
      }
    }
    #pragma unroll
    for (int off = 1; off < 16; off <<= 1){
      #pragma unroll
      for (int reg = 0; reg < 4; reg++){
        p0[reg] += __shfl_xor(p0[reg], off, 64);
        p1[reg] += __shfl_xor(p1[reg], off, 64);
      }
    }
    if (cr == 0){
      float c20 = s_wq[s0*68 + 64];
      float c21 = s_wq[sB*68 + 64];
      #pragma unroll
      for (int reg = 0; reg < 4; reg++){
        s_log[s0*32 + rowHalf*16 + q*4 + reg] = (p0[reg] + c20) * 0.125f;
        if (np == 2) s_log[sB*32 + rowHalf*16 + q*4 + reg] = (p1[reg] + c21) * 0.125f;
      }
    }
  }
  __syncthreads();

  // softmax over slots (per d column); att stays in s_log
  if (t < 32){
    float lv[7];
    #pragma unroll
    for (int s = 0; s < 7; s++) lv[s] = s_log[s*32 + t];
    float mx = lv[0];
    #pragma unroll
    for (int s = 1; s < 7; s++) mx = fmaxf(mx, lv[s]);
    float sm = 0.f;
    #pragma unroll
    for (int s = 0; s < 7; s++){ lv[s] = expf(lv[s] - mx); sm += lv[s]; }
    float inv = 1.0f / sm;
    #pragma unroll
    for (int s = 0; s < 7; s++){
      float a = lv[s] * inv;
      s_log[s*32 + t] = a;
      if (mode == 1) attOut[(size_t)(b*7+s)*4096 + tile*32 + t] = a;
    }
  }
  __syncthreads();

  // frames partials: thread (s, r) covers column r (32 cols); d = tile*32 + r
  if (t < 224){
    int s = t >> 5, r = t & 31;
    float a1 = s_log[s*32 + r];
    int dcol = tile*32 + r;
    float gx1 = -0.5f + (float)(dcol & 63) * (1.f/63.f);
    float gyc = -0.5f + (float)(dcol >> 6) * (1.f/63.f);
    float w0 = a1;
    float w1 = a1*gx1;
    float w2 = a1*gyc;
    float w3 = a1*(gx1*gx1 + gyc*gyc);
    #pragma unroll
    for (int m = 1; m < 32; m <<= 1){
      w0 += __shfl_xor(w0, m, 64);
      w1 += __shfl_xor(w1, m, 64);
      w2 += __shfl_xor(w2, m, 64);
      w3 += __shfl_xor(w3, m, 64);
    }
    if (r == 0){
      atomicAdd(&accF[(b*7+s)*4 + 0], w0);
      atomicAdd(&accF[(b*7+s)*4 + 1], w1);
      atomicAdd(&accF[(b*7+s)*4 + 2], w2);
      atomicAdd(&accF[(b*7+s)*4 + 3], w3);
    }
  }

  // ---- V loop: weighted reduce into s_upd (U1, U2) ----
  if (mode == 0){
    float xbv[16];
    #pragma unroll
    for (int i = 0; i < 8; i++){ xbv[i] = (float)vb0[i]; xbv[8+i] = (float)vb1[i]; }
    for (int spi = 0; spi < 2; spi++){
      int sp = spg*2 + spi;
      int s0 = sp*2;
      int np = (sp == 3) ? 1 : 2;
      int sB = (np == 2) ? s0 + 1 : s0;
      float x0[16], x1[16];
      float s1a = 0.f, s2a = 0.f, s1b = 0.f, s2b = 0.f;
      {
        const float* Ac = s_absc + s0*192;
        #pragma unroll
        for (int h = 0; h < 2; h++){
          int fb = h ? (32 + q*8) : (q*8);
          const float4* A4 = reinterpret_cast<const float4*>(Ac + fb);
          const float4* B4 = reinterpret_cast<const float4*>(Ac + 64 + fb);
          const float4* C4 = reinterpret_cast<const float4*>(Ac + 128 + fb);
          #pragma unroll
          for (int pp = 0; pp < 2; pp++){
            float4 Av = A4[pp], Bv = B4[pp], Cv = C4[pp];
            int o = h*8 + pp*4;
            x0[o+0] = xbv[o+0] + gx*Av.x + gy*Bv.x + Cv.x;
            x0[o+1] = xbv[o+1] + gx*Av.y + gy*Bv.y + Cv.y;
            x0[o+2] = xbv[o+2] + gx*Av.z + gy*Bv.z + Cv.z;
            x0[o+3] = xbv[o+3] + gx*Av.w + gy*Bv.w + Cv.w;
          }
        }
        #pragma unroll
        for (int k = 0; k < 16; k++){ s1a += x0[k]; s2a = fmaf(x0[k], x0[k], s2a); }
      }
      {
        const float* Ac = s_absc + sB*192;
        #pragma unroll
        for (int h = 0; h < 2; h++){
          int fb = h ? (32 + q*8) : (q*8);
          const float4* A4 = reinterpret_cast<const float4*>(Ac + fb);
          const float4* B4 = reinterpret_cast<const float4*>(Ac + 64 + fb);
          const float4* C4 = reinterpret_cast<const float4*>(Ac + 128 + fb);
          #pragma unroll
          for (int pp = 0; pp < 2; pp++){
            float4 Av = A4[pp], Bv = B4[pp], Cv = C4[pp];
            int o = h*8 + pp*4;
            x1[o+0] = xbv[o+0] + gx*Av.x + gy*Bv.x + Cv.x;
            x1[o+1] = xbv[o+1] + gx*Av.y + gy*Bv.y + Cv.y;
            x1[o+2] = xbv[o+2] + gx*Av.z + gy*Bv.z + Cv.z;
            x1[o+3] = xbv[o+3] + gx*Av.w + gy*Bv.w + Cv.w;
          }
        }
        #pragma unroll
        for (int k = 0; k < 16; k++){ s1b += x1[k]; s2b = fmaf(x1[k], x1[k], s2b); }
      }
      s1a += __shfl_xor(s1a, 16, 64); s2a += __shfl_xor(s2a, 16, 64);
      s1b += __shfl_xor(s1b, 16, 64); s2b += __shfl_xor(s2b, 16, 64);
      s1a += __shfl_xor(s1a, 32, 64); s2a += __shfl_xor(s2a, 32, 64);
      s1b += __shfl_xor(s1b, 32, 64); s2b += __shfl_xor(s2b, 32, 64);
      float mA = s1a*(1.f/64.f);
      float rA = 1.0f/sqrtf(s2a*(1.f/64.f) - mA*mA + 1e-5f);
      float mB = s1b*(1.f/64.f);
      float rB = 1.0f/sqrtf(s2b*(1.f/64.f) - mB*mB + 1e-5f);

      bf16x8 a00, a01, a10, a11;
      #pragma unroll
      for (int k = 0; k < 8; k++){
        a00[k] = (__bf16)((x0[k]    - mA)*rA*gq[k]   + bq[k]);
        a01[k] = (__bf16)((x0[8+k]  - mA)*rA*gq[8+k] + bq[8+k]);
        a10[k] = (__bf16)((x1[k]    - mB)*rB*gq[k]   + bq[k]);
        a11[k] = (__bf16)((x1[8+k]  - mB)*rB*gq[8+k] + bq[8+k]);
      }

      f32x4 acc0[4], acc1[4];
      #pragma unroll
      for (int nt = 0; nt < 4; nt++){
        bf16x8 w0 = wl[nt*64 + l];
        bf16x8 w1f = wl[(4 + nt)*64 + l];
        acc0[nt] = __builtin_amdgcn_mfma_f32_16x16x32_bf16(a00, w0,  zero,     0, 0, 0);
        acc0[nt] = __builtin_amdgcn_mfma_f32_16x16x32_bf16(a01, w1f, acc0[nt], 0, 0, 0);
        acc1[nt] = __builtin_amdgcn_mfma_f32_16x16x32_bf16(a10, w0,  zero,     0, 0, 0);
        acc1[nt] = __builtin_amdgcn_mfma_f32_16x16x32_bf16(a11, w1f, acc1[nt], 0, 0, 0);
      }

      float wr0[4], wr1[4];
      #pragma unroll
      for (int reg = 0; reg < 4; reg++){
        wr0[reg] = s_log[s0*32 + rowHalf*16 + q*4 + reg];
        wr1[reg] = s_log[sB*32 + rowHalf*16 + q*4 + reg];
      }
      float pa0[4], pa1[4], pu0[4], pu1[4];
      #pragma unroll
      for (int nt = 0; nt < 4; nt++){
        pa0[nt] = 0.f; pa1[nt] = 0.f; pu0[nt] = 0.f; pu1[nt] = 0.f;
        #pragma unroll
        for (int reg = 0; reg < 4; reg++){
          float v0 = fmaxf(acc0[nt][reg] + b1v[nt], 0.f);
          float v1 = fmaxf(acc1[nt][reg] + b1v[nt], 0.f);
          pa0[nt] = fmaf(wr0[reg], v0, pa0[nt]); pu0[nt] += v0;
          pa1[nt] = fmaf(wr1[reg], v1, pa1[nt]); pu1[nt] += v1;
        }
      }
      #pragma unroll
      for (int nt = 0; nt < 4; nt++){
        pa0[nt] += __shfl_xor(pa0[nt], 16, 64); pa0[nt] += __shfl_xor(pa0[nt], 32, 64);
        pu0[nt] += __shfl_xor(pu0[nt], 16, 64); pu0[nt] += __shfl_xor(pu0[nt], 32, 64);
        pa1[nt] += __shfl_xor(pa1[nt], 16, 64); pa1[nt] += __shfl_xor(pa1[nt], 32, 64);
        pu1[nt] += __shfl_xor(pu1[nt], 16, 64); pu1[nt] += __shfl_xor(pu1[nt], 32, 64);
      }
      if (q == 0){
        #pragma unroll
        for (int nt = 0; nt < 4; nt++){
          atomicAdd(&s_upd[s0*128 + nt*16 + cr], pa0[nt]);
          atomicAdd(&s_upd[s0*128 + 64 + nt*16 + cr], pu0[nt]);
          if (np == 2){
            atomicAdd(&s_upd[sB*128 + nt*16 + cr], pa1[nt]);
            atomicAdd(&s_upd[sB*128 + 64 + nt*16 + cr], pu1[nt]);
          }
        }
      }
    }
    __syncthreads();
    for (int i = t; i < 896; i += 256)
      atomicAdd(&upd[b*896 + i], s_upd[i]);
  }
}

// ---------------- GRU cell + frames finalize + next-phase prep -------------
__global__ void k_gru(float* __restrict__ upd, float* __restrict__ queries,
                      const float* __restrict__ wih, const float* __restrict__ whh,
                      const float* __restrict__ bih, const float* __restrict__ bhh,
                      const float* __restrict__ mlp2w, const float* __restrict__ mlp2b,
                      float* __restrict__ accF, float* __restrict__ ps,
                      const float* __restrict__ qg_, const float* __restrict__ qb_,
                      const float* __restrict__ dw, const float* __restrict__ db,
                      float* __restrict__ absc, float* __restrict__ w2qc){
  int row = blockIdx.x; int t = threadIdx.x;   // 112 x 192
  __shared__ float us[64], hs[64], xs[64], gis[192], ghs[192];
  __shared__ float s_ps3[3];
  if (t < 64){
    float isa0 = 1.0f/accF[row*4];
    us[t] = upd[row*128 + t]*isa0 + 1e-8f*upd[row*128 + 64 + t];
    hs[t] = queries[row*64 + t];
  }
  if (t == 64){
    float sa = accF[row*4+0];
    float ax = accF[row*4+1], ay = accF[row*4+2], ar2 = accF[row*4+3];
    float isa = 1.0f/sa;
    float Wx = ax*isa, Wy = ay*isa;
    float Wg = ar2*isa + 1e-8f*SR2;
    float s2 = Wg - (Wx*Wx + Wy*Wy)*(2.f - W0CONST);
    s_ps3[0] = Wx; s_ps3[1] = Wy; s_ps3[2] = sqrtf(fmaxf(s2, 0.f));
  }
  __syncthreads();
  if (t < 64){
    float a = W0CONST * mlp2b[t];
    for (int i = 0; i < 64; i++) a = fmaf(us[i], mlp2w[i*64 + t], a);
    xs[t] = a;
  }
  __syncthreads();
  float gi = bih[t], gh = bhh[t];
  for (int e = 0; e < 64; e++){
    gi = fmaf(wih[t*64 + e], xs[e], gi);
    gh = fmaf(whh[t*64 + e], hs[e], gh);
  }
  gis[t] = gi; ghs[t] = gh;
  __syncthreads();
  if (t < 64){
    float r = 1.0f/(1.0f + expf(-(gis[t]      + ghs[t])));
    float z = 1.0f/(1.0f + expf(-(gis[64+t]   + ghs[64+t])));
    float n = tanhf(gis[128+t] + r*ghs[128+t]);
    float newq = (1.0f - z)*n + z*hs[t];
    queries[row*64 + t] = newq;
    upd[row*128 + t] = 0.f;
    upd[row*128 + 64 + t] = 0.f;
    if (t < 4) accF[row*4 + t] = 0.f;
    if (t < 3) ps[row*3 + t] = s_ps3[t];
    pp_core(row, t, newq, s_ps3[0], s_ps3[1], s_ps3[2],
            qg_, qb_, dw, db, mlp2w, mlp2b, absc, w2qc);
  }
}

// ---------------- heads: alpha, slot_feat(+frames), copy queries -----------
__global__ void k_final(const float* __restrict__ queries, const float* __restrict__ accF,
                        const float* __restrict__ a1w, const float* __restrict__ a1b,
                        const float* __restrict__ a2w, const float* __restrict__ a2b,
                        const float* __restrict__ f1w, const float* __restrict__ f1b,
                        const float* __restrict__ f2w, const float* __restrict__ f2b,
                        float* __restrict__ out){
  int bs = blockIdx.x; int e = threadIdx.x;    // 112 x 64
  __shared__ float qs[64], hf[64], ha[32];
  float q = queries[bs*64 + e];
  qs[e] = q;
  out[bs*64 + e] = q;
  __syncthreads();
  float accf = f1b[e];
  for (int i = 0; i < 64; i++) accf = fmaf(qs[i], f1w[i*64 + e], accf);
  hf[e] = fmaxf(accf, 0.f);
  if (e < 32){
    float acca = a1b[e];
    for (int i = 0; i < 64; i++) acca = fmaf(qs[i], a1w[i*32 + e], acca);
    ha[e] = fmaxf(acca, 0.f);
  }
  __syncthreads();
  if (e < 3){
    float sf = f2b[e];
    for (int o = 0; o < 64; o++) sf = fmaf(hf[o], f2w[o*3 + e], sf);
    float sa = accF[bs*4+0], ax = accF[bs*4+1], ay = accF[bs*4+2], ar2 = accF[bs*4+3];
    float isa = 1.0f/sa;
    float Wx = ax*isa, Wy = ay*isa;
    float Wg = ar2*isa + 1e-8f*SR2;
    float s2 = Wg - (Wx*Wx + Wy*Wy)*(2.f - W0CONST);
    float nv = (e == 0) ? Wx : ((e == 1) ? Wy : sqrtf(fmaxf(s2, 0.f)));
    out[465920 + bs*3 + e] = sf + nv;
  }
  if (e == 32){
    float al = a2b[0];
    for (int o = 0; o < 32; o++) al = fmaf(ha[o], a2w[o], al);
    out[466256 + bs] = 1.0f/(1.0f + expf(-al));
  }
}

// ---------------------------------------------------------------------------
extern "C" void kernel_launch(void* const* d_in, const int* in_sizes, int n_in,
                              void* d_out, int out_size, void* d_ws, size_t ws_size,
                              hipStream_t stream){
  const float* data        = (const float*)d_in[0];
  const float* slot_noise  = (const float*)d_in[1];
  const float* pos_rand    = (const float*)d_in[2];
  const float* conv0_w     = (const float*)d_in[3];
  const float* conv0_b     = (const float*)d_in[4];
  const float* conv1_w     = (const float*)d_in[5];
  const float* conv1_b     = (const float*)d_in[6];
  const float* conv2_w     = (const float*)d_in[7];
  const float* conv2_b     = (const float*)d_in[8];
  const float* dataN_g     = (const float*)d_in[9];
  const float* dataN_b     = (const float*)d_in[10];
  const float* queryN_g    = (const float*)d_in[11];
  const float* queryN_b    = (const float*)d_in[12];
  const float* toK_w       = (const float*)d_in[13];
  const float* toK_b       = (const float*)d_in[14];
  const float* toV_w       = (const float*)d_in[15];
  const float* toV_b       = (const float*)d_in[16];
  const float* dense_w     = (const float*)d_in[17];
  const float* dense_b     = (const float*)d_in[18];
  const float* mlp1_w      = (const float*)d_in[19];
  const float* mlp1_b      = (const float*)d_in[20];
  const float* mlp2_w      = (const float*)d_in[21];
  const float* mlp2_b      = (const float*)d_in[22];
  const float* gru_wih     = (const float*)d_in[23];
  const float* gru_whh     = (const float*)d_in[24];
  const float* gru_bih     = (const float*)d_in[25];
  const float* gru_bhh     = (const float*)d_in[26];
  const float* alpha1_w    = (const float*)d_in[27];
  const float* alpha1_b    = (const float*)d_in[28];
  const float* alpha2_w    = (const float*)d_in[29];
  const float* alpha2_b    = (const float*)d_in[30];
  const float* final1_w    = (const float*)d_in[31];
  const float* final1_b    = (const float*)d_in[32];
  const float* final2_w    = (const float*)d_in[33];
  const float* final2_b    = (const float*)d_in[34];
  const float* slots_mu    = (const float*)d_in[35];
  const float* slots_lsig  = (const float*)d_in[36];

  float* ws   = (float*)d_ws;
  float* bufA = ws;                    // c0_bf (bf16) then encK (bf16)
  float* bufB = bufA + 4194304;        // enc bf16
  float* bufC = bufB + 4194304;        // c1_bf (bf16) then encV (bf16)
  float* queries = bufC + 4194304;     // 7,168
  float* ps   = queries + 7168;        // 512 ([112][3], 336 used)
  float* absc = ps + 512;              // 21,504 (A/B/cc per (b,s))
  float* accF = absc + 21504;          // 512 ([112][4]: sa, ax, ay, ar2)
  float* upd  = accF + 512;            // 14,336 ([112][128]: U1 | U2)
  float* w2qc = upd + 14336;           // 7,616 ([112][68])
  unsigned short* w1pack = (unsigned short*)(w2qc + 7616);   // 4096 bf16
  unsigned short* kpack  = w1pack + 4096;                    // 4096
  unsigned short* vpack  = kpack + 4096;                     // 4096
  unsigned short* wp1    = vpack + 4096;                     // 102,400
  unsigned short* wp2    = wp1 + 102400;                     // 102,400

  unsigned short* c0_bf = (unsigned short*)bufA;   // conv0 out, NHWC bf16
  unsigned short* c1_bf = (unsigned short*)bufC;   // conv1 out, NHWC bf16
  unsigned short* enc   = (unsigned short*)bufB;   // LN(conv2) bf16
  unsigned short* encK  = (unsigned short*)bufA;   // overwrites c0_bf (done)
  unsigned short* encV  = (unsigned short*)bufC;   // overwrites c1_bf (done)

  float* outq   = (float*)d_out;       // queries [7168]
  float* outatt = outq + 7168;         // att [458752]

  k_packall<<<960, 256, 0, stream>>>(mlp1_w, toK_w, toV_w, conv1_w, conv2_w,
                                     w1pack, kpack, vpack, wp1, wp2,
                                     slot_noise, pos_rand, slots_mu, slots_lsig,
                                     queryN_g, queryN_b, dense_w, dense_b, mlp2_w, mlp2_b,
                                     queries, ps, absc, w2qc, accF, upd);
  k_conv0<<<1024, 256, 0, stream>>>(data, conv0_w, conv0_b, c0_bf);
  k_convm<<<512, 256, 0, stream>>>(c0_bf, wp1, conv1_b, nullptr, nullptr, c1_bf, 0);
  k_convm<<<512, 256, 0, stream>>>(c1_bf, wp2, conv2_b, dataN_g, dataN_b, enc, 1);
  k_projm<<<1024, 256, 0, stream>>>(enc, kpack, toK_b, vpack, toV_b, encK, encV);

  for (int p = 0; p < 4; p++){
    k_attn<<<2048, 256, 0, stream>>>(encK, encV, w1pack, mlp1_b, absc,
                                     queryN_g, queryN_b, w2qc, outatt, accF, upd,
                                     (p < 3) ? 0 : 1);
    if (p < 3){
      k_gru<<<112, 192, 0, stream>>>(upd, queries, gru_wih, gru_whh, gru_bih, gru_bhh,
                                     mlp2_w, mlp2_b, accF, ps, queryN_g, queryN_b,
                                     dense_w, dense_b, absc, w2qc);
    }
  }
  k_final<<<112, 64, 0, stream>>>(queries, accF,
                                  alpha1_w, alpha1_b, alpha2_w, alpha2_b,
                                  final1_w, final1_b, final2_w, final2_b, outq);
}

// Round 8
// 482.083 us; speedup vs baseline: 1.6454x; 1.4130x over previous
//
#include <hip/hip_runtime.h>
#include <cmath>

// ---------------------------------------------------------------------------
// InvariantSlotAttention forward. R23 = exact revert to R16 (R1 champion,
// 486.6us, passed): fused attnK+attnV (softmax block-local over slots; V
// normalization deferred to k_gru via U1/U2), bundled packing+prep launch.
// Post-R16 variants all failed/regressed: R17 transposed K-MFMA (VGPR 100->108
// occupancy cliff), R18 cooperative launch (rejected by harness), R19
// last-block tail fusion (16-block serialization, 793us), R20 2048-block
// re-grid (staging doubled, 681us), R21/R22 closed-form LN moments (precision:
// att absmax 0.096 > 0.053 from raw-moment cancellation at small slot scale).
// This configuration is a verified local optimum of the latency-bound k_attn.
// B=16, S=7, E=HID=64, D=4096, N_ITER=3, TSOFT=0.125
// ---------------------------------------------------------------------------

#define RLOW_F 0.1f
#define RHIGH_F 0.22360679774997896f
#define W0CONST 1.00004096f      /* sum_d wts = 1 + 4096e-8 exactly */
#define SR2 704.3386243f         /* sum_d (gx^2+gy^2) */

typedef __attribute__((ext_vector_type(8))) __bf16 bf16x8;
typedef __attribute__((ext_vector_type(4))) float f32x4;

__device__ __forceinline__ float wsum64(float v){
  #pragma unroll
  for (int off = 32; off > 0; off >>= 1) v += __shfl_xor(v, off, 64);
  return v;
}
__device__ __forceinline__ float rdlane(float v, int l){
  return __int_as_float(__builtin_amdgcn_readlane(__float_as_int(v), l));
}
__device__ __forceinline__ unsigned short bf16bits(float v){
  __bf16 h = (__bf16)v;
  return *reinterpret_cast<unsigned short*>(&h);
}

// ---- phase prep core: one full wave (lanes 0..63), e = lane ---------------
__device__ __forceinline__ void pp_core(int row, int e, float qv,
    float px, float py, float sc,
    const float* __restrict__ qg_, const float* __restrict__ qb_,
    const float* __restrict__ dw, const float* __restrict__ db,
    const float* __restrict__ mlp2w, const float* __restrict__ mlp2b,
    float* __restrict__ absc, float* __restrict__ w2qc){
  float m = wsum64(qv) * (1.f/64.f);
  float d = qv - m;
  float var = wsum64(d*d) * (1.f/64.f);
  float qlnv = d * (1.0f/sqrtf(var + 1e-5f)) * qg_[e] + qb_[e];
  float A  = dw[e]      / sc;
  float Bv = dw[64 + e] / sc;
  absc[row*192 + e]       = A;
  absc[row*192 + 64 + e]  = Bv;
  absc[row*192 + 128 + e] = db[e] - px*A - py*Bv;
  float acc = 0.f;
  const float* wrow = mlp2w + e*64;
  for (int j = 0; j < 64; j++) acc = fmaf(wrow[j], rdlane(qlnv, j), acc);
  w2qc[row*68 + e] = acc;
  float c2 = wsum64(mlp2b[e] * qlnv);
  if (e == 0) w2qc[row*68 + 64] = c2;
}

// ---------------- bundled: weight packing + phase-0 prep -------------------
// blocks 0-15: w1pack; 16-31: kpack; 32-47: vpack; 48-447: wp1; 448-847: wp2;
// 848-959: prep (row = bi-848, threads 0-63 active).
__global__ void k_packall(const float* __restrict__ mlp1_w, const float* __restrict__ toK_w,
                          const float* __restrict__ toV_w, const float* __restrict__ conv1_w,
                          const float* __restrict__ conv2_w,
                          unsigned short* __restrict__ w1pack, unsigned short* __restrict__ kpack,
                          unsigned short* __restrict__ vpack, unsigned short* __restrict__ wp1,
                          unsigned short* __restrict__ wp2,
                          const float* __restrict__ noise, const float* __restrict__ prand,
                          const float* __restrict__ mu, const float* __restrict__ logsig,
                          const float* __restrict__ qg_, const float* __restrict__ qb_,
                          const float* __restrict__ dw, const float* __restrict__ db,
                          const float* __restrict__ mlp2w, const float* __restrict__ mlp2b,
                          float* __restrict__ queries, float* __restrict__ ps,
                          float* __restrict__ absc, float* __restrict__ w2qc,
                          float* __restrict__ accF, float* __restrict__ upd){
  int bi = blockIdx.x; int t = threadIdx.x;
  if (bi < 48){
    const float* src = (bi < 16) ? mlp1_w : ((bi < 32) ? toK_w : toV_w);
    unsigned short* dst = (bi < 16) ? w1pack : ((bi < 32) ? kpack : vpack);
    int idx = (bi & 15)*256 + t;
    int jj = idx & 7;
    int lane = (idx >> 3) & 63;
    int frag = idx >> 9;
    int ks = frag >> 2, nt = frag & 3;
    int q = lane >> 4, cr = lane & 15;
    int k = ks*32 + q*8 + jj;
    int n = nt*16 + cr;
    dst[idx] = bf16bits(src[k*64 + n]);
  } else if (bi < 848){
    int rb = bi - 48;
    const float* src = (rb < 400) ? conv1_w : conv2_w;
    unsigned short* dst = (rb < 400) ? wp1 : wp2;
    int idx = (rb % 400)*256 + t;
    int j = idx & 7;
    int l = (idx >> 3) & 63;
    int frag = idx >> 9;
    int nt = frag & 3;
    int ks = (frag >> 2) % 10;
    int dy = frag / 40;
    int q = l >> 4, cr = l & 15;
    int k = ks*32 + q*8 + j;
    int kx = k >> 6, ch = k & 63;
    int n = nt*16 + cr;
    dst[idx] = bf16bits(src[((n*64 + ch)*5 + dy)*5 + kx]);
  } else {
    if (t >= 64) return;
    int row = bi - 848;           // 112 rows
    int e = t;
    int s = row % 7;
    float qv = mu[e] + expf(logsig[e]) * noise[row*64 + e];
    queries[row*64 + e] = qv;
    upd[row*128 + e] = 0.f;
    upd[row*128 + 64 + e] = 0.f;
    if (e < 4) accF[row*4 + e] = 0.f;
    float pv = 0.f;
    if (e < 3){
      float pr = prand[row*3 + e];
      if (s < 2)       pv = pr - 0.5f;
      else if (s == 6) pv = (RLOW_F - RHIGH_F)*pr + RHIGH_F;
      else             pv = pr;
      ps[row*3 + e] = pv;
    }
    float px = rdlane(pv, 0), py = rdlane(pv, 1), sc = rdlane(pv, 2);
    pp_core(row, e, qv, px, py, sc, qg_, qb_, dw, db, mlp2w, mlp2b, absc, w2qc);
  }
}

// ---------------- conv0: 1->64 channels, 5x5 same, relu, NHWC bf16 out -----
__global__ __launch_bounds__(256) void k_conv0(const float* __restrict__ in,
                        const float* __restrict__ w, const float* __restrict__ bias,
                        unsigned short* __restrict__ out){
  int bi = blockIdx.x; int b = bi >> 6; int y = bi & 63;   // 1024 blocks
  int t = threadIdx.x; int lane = t & 63; int xg = t >> 6;
  __shared__ float s_in[5*68];
  __shared__ float s_w[64*25];
  __shared__ float s_out[64*65];
  for (int i = t; i < 1600; i += 256) s_w[i] = w[i];
  for (int i = t; i < 340; i += 256){
    int r = i / 68, cx = i % 68;
    int yy = y + r - 2, gx = cx - 2;
    float v = 0.f;
    if (yy >= 0 && yy < 64 && gx >= 0 && gx < 64) v = in[(b*64 + yy)*64 + gx];
    s_in[r*68 + cx] = v;
  }
  __syncthreads();
  int o = lane;
  float bvv = bias[o];
  float acc[16];
  #pragma unroll
  for (int k = 0; k < 16; k++) acc[k] = bvv;
  #pragma unroll
  for (int ky = 0; ky < 5; ky++){
    float rv[20];
    const float4* p = reinterpret_cast<const float4*>(&s_in[ky*68 + xg*16]);
    #pragma unroll
    for (int q = 0; q < 5; q++){ float4 f = p[q]; rv[q*4]=f.x; rv[q*4+1]=f.y; rv[q*4+2]=f.z; rv[q*4+3]=f.w; }
    #pragma unroll
    for (int kx = 0; kx < 5; kx++){
      float wv = s_w[o*25 + ky*5 + kx];
      #pragma unroll
      for (int k = 0; k < 16; k++) acc[k] = fmaf(rv[k+kx], wv, acc[k]);
    }
  }
  #pragma unroll
  for (int k = 0; k < 16; k++) s_out[o*65 + xg*16 + k] = fmaxf(acc[k], 0.f);
  __syncthreads();
  for (int i = t; i < 4096; i += 256){
    int px = i >> 6, ch = i & 63;
    out[((size_t)(b*64 + y)*64 + px)*64 + ch] = bf16bits(s_out[ch*65 + px]);
  }
}

// ---------------- conv1/conv2 bf16 MFMA implicit GEMM (512 blocks) ---------
__global__ __launch_bounds__(256) void k_convm(const unsigned short* __restrict__ in_bf,
                        const unsigned short* __restrict__ wpack,
                        const float* __restrict__ bias,
                        const float* __restrict__ lng, const float* __restrict__ lnb,
                        unsigned short* __restrict__ out_bf, int mode){
  int bi = blockIdx.x;                  // 512 = 16 b * 16 yg * 2 xh
  int b = bi >> 5; int yg = (bi >> 1) & 15; int xh = bi & 1;
  int t = threadIdx.x; int wv = t >> 6; int l = t & 63;
  int q = l >> 4, cr = l & 15;
  int yr = wv >> 1, ph = wv & 1;
  int p0 = ph*16;

  __shared__ char lds[8*36*144];

  for (int ri = 0; ri < 8; ri++){
    int yy = yg*4 + ri - 2;
    bool rok = (yy >= 0 && yy < 64);
    const uint4* src = reinterpret_cast<const uint4*>(in_bf + (size_t)(b*64 + yy)*64*64);
    for (int i = t; i < 288; i += 256){
      int px = i >> 3, c8 = i & 7;
      uint4 v = {0u,0u,0u,0u};
      int gx = xh*32 + px - 2;
      if (rok && gx >= 0 && gx < 64) v = src[gx*8 + c8];
      *reinterpret_cast<uint4*>(&lds[ri*5184 + px*144 + c8*16]) = v;
    }
  }
  __syncthreads();

  f32x4 acc[2][4];
  #pragma unroll
  for (int r = 0; r < 2; r++)
    #pragma unroll
    for (int nt = 0; nt < 4; nt++) acc[r][nt] = (f32x4){0.f,0.f,0.f,0.f};

  const bf16x8* wp = reinterpret_cast<const bf16x8*>(wpack);
  for (int dy = 0; dy < 5; dy++){
    for (int ks = 0; ks < 10; ks++){
      bf16x8 Bf[4];
      int fbase = (dy*10 + ks)*4;
      #pragma unroll
      for (int nt = 0; nt < 4; nt++) Bf[nt] = wp[(fbase + nt)*64 + l];
      int aoff = (p0 + cr + (ks >> 1))*144 + (ks & 1)*64 + q*16;
      #pragma unroll
      for (int r = 0; r < 2; r++){
        int ri = yr*2 + r + dy;
        bf16x8 a = *reinterpret_cast<const bf16x8*>(&lds[ri*5184 + aoff]);
        #pragma unroll
        for (int nt = 0; nt < 4; nt++)
          acc[r][nt] = __builtin_amdgcn_mfma_f32_16x16x32_bf16(a, Bf[nt], acc[r][nt], 0, 0, 0);
      }
    }
  }

  float bvv[4];
  #pragma unroll
  for (int nt = 0; nt < 4; nt++) bvv[nt] = bias[nt*16 + cr];

  if (mode == 0){
    #pragma unroll
    for (int r = 0; r < 2; r++){
      int y = yg*4 + yr*2 + r;
      #pragma unroll
      for (int reg = 0; reg < 4; reg++){
        int p = xh*32 + p0 + q*4 + reg;
        size_t base = ((size_t)(b*64 + y)*64 + p)*64;
        #pragma unroll
        for (int nt = 0; nt < 4; nt++)
          out_bf[base + nt*16 + cr] = bf16bits(fmaxf(acc[r][nt][reg] + bvv[nt], 0.f));
      }
    }
  } else {
    float gv[4], bb[4];
    #pragma unroll
    for (int nt = 0; nt < 4; nt++){ gv[nt] = lng[nt*16 + cr]; bb[nt] = lnb[nt*16 + cr]; }
    #pragma unroll
    for (int r = 0; r < 2; r++){
      int y = yg*4 + yr*2 + r;
      #pragma unroll
      for (int reg = 0; reg < 4; reg++){
        int p = xh*32 + p0 + q*4 + reg;
        float v[4]; float s1 = 0.f, s2 = 0.f;
        #pragma unroll
        for (int nt = 0; nt < 4; nt++){
          v[nt] = fmaxf(acc[r][nt][reg] + bvv[nt], 0.f);
          s1 += v[nt]; s2 += v[nt]*v[nt];
        }
        #pragma unroll
        for (int m = 1; m < 16; m <<= 1){ s1 += __shfl_xor(s1, m, 64); s2 += __shfl_xor(s2, m, 64); }
        float mean = s1 * (1.f/64.f);
        float var  = s2 * (1.f/64.f) - mean*mean;
        float rstd = 1.0f/sqrtf(var + 1e-5f);
        size_t base = ((size_t)b*4096 + y*64 + p)*64;
        #pragma unroll
        for (int nt = 0; nt < 4; nt++)
          out_bf[base + nt*16 + cr] = bf16bits((v[nt] - mean)*rstd*gv[nt] + bb[nt]);
      }
    }
  }
}

// ---------------- K/V projection: enc(bf16) @ toK_w, toV_w -> bf16 ---------
__global__ __launch_bounds__(256) void k_projm(const unsigned short* __restrict__ enc,
                       const unsigned short* __restrict__ kpack, const float* __restrict__ bk,
                       const unsigned short* __restrict__ vpack, const float* __restrict__ bvp,
                       unsigned short* __restrict__ K, unsigned short* __restrict__ V){
  int bi = blockIdx.x; int b = bi >> 6; int tile = bi & 63;  // 1024 blocks
  int t = threadIdx.x; int wv = t >> 6; int l = t & 63;
  int q = l >> 4, cr = l & 15;
  int d0 = tile*64 + wv*16;

  const bf16x8* kp = reinterpret_cast<const bf16x8*>(kpack);
  const bf16x8* vp = reinterpret_cast<const bf16x8*>(vpack);
  bf16x8 KB[8], VB[8];
  #pragma unroll
  for (int f = 0; f < 8; f++){ KB[f] = kp[f*64 + l]; VB[f] = vp[f*64 + l]; }

  const unsigned short* er = enc + (size_t)(b*4096 + d0 + cr)*64;
  bf16x8 a0 = *reinterpret_cast<const bf16x8*>(er + q*8);
  bf16x8 a1 = *reinterpret_cast<const bf16x8*>(er + 32 + q*8);

  f32x4 zero = {0.f,0.f,0.f,0.f};
  f32x4 aK[4], aV[4];
  #pragma unroll
  for (int nt = 0; nt < 4; nt++){
    aK[nt] = __builtin_amdgcn_mfma_f32_16x16x32_bf16(a0, KB[nt],     zero,   0, 0, 0);
    aK[nt] = __builtin_amdgcn_mfma_f32_16x16x32_bf16(a1, KB[4 + nt], aK[nt], 0, 0, 0);
    aV[nt] = __builtin_amdgcn_mfma_f32_16x16x32_bf16(a0, VB[nt],     zero,   0, 0, 0);
    aV[nt] = __builtin_amdgcn_mfma_f32_16x16x32_bf16(a1, VB[4 + nt], aV[nt], 0, 0, 0);
  }
  #pragma unroll
  for (int nt = 0; nt < 4; nt++){
    float bkv = bk[nt*16 + cr], bvv = bvp[nt*16 + cr];
    #pragma unroll
    for (int reg = 0; reg < 4; reg++){
      size_t base = ((size_t)b*4096 + d0 + q*4 + reg)*64 + nt*16 + cr;
      K[base] = bf16bits(aK[nt][reg] + bkv);
      V[base] = bf16bits(aV[nt][reg] + bvv);
    }
  }
}

// ---------------- fused attention: K logits + softmax + frames + V reduce --
// mode 0 (iters 0-2): att stays in LDS; V path accumulates U1=sum att*relu(h)
//   and U2=sum relu(h) into upd[112][128] (normalization deferred to k_gru).
// mode 1 (iter 3): write att to global, skip V.
__global__ __launch_bounds__(256) void k_attn(const unsigned short* __restrict__ encK,
     const unsigned short* __restrict__ encV,
     const unsigned short* __restrict__ w1pack, const float* __restrict__ mlp1b,
     const float* __restrict__ absc, const float* __restrict__ qg_,
     const float* __restrict__ qb_, const float* __restrict__ w2qc,
     float* __restrict__ attOut, float* __restrict__ accF,
     float* __restrict__ upd, int mode){
  int bi = blockIdx.x;                 // 1024 = 16 b * 64 tiles
  int b = bi >> 6, tile = bi & 63;
  int t = threadIdx.x; int wv = t >> 6; int l = t & 63;
  int q = l >> 4, cr = l & 15;
  int m0 = tile*64 + wv*16;
  int drow = m0 + cr;

  __shared__ float s_log[7*64];
  __shared__ float s_absc[7*192];
  __shared__ float s_wq[7*68];
  __shared__ float s_upd[7*128];
  __shared__ unsigned short s_w1[4096];
  for (int i = t; i < 1344; i += 256) s_absc[i] = absc[b*7*192 + i];
  for (int i = t; i < 476;  i += 256) s_wq[i]   = w2qc[b*7*68 + i];
  if (mode == 0)
    for (int i = t; i < 896; i += 256) s_upd[i] = 0.f;
  {
    const uint4* g = reinterpret_cast<const uint4*>(w1pack);
    uint4* d = reinterpret_cast<uint4*>(s_w1);
    for (int i = t; i < 512; i += 256) d[i] = g[i];
  }

  const unsigned short* er = encK + (size_t)(b*4096 + drow)*64;
  float gx = -0.5f + (float)(drow & 63) * (1.f/63.f);
  float gy = -0.5f + (float)((drow >> 6) & 63) * (1.f/63.f);
  float xb[16], gq[16], bq[16];
  {
    bf16x8 ea = *reinterpret_cast<const bf16x8*>(er + q*8);
    bf16x8 eb = *reinterpret_cast<const bf16x8*>(er + 32 + q*8);
    #pragma unroll
    for (int i = 0; i < 8; i++){ xb[i] = (float)ea[i]; xb[8+i] = (float)eb[i]; }
  }
  bf16x8 vb0, vb1;                     // encV row held bf16 until V loop
  if (mode == 0){
    const unsigned short* ev = encV + (size_t)(b*4096 + drow)*64;
    vb0 = *reinterpret_cast<const bf16x8*>(ev + q*8);
    vb1 = *reinterpret_cast<const bf16x8*>(ev + 32 + q*8);
  }
  #pragma unroll
  for (int h = 0; h < 2; h++){
    int fb = h ? (32 + q*8) : (q*8);
    const float4* g4 = reinterpret_cast<const float4*>(qg_ + fb);
    const float4* b4 = reinterpret_cast<const float4*>(qb_ + fb);
    #pragma unroll
    for (int p = 0; p < 2; p++){
      float4 gg = g4[p], bb = b4[p];
      int o = h*8 + p*4;
      gq[o+0]=gg.x; gq[o+1]=gg.y; gq[o+2]=gg.z; gq[o+3]=gg.w;
      bq[o+0]=bb.x; bq[o+1]=bb.y; bq[o+2]=bb.z; bq[o+3]=bb.w;
    }
  }
  float b1v[4];
  #pragma unroll
  for (int nt = 0; nt < 4; nt++) b1v[nt] = mlp1b[nt*16 + cr];
  __syncthreads();

  const bf16x8* wl = reinterpret_cast<const bf16x8*>(s_w1);
  f32x4 zero = {0.f, 0.f, 0.f, 0.f};

  // ---- K loop: logits for all 7 slots (slot-paired) ----
  for (int sp = 0; sp < 4; sp++){
    int s0 = sp*2;
    int np = (sp == 3) ? 1 : 2;
    int sB = (np == 2) ? s0 + 1 : s0;
    float x0[16], x1[16];
    float s1a = 0.f, s2a = 0.f, s1b = 0.f, s2b = 0.f;
    {
      const float* Ac = s_absc + s0*192;
      #pragma unroll
      for (int h = 0; h < 2; h++){
        int fb = h ? (32 + q*8) : (q*8);
        const float4* A4 = reinterpret_cast<const float4*>(Ac + fb);
        const float4* B4 = reinterpret_cast<const float4*>(Ac + 64 + fb);
        const float4* C4 = reinterpret_cast<const float4*>(Ac + 128 + fb);
        #pragma unroll
        for (int pp = 0; pp < 2; pp++){
          float4 Av = A4[pp], Bv = B4[pp], Cv = C4[pp];
          int o = h*8 + pp*4;
          x0[o+0] = xb[o+0] + gx*Av.x + gy*Bv.x + Cv.x;
          x0[o+1] = xb[o+1] + gx*Av.y + gy*Bv.y + Cv.y;
          x0[o+2] = xb[o+2] + gx*Av.z + gy*Bv.z + Cv.z;
          x0[o+3] = xb[o+3] + gx*Av.w + gy*Bv.w + Cv.w;
        }
      }
      #pragma unroll
      for (int k = 0; k < 16; k++){ s1a += x0[k]; s2a = fmaf(x0[k], x0[k], s2a); }
    }
    {
      const float* Ac = s_absc + sB*192;
      #pragma unroll
      for (int h = 0; h < 2; h++){
        int fb = h ? (32 + q*8) : (q*8);
        const float4* A4 = reinterpret_cast<const float4*>(Ac + fb);
        const float4* B4 = reinterpret_cast<const float4*>(Ac + 64 + fb);
        const float4* C4 = reinterpret_cast<const float4*>(Ac + 128 + fb);
        #pragma unroll
        for (int pp = 0; pp < 2; pp++){
          float4 Av = A4[pp], Bv = B4[pp], Cv = C4[pp];
          int o = h*8 + pp*4;
          x1[o+0] = xb[o+0] + gx*Av.x + gy*Bv.x + Cv.x;
          x1[o+1] = xb[o+1] + gx*Av.y + gy*Bv.y + Cv.y;
          x1[o+2] = xb[o+2] + gx*Av.z + gy*Bv.z + Cv.z;
          x1[o+3] = xb[o+3] + gx*Av.w + gy*Bv.w + Cv.w;
        }
      }
      #pragma unroll
      for (int k = 0; k < 16; k++){ s1b += x1[k]; s2b = fmaf(x1[k], x1[k], s2b); }
    }
    s1a += __shfl_xor(s1a, 16, 64); s2a += __shfl_xor(s2a, 16, 64);
    s1b += __shfl_xor(s1b, 16, 64); s2b += __shfl_xor(s2b, 16, 64);
    s1a += __shfl_xor(s1a, 32, 64); s2a += __shfl_xor(s2a, 32, 64);
    s1b += __shfl_xor(s1b, 32, 64); s2b += __shfl_xor(s2b, 32, 64);
    float mA = s1a*(1.f/64.f);
    float rA = 1.0f/sqrtf(s2a*(1.f/64.f) - mA*mA + 1e-5f);
    float mB = s1b*(1.f/64.f);
    float rB = 1.0f/sqrtf(s2b*(1.f/64.f) - mB*mB + 1e-5f);

    bf16x8 a00, a01, a10, a11;
    #pragma unroll
    for (int k = 0; k < 8; k++){
      a00[k] = (__bf16)((x0[k]    - mA)*rA*gq[k]   + bq[k]);
      a01[k] = (__bf16)((x0[8+k]  - mA)*rA*gq[8+k] + bq[8+k]);
      a10[k] = (__bf16)((x1[k]    - mB)*rB*gq[k]   + bq[k]);
      a11[k] = (__bf16)((x1[8+k]  - mB)*rB*gq[8+k] + bq[8+k]);
    }

    f32x4 acc0[4], acc1[4];
    #pragma unroll
    for (int nt = 0; nt < 4; nt++){
      bf16x8 w0 = wl[nt*64 + l];
      bf16x8 w1f = wl[(4 + nt)*64 + l];
      acc0[nt] = __builtin_amdgcn_mfma_f32_16x16x32_bf16(a00, w0,  zero,     0, 0, 0);
      acc0[nt] = __builtin_amdgcn_mfma_f32_16x16x32_bf16(a01, w1f, acc0[nt], 0, 0, 0);
      acc1[nt] = __builtin_amdgcn_mfma_f32_16x16x32_bf16(a10, w0,  zero,     0, 0, 0);
      acc1[nt] = __builtin_amdgcn_mfma_f32_16x16x32_bf16(a11, w1f, acc1[nt], 0, 0, 0);
    }

    float p0[4] = {0.f,0.f,0.f,0.f}, p1[4] = {0.f,0.f,0.f,0.f};
    #pragma unroll
    for (int nt = 0; nt < 4; nt++){
      float wq0 = s_wq[s0*68 + nt*16 + cr];
      float wq1 = s_wq[sB*68 + nt*16 + cr];
      #pragma unroll
      for (int reg = 0; reg < 4; reg++){
        p0[reg] = fmaf(fmaxf(acc0[nt][reg] + b1v[nt], 0.f), wq0, p0[reg]);
        p1[reg] = fmaf(fmaxf(acc1[nt][reg] + b1v[nt], 0.f), wq1, p1[reg]);
      }
    }
    #pragma unroll
    for (int off = 1; off < 16; off <<= 1){
      #pragma unroll
      for (int reg = 0; reg < 4; reg++){
        p0[reg] += __shfl_xor(p0[reg], off, 64);
        p1[reg] += __shfl_xor(p1[reg], off, 64);
      }
    }
    if (cr == 0){
      float c20 = s_wq[s0*68 + 64];
      float c21 = s_wq[sB*68 + 64];
      #pragma unroll
      for (int reg = 0; reg < 4; reg++){
        s_log[s0*64 + wv*16 + q*4 + reg] = (p0[reg] + c20) * 0.125f;
        if (np == 2) s_log[sB*64 + wv*16 + q*4 + reg] = (p1[reg] + c21) * 0.125f;
      }
    }
  }
  __syncthreads();

  // softmax over slots (per d column); att stays in s_log
  if (t < 64){
    float lv[7];
    #pragma unroll
    for (int s = 0; s < 7; s++) lv[s] = s_log[s*64 + t];
    float mx = lv[0];
    #pragma unroll
    for (int s = 1; s < 7; s++) mx = fmaxf(mx, lv[s]);
    float sm = 0.f;
    #pragma unroll
    for (int s = 0; s < 7; s++){ lv[s] = expf(lv[s] - mx); sm += lv[s]; }
    float inv = 1.0f / sm;
    #pragma unroll
    for (int s = 0; s < 7; s++){
      float a = lv[s] * inv;
      s_log[s*64 + t] = a;
      if (mode == 1) attOut[(size_t)(b*7+s)*4096 + tile*64 + t] = a;
    }
  }
  __syncthreads();

  // frames partials: thread (s, r) covers columns r and r+32
  if (t < 224){
    int s = t >> 5, r = t & 31;
    float a1 = s_log[s*64 + r];
    float a2 = s_log[s*64 + r + 32];
    float gx1 = -0.5f + (float)r * (1.f/63.f);
    float gx2 = -0.5f + (float)(r + 32) * (1.f/63.f);
    float gyc = -0.5f + (float)tile * (1.f/63.f);
    float gy2c = gyc*gyc;
    float w0 = a1 + a2;
    float w1 = a1*gx1 + a2*gx2;
    float w2 = w0*gyc;
    float w3 = a1*(gx1*gx1 + gy2c) + a2*(gx2*gx2 + gy2c);
    #pragma unroll
    for (int m = 1; m < 32; m <<= 1){
      w0 += __shfl_xor(w0, m, 64);
      w1 += __shfl_xor(w1, m, 64);
      w2 += __shfl_xor(w2, m, 64);
      w3 += __shfl_xor(w3, m, 64);
    }
    if (r == 0){
      atomicAdd(&accF[(b*7+s)*4 + 0], w0);
      atomicAdd(&accF[(b*7+s)*4 + 1], w1);
      atomicAdd(&accF[(b*7+s)*4 + 2], w2);
      atomicAdd(&accF[(b*7+s)*4 + 3], w3);
    }
  }

  // ---- V loop: weighted reduce into s_upd (U1, U2) ----
  if (mode == 0){
    float xbv[16];
    #pragma unroll
    for (int i = 0; i < 8; i++){ xbv[i] = (float)vb0[i]; xbv[8+i] = (float)vb1[i]; }
    for (int sp = 0; sp < 4; sp++){
      int s0 = sp*2;
      int np = (sp == 3) ? 1 : 2;
      int sB = (np == 2) ? s0 + 1 : s0;
      float x0[16], x1[16];
      float s1a = 0.f, s2a = 0.f, s1b = 0.f, s2b = 0.f;
      {
        const float* Ac = s_absc + s0*192;
        #pragma unroll
        for (int h = 0; h < 2; h++){
          int fb = h ? (32 + q*8) : (q*8);
          const float4* A4 = reinterpret_cast<const float4*>(Ac + fb);
          const float4* B4 = reinterpret_cast<const float4*>(Ac + 64 + fb);
          const float4* C4 = reinterpret_cast<const float4*>(Ac + 128 + fb);
          #pragma unroll
          for (int pp = 0; pp < 2; pp++){
            float4 Av = A4[pp], Bv = B4[pp], Cv = C4[pp];
            int o = h*8 + pp*4;
            x0[o+0] = xbv[o+0] + gx*Av.x + gy*Bv.x + Cv.x;
            x0[o+1] = xbv[o+1] + gx*Av.y + gy*Bv.y + Cv.y;
            x0[o+2] = xbv[o+2] + gx*Av.z + gy*Bv.z + Cv.z;
            x0[o+3] = xbv[o+3] + gx*Av.w + gy*Bv.w + Cv.w;
          }
        }
        #pragma unroll
        for (int k = 0; k < 16; k++){ s1a += x0[k]; s2a = fmaf(x0[k], x0[k], s2a); }
      }
      {
        const float* Ac = s_absc + sB*192;
        #pragma unroll
        for (int h = 0; h < 2; h++){
          int fb = h ? (32 + q*8) : (q*8);
          const float4* A4 = reinterpret_cast<const float4*>(Ac + fb);
          const float4* B4 = reinterpret_cast<const float4*>(Ac + 64 + fb);
          const float4* C4 = reinterpret_cast<const float4*>(Ac + 128 + fb);
          #pragma unroll
          for (int pp = 0; pp < 2; pp++){
            float4 Av = A4[pp], Bv = B4[pp], Cv = C4[pp];
            int o = h*8 + pp*4;
            x1[o+0] = xbv[o+0] + gx*Av.x + gy*Bv.x + Cv.x;
            x1[o+1] = xbv[o+1] + gx*Av.y + gy*Bv.y + Cv.y;
            x1[o+2] = xbv[o+2] + gx*Av.z + gy*Bv.z + Cv.z;
            x1[o+3] = xbv[o+3] + gx*Av.w + gy*Bv.w + Cv.w;
          }
        }
        #pragma unroll
        for (int k = 0; k < 16; k++){ s1b += x1[k]; s2b = fmaf(x1[k], x1[k], s2b); }
      }
      s1a += __shfl_xor(s1a, 16, 64); s2a += __shfl_xor(s2a, 16, 64);
      s1b += __shfl_xor(s1b, 16, 64); s2b += __shfl_xor(s2b, 16, 64);
      s1a += __shfl_xor(s1a, 32, 64); s2a += __shfl_xor(s2a, 32, 64);
      s1b += __shfl_xor(s1b, 32, 64); s2b += __shfl_xor(s2b, 32, 64);
      float mA = s1a*(1.f/64.f);
      float rA = 1.0f/sqrtf(s2a*(1.f/64.f) - mA*mA + 1e-5f);
      float mB = s1b*(1.f/64.f);
      float rB = 1.0f/sqrtf(s2b*(1.f/64.f) - mB*mB + 1e-5f);

      bf16x8 a00, a01, a10, a11;
      #pragma unroll
      for (int k = 0; k < 8; k++){
        a00[k] = (__bf16)((x0[k]    - mA)*rA*gq[k]   + bq[k]);
        a01[k] = (__bf16)((x0[8+k]  - mA)*rA*gq[8+k] + bq[8+k]);
        a10[k] = (__bf16)((x1[k]    - mB)*rB*gq[k]   + bq[k]);
        a11[k] = (__bf16)((x1[8+k]  - mB)*rB*gq[8+k] + bq[8+k]);
      }

      f32x4 acc0[4], acc1[4];
      #pragma unroll
      for (int nt = 0; nt < 4; nt++){
        bf16x8 w0 = wl[nt*64 + l];
        bf16x8 w1f = wl[(4 + nt)*64 + l];
        acc0[nt] = __builtin_amdgcn_mfma_f32_16x16x32_bf16(a00, w0,  zero,     0, 0, 0);
        acc0[nt] = __builtin_amdgcn_mfma_f32_16x16x32_bf16(a01, w1f, acc0[nt], 0, 0, 0);
        acc1[nt] = __builtin_amdgcn_mfma_f32_16x16x32_bf16(a10, w0,  zero,     0, 0, 0);
        acc1[nt] = __builtin_amdgcn_mfma_f32_16x16x32_bf16(a11, w1f, acc1[nt], 0, 0, 0);
      }

      float wr0[4], wr1[4];
      #pragma unroll
      for (int reg = 0; reg < 4; reg++){
        wr0[reg] = s_log[s0*64 + wv*16 + q*4 + reg];
        wr1[reg] = s_log[sB*64 + wv*16 + q*4 + reg];
      }
      float pa0[4], pa1[4], pu0[4], pu1[4];
      #pragma unroll
      for (int nt = 0; nt < 4; nt++){
        pa0[nt] = 0.f; pa1[nt] = 0.f; pu0[nt] = 0.f; pu1[nt] = 0.f;
        #pragma unroll
        for (int reg = 0; reg < 4; reg++){
          float v0 = fmaxf(acc0[nt][reg] + b1v[nt], 0.f);
          float v1 = fmaxf(acc1[nt][reg] + b1v[nt], 0.f);
          pa0[nt] = fmaf(wr0[reg], v0, pa0[nt]); pu0[nt] += v0;
          pa1[nt] = fmaf(wr1[reg], v1, pa1[nt]); pu1[nt] += v1;
        }
      }
      #pragma unroll
      for (int nt = 0; nt < 4; nt++){
        pa0[nt] += __shfl_xor(pa0[nt], 16, 64); pa0[nt] += __shfl_xor(pa0[nt], 32, 64);
        pu0[nt] += __shfl_xor(pu0[nt], 16, 64); pu0[nt] += __shfl_xor(pu0[nt], 32, 64);
        pa1[nt] += __shfl_xor(pa1[nt], 16, 64); pa1[nt] += __shfl_xor(pa1[nt], 32, 64);
        pu1[nt] += __shfl_xor(pu1[nt], 16, 64); pu1[nt] += __shfl_xor(pu1[nt], 32, 64);
      }
      if (q == 0){
        #pragma unroll
        for (int nt = 0; nt < 4; nt++){
          atomicAdd(&s_upd[s0*128 + nt*16 + cr], pa0[nt]);
          atomicAdd(&s_upd[s0*128 + 64 + nt*16 + cr], pu0[nt]);
          if (np == 2){
            atomicAdd(&s_upd[sB*128 + nt*16 + cr], pa1[nt]);
            atomicAdd(&s_upd[sB*128 + 64 + nt*16 + cr], pu1[nt]);
          }
        }
      }
    }
    __syncthreads();
    for (int i = t; i < 896; i += 256)
      atomicAdd(&upd[b*896 + i], s_upd[i]);
  }
}

// ---------------- GRU cell + frames finalize + next-phase prep -------------
__global__ void k_gru(float* __restrict__ upd, float* __restrict__ queries,
                      const float* __restrict__ wih, const float* __restrict__ whh,
                      const float* __restrict__ bih, const float* __restrict__ bhh,
                      const float* __restrict__ mlp2w, const float* __restrict__ mlp2b,
                      float* __restrict__ accF, float* __restrict__ ps,
                      const float* __restrict__ qg_, const float* __restrict__ qb_,
                      const float* __restrict__ dw, const float* __restrict__ db,
                      float* __restrict__ absc, float* __restrict__ w2qc){
  int row = blockIdx.x; int t = threadIdx.x;   // 112 x 192
  __shared__ float us[64], hs[64], xs[64], gis[192], ghs[192];
  __shared__ float s_ps3[3];
  if (t < 64){
    float isa0 = 1.0f/accF[row*4];
    us[t] = upd[row*128 + t]*isa0 + 1e-8f*upd[row*128 + 64 + t];
    hs[t] = queries[row*64 + t];
  }
  if (t == 64){
    float sa = accF[row*4+0];
    float ax = accF[row*4+1], ay = accF[row*4+2], ar2 = accF[row*4+3];
    float isa = 1.0f/sa;
    float Wx = ax*isa, Wy = ay*isa;
    float Wg = ar2*isa + 1e-8f*SR2;
    float s2 = Wg - (Wx*Wx + Wy*Wy)*(2.f - W0CONST);
    s_ps3[0] = Wx; s_ps3[1] = Wy; s_ps3[2] = sqrtf(fmaxf(s2, 0.f));
  }
  __syncthreads();
  if (t < 64){
    float a = W0CONST * mlp2b[t];
    for (int i = 0; i < 64; i++) a = fmaf(us[i], mlp2w[i*64 + t], a);
    xs[t] = a;
  }
  __syncthreads();
  float gi = bih[t], gh = bhh[t];
  for (int e = 0; e < 64; e++){
    gi = fmaf(wih[t*64 + e], xs[e], gi);
    gh = fmaf(whh[t*64 + e], hs[e], gh);
  }
  gis[t] = gi; ghs[t] = gh;
  __syncthreads();
  if (t < 64){
    float r = 1.0f/(1.0f + expf(-(gis[t]      + ghs[t])));
    float z = 1.0f/(1.0f + expf(-(gis[64+t]   + ghs[64+t])));
    float n = tanhf(gis[128+t] + r*ghs[128+t]);
    float newq = (1.0f - z)*n + z*hs[t];
    queries[row*64 + t] = newq;
    upd[row*128 + t] = 0.f;
    upd[row*128 + 64 + t] = 0.f;
    if (t < 4) accF[row*4 + t] = 0.f;
    if (t < 3) ps[row*3 + t] = s_ps3[t];
    pp_core(row, t, newq, s_ps3[0], s_ps3[1], s_ps3[2],
            qg_, qb_, dw, db, mlp2w, mlp2b, absc, w2qc);
  }
}

// ---------------- heads: alpha, slot_feat(+frames), copy queries -----------
__global__ void k_final(const float* __restrict__ queries, const float* __restrict__ accF,
                        const float* __restrict__ a1w, const float* __restrict__ a1b,
                        const float* __restrict__ a2w, const float* __restrict__ a2b,
                        const float* __restrict__ f1w, const float* __restrict__ f1b,
                        const float* __restrict__ f2w, const float* __restrict__ f2b,
                        float* __restrict__ out){
  int bs = blockIdx.x; int e = threadIdx.x;    // 112 x 64
  __shared__ float qs[64], hf[64], ha[32];
  float q = queries[bs*64 + e];
  qs[e] = q;
  out[bs*64 + e] = q;
  __syncthreads();
  float accf = f1b[e];
  for (int i = 0; i < 64; i++) accf = fmaf(qs[i], f1w[i*64 + e], accf);
  hf[e] = fmaxf(accf, 0.f);
  if (e < 32){
    float acca = a1b[e];
    for (int i = 0; i < 64; i++) acca = fmaf(qs[i], a1w[i*32 + e], acca);
    ha[e] = fmaxf(acca, 0.f);
  }
  __syncthreads();
  if (e < 3){
    float sf = f2b[e];
    for (int o = 0; o < 64; o++) sf = fmaf(hf[o], f2w[o*3 + e], sf);
    float sa = accF[bs*4+0], ax = accF[bs*4+1], ay = accF[bs*4+2], ar2 = accF[bs*4+3];
    float isa = 1.0f/sa;
    float Wx = ax*isa, Wy = ay*isa;
    float Wg = ar2*isa + 1e-8f*SR2;
    float s2 = Wg - (Wx*Wx + Wy*Wy)*(2.f - W0CONST);
    float nv = (e == 0) ? Wx : ((e == 1) ? Wy : sqrtf(fmaxf(s2, 0.f)));
    out[465920 + bs*3 + e] = sf + nv;
  }
  if (e == 32){
    float al = a2b[0];
    for (int o = 0; o < 32; o++) al = fmaf(ha[o], a2w[o], al);
    out[466256 + bs] = 1.0f/(1.0f + expf(-al));
  }
}

// ---------------------------------------------------------------------------
extern "C" void kernel_launch(void* const* d_in, const int* in_sizes, int n_in,
                              void* d_out, int out_size, void* d_ws, size_t ws_size,
                              hipStream_t stream){
  const float* data        = (const float*)d_in[0];
  const float* slot_noise  = (const float*)d_in[1];
  const float* pos_rand    = (const float*)d_in[2];
  const float* conv0_w     = (const float*)d_in[3];
  const float* conv0_b     = (const float*)d_in[4];
  const float* conv1_w     = (const float*)d_in[5];
  const float* conv1_b     = (const float*)d_in[6];
  const float* conv2_w     = (const float*)d_in[7];
  const float* conv2_b     = (const float*)d_in[8];
  const float* dataN_g     = (const float*)d_in[9];
  const float* dataN_b     = (const float*)d_in[10];
  const float* queryN_g    = (const float*)d_in[11];
  const float* queryN_b    = (const float*)d_in[12];
  const float* toK_w       = (const float*)d_in[13];
  const float* toK_b       = (const float*)d_in[14];
  const float* toV_w       = (const float*)d_in[15];
  const float* toV_b       = (const float*)d_in[16];
  const float* dense_w     = (const float*)d_in[17];
  const float* dense_b     = (const float*)d_in[18];
  const float* mlp1_w      = (const float*)d_in[19];
  const float* mlp1_b      = (const float*)d_in[20];
  const float* mlp2_w      = (const float*)d_in[21];
  const float* mlp2_b      = (const float*)d_in[22];
  const float* gru_wih     = (const float*)d_in[23];
  const float* gru_whh     = (const float*)d_in[24];
  const float* gru_bih     = (const float*)d_in[25];
  const float* gru_bhh     = (const float*)d_in[26];
  const float* alpha1_w    = (const float*)d_in[27];
  const float* alpha1_b    = (const float*)d_in[28];
  const float* alpha2_w    = (const float*)d_in[29];
  const float* alpha2_b    = (const float*)d_in[30];
  const float* final1_w    = (const float*)d_in[31];
  const float* final1_b    = (const float*)d_in[32];
  const float* final2_w    = (const float*)d_in[33];
  const float* final2_b    = (const float*)d_in[34];
  const float* slots_mu    = (const float*)d_in[35];
  const float* slots_lsig  = (const float*)d_in[36];

  float* ws   = (float*)d_ws;
  float* bufA = ws;                    // c0_bf (bf16) then encK (bf16)
  float* bufB = bufA + 4194304;        // enc bf16
  float* bufC = bufB + 4194304;        // c1_bf (bf16) then encV (bf16)
  float* queries = bufC + 4194304;     // 7,168
  float* ps   = queries + 7168;        // 512 ([112][3], 336 used)
  float* absc = ps + 512;              // 21,504 (A/B/cc per (b,s))
  float* accF = absc + 21504;          // 512 ([112][4]: sa, ax, ay, ar2)
  float* upd  = accF + 512;            // 14,336 ([112][128]: U1 | U2)
  float* w2qc = upd + 14336;           // 7,616 ([112][68])
  unsigned short* w1pack = (unsigned short*)(w2qc + 7616);   // 4096 bf16
  unsigned short* kpack  = w1pack + 4096;                    // 4096
  unsigned short* vpack  = kpack + 4096;                     // 4096
  unsigned short* wp1    = vpack + 4096;                     // 102,400
  unsigned short* wp2    = wp1 + 102400;                     // 102,400

  unsigned short* c0_bf = (unsigned short*)bufA;   // conv0 out, NHWC bf16
  unsigned short* c1_bf = (unsigned short*)bufC;   // conv1 out, NHWC bf16
  unsigned short* enc   = (unsigned short*)bufB;   // LN(conv2) bf16
  unsigned short* encK  = (unsigned short*)bufA;   // overwrites c0_bf (done)
  unsigned short* encV  = (unsigned short*)bufC;   // overwrites c1_bf (done)

  float* outq   = (float*)d_out;       // queries [7168]
  float* outatt = outq + 7168;         // att [458752]

  k_packall<<<960, 256, 0, stream>>>(mlp1_w, toK_w, toV_w, conv1_w, conv2_w,
                                     w1pack, kpack, vpack, wp1, wp2,
                                     slot_noise, pos_rand, slots_mu, slots_lsig,
                                     queryN_g, queryN_b, dense_w, dense_b, mlp2_w, mlp2_b,
                                     queries, ps, absc, w2qc, accF, upd);
  k_conv0<<<1024, 256, 0, stream>>>(data, conv0_w, conv0_b, c0_bf);
  k_convm<<<512, 256, 0, stream>>>(c0_bf, wp1, conv1_b, nullptr, nullptr, c1_bf, 0);
  k_convm<<<512, 256, 0, stream>>>(c1_bf, wp2, conv2_b, dataN_g, dataN_b, enc, 1);
  k_projm<<<1024, 256, 0, stream>>>(enc, kpack, toK_b, vpack, toV_b, encK, encV);

  for (int p = 0; p < 4; p++){
    k_attn<<<1024, 256, 0, stream>>>(encK, encV, w1pack, mlp1_b, absc,
                                     queryN_g, queryN_b, w2qc, outatt, accF, upd,
                                     (p < 3) ? 0 : 1);
    if (p < 3){
      k_gru<<<112, 192, 0, stream>>>(upd, queries, gru_wih, gru_whh, gru_bih, gru_bhh,
                                     mlp2_w, mlp2_b, accF, ps, queryN_g, queryN_b,
                                     dense_w, dense_b, absc, w2qc);
    }
  }
  k_final<<<112, 64, 0, stream>>>(queries, accF,
                                  alpha1_w, alpha1_b, alpha2_w, alpha2_b,
                                  final1_w, final1_b, final2_w, final2_b, outq);
}

// Round 9
// 480.370 us; speedup vs baseline: 1.6512x; 1.0036x over previous
//
#include <hip/hip_runtime.h>
#include <cmath>

// ---------------------------------------------------------------------------
// InvariantSlotAttention forward. R24 = R23 champion (482us) + low-risk
// micro-opts off the k_attn path: (a) k_packall+k_conv0 merged into one
// 1984-block launch (independent work; saves one serialized launch+gap);
// (b) k_gru / pp_core serial dots rewritten with float4 weight loads and
// 4-way split accumulators (dependent chains 64 -> 16). k_attn untouched
// (verified local optimum; R17-R22 structural variants all failed/regressed).
// B=16, S=7, E=HID=64, D=4096, N_ITER=3, TSOFT=0.125
// ---------------------------------------------------------------------------

#define RLOW_F 0.1f
#define RHIGH_F 0.22360679774997896f
#define W0CONST 1.00004096f      /* sum_d wts = 1 + 4096e-8 exactly */
#define SR2 704.3386243f         /* sum_d (gx^2+gy^2) */

typedef __attribute__((ext_vector_type(8))) __bf16 bf16x8;
typedef __attribute__((ext_vector_type(4))) float f32x4;

__device__ __forceinline__ float wsum64(float v){
  #pragma unroll
  for (int off = 32; off > 0; off >>= 1) v += __shfl_xor(v, off, 64);
  return v;
}
__device__ __forceinline__ float rdlane(float v, int l){
  return __int_as_float(__builtin_amdgcn_readlane(__float_as_int(v), l));
}
__device__ __forceinline__ unsigned short bf16bits(float v){
  __bf16 h = (__bf16)v;
  return *reinterpret_cast<unsigned short*>(&h);
}

// ---- phase prep core: one full wave (lanes 0..63), e = lane ---------------
// float4 weight loads + 4-way split accumulators (chain 64 -> 16).
__device__ __forceinline__ void pp_core(int row, int e, float qv,
    float px, float py, float sc,
    const float* __restrict__ qg_, const float* __restrict__ qb_,
    const float* __restrict__ dw, const float* __restrict__ db,
    const float* __restrict__ mlp2w, const float* __restrict__ mlp2b,
    float* __restrict__ absc, float* __restrict__ w2qc){
  float m = wsum64(qv) * (1.f/64.f);
  float d = qv - m;
  float var = wsum64(d*d) * (1.f/64.f);
  float qlnv = d * (1.0f/sqrtf(var + 1e-5f)) * qg_[e] + qb_[e];
  float A  = dw[e]      / sc;
  float Bv = dw[64 + e] / sc;
  absc[row*192 + e]       = A;
  absc[row*192 + 64 + e]  = Bv;
  absc[row*192 + 128 + e] = db[e] - px*A - py*Bv;
  float a0 = 0.f, a1 = 0.f, a2 = 0.f, a3 = 0.f;
  const float4* wr4 = reinterpret_cast<const float4*>(mlp2w + e*64);
  for (int j = 0; j < 16; j++){
    float4 w4 = wr4[j];
    a0 = fmaf(w4.x, rdlane(qlnv, 4*j + 0), a0);
    a1 = fmaf(w4.y, rdlane(qlnv, 4*j + 1), a1);
    a2 = fmaf(w4.z, rdlane(qlnv, 4*j + 2), a2);
    a3 = fmaf(w4.w, rdlane(qlnv, 4*j + 3), a3);
  }
  w2qc[row*68 + e] = (a0 + a1) + (a2 + a3);
  float c2 = wsum64(mlp2b[e] * qlnv);
  if (e == 0) w2qc[row*68 + 64] = c2;
}

// ---------------- merged front: packing + phase-0 prep + conv0 -------------
// blocks 0-15: w1pack; 16-31: kpack; 32-47: vpack; 48-447: wp1; 448-847: wp2;
// 848-959: prep; 960-1983: conv0 (bi-960 = b*64 + y).
__global__ __launch_bounds__(256) void k_front(const float* __restrict__ mlp1_w,
                          const float* __restrict__ toK_w,
                          const float* __restrict__ toV_w, const float* __restrict__ conv1_w,
                          const float* __restrict__ conv2_w,
                          unsigned short* __restrict__ w1pack, unsigned short* __restrict__ kpack,
                          unsigned short* __restrict__ vpack, unsigned short* __restrict__ wp1,
                          unsigned short* __restrict__ wp2,
                          const float* __restrict__ noise, const float* __restrict__ prand,
                          const float* __restrict__ mu, const float* __restrict__ logsig,
                          const float* __restrict__ qg_, const float* __restrict__ qb_,
                          const float* __restrict__ dw, const float* __restrict__ db,
                          const float* __restrict__ mlp2w, const float* __restrict__ mlp2b,
                          float* __restrict__ queries, float* __restrict__ ps,
                          float* __restrict__ absc, float* __restrict__ w2qc,
                          float* __restrict__ accF, float* __restrict__ upd,
                          const float* __restrict__ cin, const float* __restrict__ c0w,
                          const float* __restrict__ c0b, unsigned short* __restrict__ c0out){
  int bi = blockIdx.x; int t = threadIdx.x;
  __shared__ float s_in[5*68];
  __shared__ float s_w[64*25];
  __shared__ float s_out[64*65];
  if (bi < 48){
    const float* src = (bi < 16) ? mlp1_w : ((bi < 32) ? toK_w : toV_w);
    unsigned short* dst = (bi < 16) ? w1pack : ((bi < 32) ? kpack : vpack);
    int idx = (bi & 15)*256 + t;
    int jj = idx & 7;
    int lane = (idx >> 3) & 63;
    int frag = idx >> 9;
    int ks = frag >> 2, nt = frag & 3;
    int q = lane >> 4, cr = lane & 15;
    int k = ks*32 + q*8 + jj;
    int n = nt*16 + cr;
    dst[idx] = bf16bits(src[k*64 + n]);
  } else if (bi < 848){
    int rb = bi - 48;
    const float* src = (rb < 400) ? conv1_w : conv2_w;
    unsigned short* dst = (rb < 400) ? wp1 : wp2;
    int idx = (rb % 400)*256 + t;
    int j = idx & 7;
    int l = (idx >> 3) & 63;
    int frag = idx >> 9;
    int nt = frag & 3;
    int ks = (frag >> 2) % 10;
    int dy = frag / 40;
    int q = l >> 4, cr = l & 15;
    int k = ks*32 + q*8 + j;
    int kx = k >> 6, ch = k & 63;
    int n = nt*16 + cr;
    dst[idx] = bf16bits(src[((n*64 + ch)*5 + dy)*5 + kx]);
  } else if (bi < 960){
    if (t >= 64) return;
    int row = bi - 848;           // 112 rows
    int e = t;
    int s = row % 7;
    float qv = mu[e] + expf(logsig[e]) * noise[row*64 + e];
    queries[row*64 + e] = qv;
    upd[row*128 + e] = 0.f;
    upd[row*128 + 64 + e] = 0.f;
    if (e < 4) accF[row*4 + e] = 0.f;
    float pv = 0.f;
    if (e < 3){
      float pr = prand[row*3 + e];
      if (s < 2)       pv = pr - 0.5f;
      else if (s == 6) pv = (RLOW_F - RHIGH_F)*pr + RHIGH_F;
      else             pv = pr;
      ps[row*3 + e] = pv;
    }
    float px = rdlane(pv, 0), py = rdlane(pv, 1), sc = rdlane(pv, 2);
    pp_core(row, e, qv, px, py, sc, qg_, qb_, dw, db, mlp2w, mlp2b, absc, w2qc);
  } else {
    // ---- conv0: 1->64 channels, 5x5 same, relu, NHWC bf16 out ----
    int ci = bi - 960; int b = ci >> 6; int y = ci & 63;
    int lane = t & 63; int xg = t >> 6;
    for (int i = t; i < 1600; i += 256) s_w[i] = c0w[i];
    for (int i = t; i < 340; i += 256){
      int r = i / 68, cx = i % 68;
      int yy = y + r - 2, gx = cx - 2;
      float v = 0.f;
      if (yy >= 0 && yy < 64 && gx >= 0 && gx < 64) v = cin[(b*64 + yy)*64 + gx];
      s_in[r*68 + cx] = v;
    }
    __syncthreads();
    int o = lane;
    float bvv = c0b[o];
    float acc[16];
    #pragma unroll
    for (int k = 0; k < 16; k++) acc[k] = bvv;
    #pragma unroll
    for (int ky = 0; ky < 5; ky++){
      float rv[20];
      const float4* p = reinterpret_cast<const float4*>(&s_in[ky*68 + xg*16]);
      #pragma unroll
      for (int q = 0; q < 5; q++){ float4 f = p[q]; rv[q*4]=f.x; rv[q*4+1]=f.y; rv[q*4+2]=f.z; rv[q*4+3]=f.w; }
      #pragma unroll
      for (int kx = 0; kx < 5; kx++){
        float wv = s_w[o*25 + ky*5 + kx];
        #pragma unroll
        for (int k = 0; k < 16; k++) acc[k] = fmaf(rv[k+kx], wv, acc[k]);
      }
    }
    #pragma unroll
    for (int k = 0; k < 16; k++) s_out[o*65 + xg*16 + k] = fmaxf(acc[k], 0.f);
    __syncthreads();
    for (int i = t; i < 4096; i += 256){
      int px = i >> 6, ch = i & 63;
      c0out[((size_t)(b*64 + y)*64 + px)*64 + ch] = bf16bits(s_out[ch*65 + px]);
    }
  }
}

// ---------------- conv1/conv2 bf16 MFMA implicit GEMM (512 blocks) ---------
__global__ __launch_bounds__(256) void k_convm(const unsigned short* __restrict__ in_bf,
                        const unsigned short* __restrict__ wpack,
                        const float* __restrict__ bias,
                        const float* __restrict__ lng, const float* __restrict__ lnb,
                        unsigned short* __restrict__ out_bf, int mode){
  int bi = blockIdx.x;                  // 512 = 16 b * 16 yg * 2 xh
  int b = bi >> 5; int yg = (bi >> 1) & 15; int xh = bi & 1;
  int t = threadIdx.x; int wv = t >> 6; int l = t & 63;
  int q = l >> 4, cr = l & 15;
  int yr = wv >> 1, ph = wv & 1;
  int p0 = ph*16;

  __shared__ char lds[8*36*144];

  for (int ri = 0; ri < 8; ri++){
    int yy = yg*4 + ri - 2;
    bool rok = (yy >= 0 && yy < 64);
    const uint4* src = reinterpret_cast<const uint4*>(in_bf + (size_t)(b*64 + yy)*64*64);
    for (int i = t; i < 288; i += 256){
      int px = i >> 3, c8 = i & 7;
      uint4 v = {0u,0u,0u,0u};
      int gx = xh*32 + px - 2;
      if (rok && gx >= 0 && gx < 64) v = src[gx*8 + c8];
      *reinterpret_cast<uint4*>(&lds[ri*5184 + px*144 + c8*16]) = v;
    }
  }
  __syncthreads();

  f32x4 acc[2][4];
  #pragma unroll
  for (int r = 0; r < 2; r++)
    #pragma unroll
    for (int nt = 0; nt < 4; nt++) acc[r][nt] = (f32x4){0.f,0.f,0.f,0.f};

  const bf16x8* wp = reinterpret_cast<const bf16x8*>(wpack);
  for (int dy = 0; dy < 5; dy++){
    for (int ks = 0; ks < 10; ks++){
      bf16x8 Bf[4];
      int fbase = (dy*10 + ks)*4;
      #pragma unroll
      for (int nt = 0; nt < 4; nt++) Bf[nt] = wp[(fbase + nt)*64 + l];
      int aoff = (p0 + cr + (ks >> 1))*144 + (ks & 1)*64 + q*16;
      #pragma unroll
      for (int r = 0; r < 2; r++){
        int ri = yr*2 + r + dy;
        bf16x8 a = *reinterpret_cast<const bf16x8*>(&lds[ri*5184 + aoff]);
        #pragma unroll
        for (int nt = 0; nt < 4; nt++)
          acc[r][nt] = __builtin_amdgcn_mfma_f32_16x16x32_bf16(a, Bf[nt], acc[r][nt], 0, 0, 0);
      }
    }
  }

  float bvv[4];
  #pragma unroll
  for (int nt = 0; nt < 4; nt++) bvv[nt] = bias[nt*16 + cr];

  if (mode == 0){
    #pragma unroll
    for (int r = 0; r < 2; r++){
      int y = yg*4 + yr*2 + r;
      #pragma unroll
      for (int reg = 0; reg < 4; reg++){
        int p = xh*32 + p0 + q*4 + reg;
        size_t base = ((size_t)(b*64 + y)*64 + p)*64;
        #pragma unroll
        for (int nt = 0; nt < 4; nt++)
          out_bf[base + nt*16 + cr] = bf16bits(fmaxf(acc[r][nt][reg] + bvv[nt], 0.f));
      }
    }
  } else {
    float gv[4], bb[4];
    #pragma unroll
    for (int nt = 0; nt < 4; nt++){ gv[nt] = lng[nt*16 + cr]; bb[nt] = lnb[nt*16 + cr]; }
    #pragma unroll
    for (int r = 0; r < 2; r++){
      int y = yg*4 + yr*2 + r;
      #pragma unroll
      for (int reg = 0; reg < 4; reg++){
        int p = xh*32 + p0 + q*4 + reg;
        float v[4]; float s1 = 0.f, s2 = 0.f;
        #pragma unroll
        for (int nt = 0; nt < 4; nt++){
          v[nt] = fmaxf(acc[r][nt][reg] + bvv[nt], 0.f);
          s1 += v[nt]; s2 += v[nt]*v[nt];
        }
        #pragma unroll
        for (int m = 1; m < 16; m <<= 1){ s1 += __shfl_xor(s1, m, 64); s2 += __shfl_xor(s2, m, 64); }
        float mean = s1 * (1.f/64.f);
        float var  = s2 * (1.f/64.f) - mean*mean;
        float rstd = 1.0f/sqrtf(var + 1e-5f);
        size_t base = ((size_t)b*4096 + y*64 + p)*64;
        #pragma unroll
        for (int nt = 0; nt < 4; nt++)
          out_bf[base + nt*16 + cr] = bf16bits((v[nt] - mean)*rstd*gv[nt] + bb[nt]);
      }
    }
  }
}

// ---------------- K/V projection: enc(bf16) @ toK_w, toV_w -> bf16 ---------
__global__ __launch_bounds__(256) void k_projm(const unsigned short* __restrict__ enc,
                       const unsigned short* __restrict__ kpack, const float* __restrict__ bk,
                       const unsigned short* __restrict__ vpack, const float* __restrict__ bvp,
                       unsigned short* __restrict__ K, unsigned short* __restrict__ V){
  int bi = blockIdx.x; int b = bi >> 6; int tile = bi & 63;  // 1024 blocks
  int t = threadIdx.x; int wv = t >> 6; int l = t & 63;
  int q = l >> 4, cr = l & 15;
  int d0 = tile*64 + wv*16;

  const bf16x8* kp = reinterpret_cast<const bf16x8*>(kpack);
  const bf16x8* vp = reinterpret_cast<const bf16x8*>(vpack);
  bf16x8 KB[8], VB[8];
  #pragma unroll
  for (int f = 0; f < 8; f++){ KB[f] = kp[f*64 + l]; VB[f] = vp[f*64 + l]; }

  const unsigned short* er = enc + (size_t)(b*4096 + d0 + cr)*64;
  bf16x8 a0 = *reinterpret_cast<const bf16x8*>(er + q*8);
  bf16x8 a1 = *reinterpret_cast<const bf16x8*>(er + 32 + q*8);

  f32x4 zero = {0.f,0.f,0.f,0.f};
  f32x4 aK[4], aV[4];
  #pragma unroll
  for (int nt = 0; nt < 4; nt++){
    aK[nt] = __builtin_amdgcn_mfma_f32_16x16x32_bf16(a0, KB[nt],     zero,   0, 0, 0);
    aK[nt] = __builtin_amdgcn_mfma_f32_16x16x32_bf16(a1, KB[4 + nt], aK[nt], 0, 0, 0);
    aV[nt] = __builtin_amdgcn_mfma_f32_16x16x32_bf16(a0, VB[nt],     zero,   0, 0, 0);
    aV[nt] = __builtin_amdgcn_mfma_f32_16x16x32_bf16(a1, VB[4 + nt], aV[nt], 0, 0, 0);
  }
  #pragma unroll
  for (int nt = 0; nt < 4; nt++){
    float bkv = bk[nt*16 + cr], bvv = bvp[nt*16 + cr];
    #pragma unroll
    for (int reg = 0; reg < 4; reg++){
      size_t base = ((size_t)b*4096 + d0 + q*4 + reg)*64 + nt*16 + cr;
      K[base] = bf16bits(aK[nt][reg] + bkv);
      V[base] = bf16bits(aV[nt][reg] + bvv);
    }
  }
}

// ---------------- fused attention: K logits + softmax + frames + V reduce --
// mode 0 (iters 0-2): att stays in LDS; V path accumulates U1=sum att*relu(h)
//   and U2=sum relu(h) into upd[112][128] (normalization deferred to k_gru).
// mode 1 (iter 3): write att to global, skip V.
__global__ __launch_bounds__(256) void k_attn(const unsigned short* __restrict__ encK,
     const unsigned short* __restrict__ encV,
     const unsigned short* __restrict__ w1pack, const float* __restrict__ mlp1b,
     const float* __restrict__ absc, const float* __restrict__ qg_,
     const float* __restrict__ qb_, const float* __restrict__ w2qc,
     float* __restrict__ attOut, float* __restrict__ accF,
     float* __restrict__ upd, int mode){
  int bi = blockIdx.x;                 // 1024 = 16 b * 64 tiles
  int b = bi >> 6, tile = bi & 63;
  int t = threadIdx.x; int wv = t >> 6; int l = t & 63;
  int q = l >> 4, cr = l & 15;
  int m0 = tile*64 + wv*16;
  int drow = m0 + cr;

  __shared__ float s_log[7*64];
  __shared__ float s_absc[7*192];
  __shared__ float s_wq[7*68];
  __shared__ float s_upd[7*128];
  __shared__ unsigned short s_w1[4096];
  for (int i = t; i < 1344; i += 256) s_absc[i] = absc[b*7*192 + i];
  for (int i = t; i < 476;  i += 256) s_wq[i]   = w2qc[b*7*68 + i];
  if (mode == 0)
    for (int i = t; i < 896; i += 256) s_upd[i] = 0.f;
  {
    const uint4* g = reinterpret_cast<const uint4*>(w1pack);
    uint4* d = reinterpret_cast<uint4*>(s_w1);
    for (int i = t; i < 512; i += 256) d[i] = g[i];
  }

  const unsigned short* er = encK + (size_t)(b*4096 + drow)*64;
  float gx = -0.5f + (float)(drow & 63) * (1.f/63.f);
  float gy = -0.5f + (float)((drow >> 6) & 63) * (1.f/63.f);
  float xb[16], gq[16], bq[16];
  {
    bf16x8 ea = *reinterpret_cast<const bf16x8*>(er + q*8);
    bf16x8 eb = *reinterpret_cast<const bf16x8*>(er + 32 + q*8);
    #pragma unroll
    for (int i = 0; i < 8; i++){ xb[i] = (float)ea[i]; xb[8+i] = (float)eb[i]; }
  }
  bf16x8 vb0, vb1;                     // encV row held bf16 until V loop
  if (mode == 0){
    const unsigned short* ev = encV + (size_t)(b*4096 + drow)*64;
    vb0 = *reinterpret_cast<const bf16x8*>(ev + q*8);
    vb1 = *reinterpret_cast<const bf16x8*>(ev + 32 + q*8);
  }
  #pragma unroll
  for (int h = 0; h < 2; h++){
    int fb = h ? (32 + q*8) : (q*8);
    const float4* g4 = reinterpret_cast<const float4*>(qg_ + fb);
    const float4* b4 = reinterpret_cast<const float4*>(qb_ + fb);
    #pragma unroll
    for (int p = 0; p < 2; p++){
      float4 gg = g4[p], bb = b4[p];
      int o = h*8 + p*4;
      gq[o+0]=gg.x; gq[o+1]=gg.y; gq[o+2]=gg.z; gq[o+3]=gg.w;
      bq[o+0]=bb.x; bq[o+1]=bb.y; bq[o+2]=bb.z; bq[o+3]=bb.w;
    }
  }
  float b1v[4];
  #pragma unroll
  for (int nt = 0; nt < 4; nt++) b1v[nt] = mlp1b[nt*16 + cr];
  __syncthreads();

  const bf16x8* wl = reinterpret_cast<const bf16x8*>(s_w1);
  f32x4 zero = {0.f, 0.f, 0.f, 0.f};

  // ---- K loop: logits for all 7 slots (slot-paired) ----
  for (int sp = 0; sp < 4; sp++){
    int s0 = sp*2;
    int np = (sp == 3) ? 1 : 2;
    int sB = (np == 2) ? s0 + 1 : s0;
    float x0[16], x1[16];
    float s1a = 0.f, s2a = 0.f, s1b = 0.f, s2b = 0.f;
    {
      const float* Ac = s_absc + s0*192;
      #pragma unroll
      for (int h = 0; h < 2; h++){
        int fb = h ? (32 + q*8) : (q*8);
        const float4* A4 = reinterpret_cast<const float4*>(Ac + fb);
        const float4* B4 = reinterpret_cast<const float4*>(Ac + 64 + fb);
        const float4* C4 = reinterpret_cast<const float4*>(Ac + 128 + fb);
        #pragma unroll
        for (int pp = 0; pp < 2; pp++){
          float4 Av = A4[pp], Bv = B4[pp], Cv = C4[pp];
          int o = h*8 + pp*4;
          x0[o+0] = xb[o+0] + gx*Av.x + gy*Bv.x + Cv.x;
          x0[o+1] = xb[o+1] + gx*Av.y + gy*Bv.y + Cv.y;
          x0[o+2] = xb[o+2] + gx*Av.z + gy*Bv.z + Cv.z;
          x0[o+3] = xb[o+3] + gx*Av.w + gy*Bv.w + Cv.w;
        }
      }
      #pragma unroll
      for (int k = 0; k < 16; k++){ s1a += x0[k]; s2a = fmaf(x0[k], x0[k], s2a); }
    }
    {
      const float* Ac = s_absc + sB*192;
      #pragma unroll
      for (int h = 0; h < 2; h++){
        int fb = h ? (32 + q*8) : (q*8);
        const float4* A4 = reinterpret_cast<const float4*>(Ac + fb);
        const float4* B4 = reinterpret_cast<const float4*>(Ac + 64 + fb);
        const float4* C4 = reinterpret_cast<const float4*>(Ac + 128 + fb);
        #pragma unroll
        for (int pp = 0; pp < 2; pp++){
          float4 Av = A4[pp], Bv = B4[pp], Cv = C4[pp];
          int o = h*8 + pp*4;
          x1[o+0] = xb[o+0] + gx*Av.x + gy*Bv.x + Cv.x;
          x1[o+1] = xb[o+1] + gx*Av.y + gy*Bv.y + Cv.y;
          x1[o+2] = xb[o+2] + gx*Av.z + gy*Bv.z + Cv.z;
          x1[o+3] = xb[o+3] + gx*Av.w + gy*Bv.w + Cv.w;
        }
      }
      #pragma unroll
      for (int k = 0; k < 16; k++){ s1b += x1[k]; s2b = fmaf(x1[k], x1[k], s2b); }
    }
    s1a += __shfl_xor(s1a, 16, 64); s2a += __shfl_xor(s2a, 16, 64);
    s1b += __shfl_xor(s1b, 16, 64); s2b += __shfl_xor(s2b, 16, 64);
    s1a += __shfl_xor(s1a, 32, 64); s2a += __shfl_xor(s2a, 32, 64);
    s1b += __shfl_xor(s1b, 32, 64); s2b += __shfl_xor(s2b, 32, 64);
    float mA = s1a*(1.f/64.f);
    float rA = 1.0f/sqrtf(s2a*(1.f/64.f) - mA*mA + 1e-5f);
    float mB = s1b*(1.f/64.f);
    float rB = 1.0f/sqrtf(s2b*(1.f/64.f) - mB*mB + 1e-5f);

    bf16x8 a00, a01, a10, a11;
    #pragma unroll
    for (int k = 0; k < 8; k++){
      a00[k] = (__bf16)((x0[k]    - mA)*rA*gq[k]   + bq[k]);
      a01[k] = (__bf16)((x0[8+k]  - mA)*rA*gq[8+k] + bq[8+k]);
      a10[k] = (__bf16)((x1[k]    - mB)*rB*gq[k]   + bq[k]);
      a11[k] = (__bf16)((x1[8+k]  - mB)*rB*gq[8+k] + bq[8+k]);
    }

    f32x4 acc0[4], acc1[4];
    #pragma unroll
    for (int nt = 0; nt < 4; nt++){
      bf16x8 w0 = wl[nt*64 + l];
      bf16x8 w1f = wl[(4 + nt)*64 + l];
      acc0[nt] = __builtin_amdgcn_mfma_f32_16x16x32_bf16(a00, w0,  zero,     0, 0, 0);
      acc0[nt] = __builtin_amdgcn_mfma_f32_16x16x32_bf16(a01, w1f, acc0[nt], 0, 0, 0);
      acc1[nt] = __builtin_amdgcn_mfma_f32_16x16x32_bf16(a10, w0,  zero,     0, 0, 0);
      acc1[nt] = __builtin_amdgcn_mfma_f32_16x16x32_bf16(a11, w1f, acc1[nt], 0, 0, 0);
    }

    float p0[4] = {0.f,0.f,0.f,0.f}, p1[4] = {0.f,0.f,0.f,0.f};
    #pragma unroll
    for (int nt = 0; nt < 4; nt++){
      float wq0 = s_wq[s0*68 + nt*16 + cr];
      float wq1 = s_wq[sB*68 + nt*16 + cr];
      #pragma unroll
      for (int reg = 0; reg < 4; reg++){
        p0[reg] = fmaf(fmaxf(acc0[nt][reg] + b1v[nt], 0.f), wq0, p0[reg]);
        p1[reg] = fmaf(fmaxf(acc1[nt][reg] + b1v[nt], 0.f), wq1, p1[reg]);
      }
    }
    #pragma unroll
    for (int off = 1; off < 16; off <<= 1){
      #pragma unroll
      for (int reg = 0; reg < 4; reg++){
        p0[reg] += __shfl_xor(p0[reg], off, 64);
        p1[reg] += __shfl_xor(p1[reg], off, 64);
      }
    }
    if (cr == 0){
      float c20 = s_wq[s0*68 + 64];
      float c21 = s_wq[sB*68 + 64];
      #pragma unroll
      for (int reg = 0; reg < 4; reg++){
        s_log[s0*64 + wv*16 + q*4 + reg] = (p0[reg] + c20) * 0.125f;
        if (np == 2) s_log[sB*64 + wv*16 + q*4 + reg] = (p1[reg] + c21) * 0.125f;
      }
    }
  }
  __syncthreads();

  // softmax over slots (per d column); att stays in s_log
  if (t < 64){
    float lv[7];
    #pragma unroll
    for (int s = 0; s < 7; s++) lv[s] = s_log[s*64 + t];
    float mx = lv[0];
    #pragma unroll
    for (int s = 1; s < 7; s++) mx = fmaxf(mx, lv[s]);
    float sm = 0.f;
    #pragma unroll
    for (int s = 0; s < 7; s++){ lv[s] = expf(lv[s] - mx); sm += lv[s]; }
    float inv = 1.0f / sm;
    #pragma unroll
    for (int s = 0; s < 7; s++){
      float a = lv[s] * inv;
      s_log[s*64 + t] = a;
      if (mode == 1) attOut[(size_t)(b*7+s)*4096 + tile*64 + t] = a;
    }
  }
  __syncthreads();

  // frames partials: thread (s, r) covers columns r and r+32
  if (t < 224){
    int s = t >> 5, r = t & 31;
    float a1 = s_log[s*64 + r];
    float a2 = s_log[s*64 + r + 32];
    float gx1 = -0.5f + (float)r * (1.f/63.f);
    float gx2 = -0.5f + (float)(r + 32) * (1.f/63.f);
    float gyc = -0.5f + (float)tile * (1.f/63.f);
    float gy2c = gyc*gyc;
    float w0 = a1 + a2;
    float w1 = a1*gx1 + a2*gx2;
    float w2 = w0*gyc;
    float w3 = a1*(gx1*gx1 + gy2c) + a2*(gx2*gx2 + gy2c);
    #pragma unroll
    for (int m = 1; m < 32; m <<= 1){
      w0 += __shfl_xor(w0, m, 64);
      w1 += __shfl_xor(w1, m, 64);
      w2 += __shfl_xor(w2, m, 64);
      w3 += __shfl_xor(w3, m, 64);
    }
    if (r == 0){
      atomicAdd(&accF[(b*7+s)*4 + 0], w0);
      atomicAdd(&accF[(b*7+s)*4 + 1], w1);
      atomicAdd(&accF[(b*7+s)*4 + 2], w2);
      atomicAdd(&accF[(b*7+s)*4 + 3], w3);
    }
  }

  // ---- V loop: weighted reduce into s_upd (U1, U2) ----
  if (mode == 0){
    float xbv[16];
    #pragma unroll
    for (int i = 0; i < 8; i++){ xbv[i] = (float)vb0[i]; xbv[8+i] = (float)vb1[i]; }
    for (int sp = 0; sp < 4; sp++){
      int s0 = sp*2;
      int np = (sp == 3) ? 1 : 2;
      int sB = (np == 2) ? s0 + 1 : s0;
      float x0[16], x1[16];
      float s1a = 0.f, s2a = 0.f, s1b = 0.f, s2b = 0.f;
      {
        const float* Ac = s_absc + s0*192;
        #pragma unroll
        for (int h = 0; h < 2; h++){
          int fb = h ? (32 + q*8) : (q*8);
          const float4* A4 = reinterpret_cast<const float4*>(Ac + fb);
          const float4* B4 = reinterpret_cast<const float4*>(Ac + 64 + fb);
          const float4* C4 = reinterpret_cast<const float4*>(Ac + 128 + fb);
          #pragma unroll
          for (int pp = 0; pp < 2; pp++){
            float4 Av = A4[pp], Bv = B4[pp], Cv = C4[pp];
            int o = h*8 + pp*4;
            x0[o+0] = xbv[o+0] + gx*Av.x + gy*Bv.x + Cv.x;
            x0[o+1] = xbv[o+1] + gx*Av.y + gy*Bv.y + Cv.y;
            x0[o+2] = xbv[o+2] + gx*Av.z + gy*Bv.z + Cv.z;
            x0[o+3] = xbv[o+3] + gx*Av.w + gy*Bv.w + Cv.w;
          }
        }
        #pragma unroll
        for (int k = 0; k < 16; k++){ s1a += x0[k]; s2a = fmaf(x0[k], x0[k], s2a); }
      }
      {
        const float* Ac = s_absc + sB*192;
        #pragma unroll
        for (int h = 0; h < 2; h++){
          int fb = h ? (32 + q*8) : (q*8);
          const float4* A4 = reinterpret_cast<const float4*>(Ac + fb);
          const float4* B4 = reinterpret_cast<const float4*>(Ac + 64 + fb);
          const float4* C4 = reinterpret_cast<const float4*>(Ac + 128 + fb);
          #pragma unroll
          for (int pp = 0; pp < 2; pp++){
            float4 Av = A4[pp], Bv = B4[pp], Cv = C4[pp];
            int o = h*8 + pp*4;
            x1[o+0] = xbv[o+0] + gx*Av.x + gy*Bv.x + Cv.x;
            x1[o+1] = xbv[o+1] + gx*Av.y + gy*Bv.y + Cv.y;
            x1[o+2] = xbv[o+2] + gx*Av.z + gy*Bv.z + Cv.z;
            x1[o+3] = xbv[o+3] + gx*Av.w + gy*Bv.w + Cv.w;
          }
        }
        #pragma unroll
        for (int k = 0; k < 16; k++){ s1b += x1[k]; s2b = fmaf(x1[k], x1[k], s2b); }
      }
      s1a += __shfl_xor(s1a, 16, 64); s2a += __shfl_xor(s2a, 16, 64);
      s1b += __shfl_xor(s1b, 16, 64); s2b += __shfl_xor(s2b, 16, 64);
      s1a += __shfl_xor(s1a, 32, 64); s2a += __shfl_xor(s2a, 32, 64);
      s1b += __shfl_xor(s1b, 32, 64); s2b += __shfl_xor(s2b, 32, 64);
      float mA = s1a*(1.f/64.f);
      float rA = 1.0f/sqrtf(s2a*(1.f/64.f) - mA*mA + 1e-5f);
      float mB = s1b*(1.f/64.f);
      float rB = 1.0f/sqrtf(s2b*(1.f/64.f) - mB*mB + 1e-5f);

      bf16x8 a00, a01, a10, a11;
      #pragma unroll
      for (int k = 0; k < 8; k++){
        a00[k] = (__bf16)((x0[k]    - mA)*rA*gq[k]   + bq[k]);
        a01[k] = (__bf16)((x0[8+k]  - mA)*rA*gq[8+k] + bq[8+k]);
        a10[k] = (__bf16)((x1[k]    - mB)*rB*gq[k]   + bq[k]);
        a11[k] = (__bf16)((x1[8+k]  - mB)*rB*gq[8+k] + bq[8+k]);
      }

      f32x4 acc0[4], acc1[4];
      #pragma unroll
      for (int nt = 0; nt < 4; nt++){
        bf16x8 w0 = wl[nt*64 + l];
        bf16x8 w1f = wl[(4 + nt)*64 + l];
        acc0[nt] = __builtin_amdgcn_mfma_f32_16x16x32_bf16(a00, w0,  zero,     0, 0, 0);
        acc0[nt] = __builtin_amdgcn_mfma_f32_16x16x32_bf16(a01, w1f, acc0[nt], 0, 0, 0);
        acc1[nt] = __builtin_amdgcn_mfma_f32_16x16x32_bf16(a10, w0,  zero,     0, 0, 0);
        acc1[nt] = __builtin_amdgcn_mfma_f32_16x16x32_bf16(a11, w1f, acc1[nt], 0, 0, 0);
      }

      float wr0[4], wr1[4];
      #pragma unroll
      for (int reg = 0; reg < 4; reg++){
        wr0[reg] = s_log[s0*64 + wv*16 + q*4 + reg];
        wr1[reg] = s_log[sB*64 + wv*16 + q*4 + reg];
      }
      float pa0[4], pa1[4], pu0[4], pu1[4];
      #pragma unroll
      for (int nt = 0; nt < 4; nt++){
        pa0[nt] = 0.f; pa1[nt] = 0.f; pu0[nt] = 0.f; pu1[nt] = 0.f;
        #pragma unroll
        for (int reg = 0; reg < 4; reg++){
          float v0 = fmaxf(acc0[nt][reg] + b1v[nt], 0.f);
          float v1 = fmaxf(acc1[nt][reg] + b1v[nt], 0.f);
          pa0[nt] = fmaf(wr0[reg], v0, pa0[nt]); pu0[nt] += v0;
          pa1[nt] = fmaf(wr1[reg], v1, pa1[nt]); pu1[nt] += v1;
        }
      }
      #pragma unroll
      for (int nt = 0; nt < 4; nt++){
        pa0[nt] += __shfl_xor(pa0[nt], 16, 64); pa0[nt] += __shfl_xor(pa0[nt], 32, 64);
        pu0[nt] += __shfl_xor(pu0[nt], 16, 64); pu0[nt] += __shfl_xor(pu0[nt], 32, 64);
        pa1[nt] += __shfl_xor(pa1[nt], 16, 64); pa1[nt] += __shfl_xor(pa1[nt], 32, 64);
        pu1[nt] += __shfl_xor(pu1[nt], 16, 64); pu1[nt] += __shfl_xor(pu1[nt], 32, 64);
      }
      if (q == 0){
        #pragma unroll
        for (int nt = 0; nt < 4; nt++){
          atomicAdd(&s_upd[s0*128 + nt*16 + cr], pa0[nt]);
          atomicAdd(&s_upd[s0*128 + 64 + nt*16 + cr], pu0[nt]);
          if (np == 2){
            atomicAdd(&s_upd[sB*128 + nt*16 + cr], pa1[nt]);
            atomicAdd(&s_upd[sB*128 + 64 + nt*16 + cr], pu1[nt]);
          }
        }
      }
    }
    __syncthreads();
    for (int i = t; i < 896; i += 256)
      atomicAdd(&upd[b*896 + i], s_upd[i]);
  }
}

// ---------------- GRU cell + frames finalize + next-phase prep -------------
// float4 weight loads (wih/whh rows contiguous) + 4-way split accumulators.
__global__ void k_gru(float* __restrict__ upd, float* __restrict__ queries,
                      const float* __restrict__ wih, const float* __restrict__ whh,
                      const float* __restrict__ bih, const float* __restrict__ bhh,
                      const float* __restrict__ mlp2w, const float* __restrict__ mlp2b,
                      float* __restrict__ accF, float* __restrict__ ps,
                      const float* __restrict__ qg_, const float* __restrict__ qb_,
                      const float* __restrict__ dw, const float* __restrict__ db,
                      float* __restrict__ absc, float* __restrict__ w2qc){
  int row = blockIdx.x; int t = threadIdx.x;   // 112 x 192
  __shared__ __align__(16) float us[64], hs[64], xs[64];
  __shared__ float gis[192], ghs[192];
  __shared__ float s_ps3[3];
  if (t < 64){
    float isa0 = 1.0f/accF[row*4];
    us[t] = upd[row*128 + t]*isa0 + 1e-8f*upd[row*128 + 64 + t];
    hs[t] = queries[row*64 + t];
  }
  if (t == 64){
    float sa = accF[row*4+0];
    float ax = accF[row*4+1], ay = accF[row*4+2], ar2 = accF[row*4+3];
    float isa = 1.0f/sa;
    float Wx = ax*isa, Wy = ay*isa;
    float Wg = ar2*isa + 1e-8f*SR2;
    float s2 = Wg - (Wx*Wx + Wy*Wy)*(2.f - W0CONST);
    s_ps3[0] = Wx; s_ps3[1] = Wy; s_ps3[2] = sqrtf(fmaxf(s2, 0.f));
  }
  __syncthreads();
  if (t < 64){
    float a0 = W0CONST * mlp2b[t], a1 = 0.f, a2 = 0.f, a3 = 0.f;
    for (int i = 0; i < 64; i += 4){
      a0 = fmaf(us[i],     mlp2w[i*64 + t],       a0);
      a1 = fmaf(us[i + 1], mlp2w[(i + 1)*64 + t], a1);
      a2 = fmaf(us[i + 2], mlp2w[(i + 2)*64 + t], a2);
      a3 = fmaf(us[i + 3], mlp2w[(i + 3)*64 + t], a3);
    }
    xs[t] = (a0 + a1) + (a2 + a3);
  }
  __syncthreads();
  {
    const float4* wi4 = reinterpret_cast<const float4*>(wih + t*64);
    const float4* wh4 = reinterpret_cast<const float4*>(whh + t*64);
    float gi0 = bih[t], gi1 = 0.f, gi2 = 0.f, gi3 = 0.f;
    float gh0 = bhh[t], gh1 = 0.f, gh2 = 0.f, gh3 = 0.f;
    for (int e4 = 0; e4 < 16; e4++){
      float4 wi = wi4[e4], wh = wh4[e4];
      int e = e4*4;
      gi0 = fmaf(wi.x, xs[e],     gi0);
      gi1 = fmaf(wi.y, xs[e + 1], gi1);
      gi2 = fmaf(wi.z, xs[e + 2], gi2);
      gi3 = fmaf(wi.w, xs[e + 3], gi3);
      gh0 = fmaf(wh.x, hs[e],     gh0);
      gh1 = fmaf(wh.y, hs[e + 1], gh1);
      gh2 = fmaf(wh.z, hs[e + 2], gh2);
      gh3 = fmaf(wh.w, hs[e + 3], gh3);
    }
    gis[t] = (gi0 + gi1) + (gi2 + gi3);
    ghs[t] = (gh0 + gh1) + (gh2 + gh3);
  }
  __syncthreads();
  if (t < 64){
    float r = 1.0f/(1.0f + expf(-(gis[t]      + ghs[t])));
    float z = 1.0f/(1.0f + expf(-(gis[64+t]   + ghs[64+t])));
    float n = tanhf(gis[128+t] + r*ghs[128+t]);
    float newq = (1.0f - z)*n + z*hs[t];
    queries[row*64 + t] = newq;
    upd[row*128 + t] = 0.f;
    upd[row*128 + 64 + t] = 0.f;
    if (t < 4) accF[row*4 + t] = 0.f;
    if (t < 3) ps[row*3 + t] = s_ps3[t];
    pp_core(row, t, newq, s_ps3[0], s_ps3[1], s_ps3[2],
            qg_, qb_, dw, db, mlp2w, mlp2b, absc, w2qc);
  }
}

// ---------------- heads: alpha, slot_feat(+frames), copy queries -----------
__global__ void k_final(const float* __restrict__ queries, const float* __restrict__ accF,
                        const float* __restrict__ a1w, const float* __restrict__ a1b,
                        const float* __restrict__ a2w, const float* __restrict__ a2b,
                        const float* __restrict__ f1w, const float* __restrict__ f1b,
                        const float* __restrict__ f2w, const float* __restrict__ f2b,
                        float* __restrict__ out){
  int bs = blockIdx.x; int e = threadIdx.x;    // 112 x 64
  __shared__ float qs[64], hf[64], ha[32];
  float q = queries[bs*64 + e];
  qs[e] = q;
  out[bs*64 + e] = q;
  __syncthreads();
  float accf = f1b[e];
  for (int i = 0; i < 64; i++) accf = fmaf(qs[i], f1w[i*64 + e], accf);
  hf[e] = fmaxf(accf, 0.f);
  if (e < 32){
    float acca = a1b[e];
    for (int i = 0; i < 64; i++) acca = fmaf(qs[i], a1w[i*32 + e], acca);
    ha[e] = fmaxf(acca, 0.f);
  }
  __syncthreads();
  if (e < 3){
    float sf = f2b[e];
    for (int o = 0; o < 64; o++) sf = fmaf(hf[o], f2w[o*3 + e], sf);
    float sa = accF[bs*4+0], ax = accF[bs*4+1], ay = accF[bs*4+2], ar2 = accF[bs*4+3];
    float isa = 1.0f/sa;
    float Wx = ax*isa, Wy = ay*isa;
    float Wg = ar2*isa + 1e-8f*SR2;
    float s2 = Wg - (Wx*Wx + Wy*Wy)*(2.f - W0CONST);
    float nv = (e == 0) ? Wx : ((e == 1) ? Wy : sqrtf(fmaxf(s2, 0.f)));
    out[465920 + bs*3 + e] = sf + nv;
  }
  if (e == 32){
    float al = a2b[0];
    for (int o = 0; o < 32; o++) al = fmaf(ha[o], a2w[o], al);
    out[466256 + bs] = 1.0f/(1.0f + expf(-al));
  }
}

// ---------------------------------------------------------------------------
extern "C" void kernel_launch(void* const* d_in, const int* in_sizes, int n_in,
                              void* d_out, int out_size, void* d_ws, size_t ws_size,
                              hipStream_t stream){
  const float* data        = (const float*)d_in[0];
  const float* slot_noise  = (const float*)d_in[1];
  const float* pos_rand    = (const float*)d_in[2];
  const float* conv0_w     = (const float*)d_in[3];
  const float* conv0_b     = (const float*)d_in[4];
  const float* conv1_w     = (const float*)d_in[5];
  const float* conv1_b     = (const float*)d_in[6];
  const float* conv2_w     = (const float*)d_in[7];
  const float* conv2_b     = (const float*)d_in[8];
  const float* dataN_g     = (const float*)d_in[9];
  const float* dataN_b     = (const float*)d_in[10];
  const float* queryN_g    = (const float*)d_in[11];
  const float* queryN_b    = (const float*)d_in[12];
  const float* toK_w       = (const float*)d_in[13];
  const float* toK_b       = (const float*)d_in[14];
  const float* toV_w       = (const float*)d_in[15];
  const float* toV_b       = (const float*)d_in[16];
  const float* dense_w     = (const float*)d_in[17];
  const float* dense_b     = (const float*)d_in[18];
  const float* mlp1_w      = (const float*)d_in[19];
  const float* mlp1_b      = (const float*)d_in[20];
  const float* mlp2_w      = (const float*)d_in[21];
  const float* mlp2_b      = (const float*)d_in[22];
  const float* gru_wih     = (const float*)d_in[23];
  const float* gru_whh     = (const float*)d_in[24];
  const float* gru_bih     = (const float*)d_in[25];
  const float* gru_bhh     = (const float*)d_in[26];
  const float* alpha1_w    = (const float*)d_in[27];
  const float* alpha1_b    = (const float*)d_in[28];
  const float* alpha2_w    = (const float*)d_in[29];
  const float* alpha2_b    = (const float*)d_in[30];
  const float* final1_w    = (const float*)d_in[31];
  const float* final1_b    = (const float*)d_in[32];
  const float* final2_w    = (const float*)d_in[33];
  const float* final2_b    = (const float*)d_in[34];
  const float* slots_mu    = (const float*)d_in[35];
  const float* slots_lsig  = (const float*)d_in[36];

  float* ws   = (float*)d_ws;
  float* bufA = ws;                    // c0_bf (bf16) then encK (bf16)
  float* bufB = bufA + 4194304;        // enc bf16
  float* bufC = bufB + 4194304;        // c1_bf (bf16) then encV (bf16)
  float* queries = bufC + 4194304;     // 7,168
  float* ps   = queries + 7168;        // 512 ([112][3], 336 used)
  float* absc = ps + 512;              // 21,504 (A/B/cc per (b,s))
  float* accF = absc + 21504;          // 512 ([112][4]: sa, ax, ay, ar2)
  float* upd  = accF + 512;            // 14,336 ([112][128]: U1 | U2)
  float* w2qc = upd + 14336;           // 7,616 ([112][68])
  unsigned short* w1pack = (unsigned short*)(w2qc + 7616);   // 4096 bf16
  unsigned short* kpack  = w1pack + 4096;                    // 4096
  unsigned short* vpack  = kpack + 4096;                     // 4096
  unsigned short* wp1    = vpack + 4096;                     // 102,400
  unsigned short* wp2    = wp1 + 102400;                     // 102,400

  unsigned short* c0_bf = (unsigned short*)bufA;   // conv0 out, NHWC bf16
  unsigned short* c1_bf = (unsigned short*)bufC;   // conv1 out, NHWC bf16
  unsigned short* enc   = (unsigned short*)bufB;   // LN(conv2) bf16
  unsigned short* encK  = (unsigned short*)bufA;   // overwrites c0_bf (done)
  unsigned short* encV  = (unsigned short*)bufC;   // overwrites c1_bf (done)

  float* outq   = (float*)d_out;       // queries [7168]
  float* outatt = outq + 7168;         // att [458752]

  k_front<<<1984, 256, 0, stream>>>(mlp1_w, toK_w, toV_w, conv1_w, conv2_w,
                                    w1pack, kpack, vpack, wp1, wp2,
                                    slot_noise, pos_rand, slots_mu, slots_lsig,
                                    queryN_g, queryN_b, dense_w, dense_b, mlp2_w, mlp2_b,
                                    queries, ps, absc, w2qc, accF, upd,
                                    data, conv0_w, conv0_b, c0_bf);
  k_convm<<<512, 256, 0, stream>>>(c0_bf, wp1, conv1_b, nullptr, nullptr, c1_bf, 0);
  k_convm<<<512, 256, 0, stream>>>(c1_bf, wp2, conv2_b, dataN_g, dataN_b, enc, 1);
  k_projm<<<1024, 256, 0, stream>>>(enc, kpack, toK_b, vpack, toV_b, encK, encV);

  for (int p = 0; p < 4; p++){
    k_attn<<<1024, 256, 0, stream>>>(encK, encV, w1pack, mlp1_b, absc,
                                     queryN_g, queryN_b, w2qc, outatt, accF, upd,
                                     (p < 3) ? 0 : 1);
    if (p < 3){
      k_gru<<<112, 192, 0, stream>>>(upd, queries, gru_wih, gru_whh, gru_bih, gru_bhh,
                                     mlp2_w, mlp2_b, accF, ps, queryN_g, queryN_b,
                                     dense_w, dense_b, absc, w2qc);
    }
  }
  k_final<<<112, 64, 0, stream>>>(queries, accF,
                                  alpha1_w, alpha1_b, alpha2_w, alpha2_b,
                                  final1_w, final1_b, final2_w, final2_b, outq);
}

// Round 10
// 471.118 us; speedup vs baseline: 1.6837x; 1.0196x over previous
//
#include <hip/hip_runtime.h>
#include <cmath>

// ---------------------------------------------------------------------------
// InvariantSlotAttention forward. R25 = R24 (480us) + k_projm fused into
// k_convm mode 1: after conv+LN, the block's 128x64 enc tile is staged bf16
// in the (idle) conv LDS buffer ([128][72] pad -> 2-way-free reads) and the
// K/V projection MFMAs run in-kernel, writing encK/encV directly. Deletes
// the k_projm launch and the 4MB enc write + 4MB read. encK->bufA,
// encV->bufB (both free; previously encV aliased c1_bf which we still read).
// k_attn untouched (verified local optimum; R17-R22 all failed/regressed).
// B=16, S=7, E=HID=64, D=4096, N_ITER=3, TSOFT=0.125
// ---------------------------------------------------------------------------

#define RLOW_F 0.1f
#define RHIGH_F 0.22360679774997896f
#define W0CONST 1.00004096f      /* sum_d wts = 1 + 4096e-8 exactly */
#define SR2 704.3386243f         /* sum_d (gx^2+gy^2) */

typedef __attribute__((ext_vector_type(8))) __bf16 bf16x8;
typedef __attribute__((ext_vector_type(4))) float f32x4;

__device__ __forceinline__ float wsum64(float v){
  #pragma unroll
  for (int off = 32; off > 0; off >>= 1) v += __shfl_xor(v, off, 64);
  return v;
}
__device__ __forceinline__ float rdlane(float v, int l){
  return __int_as_float(__builtin_amdgcn_readlane(__float_as_int(v), l));
}
__device__ __forceinline__ unsigned short bf16bits(float v){
  __bf16 h = (__bf16)v;
  return *reinterpret_cast<unsigned short*>(&h);
}

// ---- phase prep core: one full wave (lanes 0..63), e = lane ---------------
// float4 weight loads + 4-way split accumulators (chain 64 -> 16).
__device__ __forceinline__ void pp_core(int row, int e, float qv,
    float px, float py, float sc,
    const float* __restrict__ qg_, const float* __restrict__ qb_,
    const float* __restrict__ dw, const float* __restrict__ db,
    const float* __restrict__ mlp2w, const float* __restrict__ mlp2b,
    float* __restrict__ absc, float* __restrict__ w2qc){
  float m = wsum64(qv) * (1.f/64.f);
  float d = qv - m;
  float var = wsum64(d*d) * (1.f/64.f);
  float qlnv = d * (1.0f/sqrtf(var + 1e-5f)) * qg_[e] + qb_[e];
  float A  = dw[e]      / sc;
  float Bv = dw[64 + e] / sc;
  absc[row*192 + e]       = A;
  absc[row*192 + 64 + e]  = Bv;
  absc[row*192 + 128 + e] = db[e] - px*A - py*Bv;
  float a0 = 0.f, a1 = 0.f, a2 = 0.f, a3 = 0.f;
  const float4* wr4 = reinterpret_cast<const float4*>(mlp2w + e*64);
  for (int j = 0; j < 16; j++){
    float4 w4 = wr4[j];
    a0 = fmaf(w4.x, rdlane(qlnv, 4*j + 0), a0);
    a1 = fmaf(w4.y, rdlane(qlnv, 4*j + 1), a1);
    a2 = fmaf(w4.z, rdlane(qlnv, 4*j + 2), a2);
    a3 = fmaf(w4.w, rdlane(qlnv, 4*j + 3), a3);
  }
  w2qc[row*68 + e] = (a0 + a1) + (a2 + a3);
  float c2 = wsum64(mlp2b[e] * qlnv);
  if (e == 0) w2qc[row*68 + 64] = c2;
}

// ---------------- merged front: packing + phase-0 prep + conv0 -------------
// blocks 0-15: w1pack; 16-31: kpack; 32-47: vpack; 48-447: wp1; 448-847: wp2;
// 848-959: prep; 960-1983: conv0 (bi-960 = b*64 + y).
__global__ __launch_bounds__(256) void k_front(const float* __restrict__ mlp1_w,
                          const float* __restrict__ toK_w,
                          const float* __restrict__ toV_w, const float* __restrict__ conv1_w,
                          const float* __restrict__ conv2_w,
                          unsigned short* __restrict__ w1pack, unsigned short* __restrict__ kpack,
                          unsigned short* __restrict__ vpack, unsigned short* __restrict__ wp1,
                          unsigned short* __restrict__ wp2,
                          const float* __restrict__ noise, const float* __restrict__ prand,
                          const float* __restrict__ mu, const float* __restrict__ logsig,
                          const float* __restrict__ qg_, const float* __restrict__ qb_,
                          const float* __restrict__ dw, const float* __restrict__ db,
                          const float* __restrict__ mlp2w, const float* __restrict__ mlp2b,
                          float* __restrict__ queries, float* __restrict__ ps,
                          float* __restrict__ absc, float* __restrict__ w2qc,
                          float* __restrict__ accF, float* __restrict__ upd,
                          const float* __restrict__ cin, const float* __restrict__ c0w,
                          const float* __restrict__ c0b, unsigned short* __restrict__ c0out){
  int bi = blockIdx.x; int t = threadIdx.x;
  __shared__ float s_in[5*68];
  __shared__ float s_w[64*25];
  __shared__ float s_out[64*65];
  if (bi < 48){
    const float* src = (bi < 16) ? mlp1_w : ((bi < 32) ? toK_w : toV_w);
    unsigned short* dst = (bi < 16) ? w1pack : ((bi < 32) ? kpack : vpack);
    int idx = (bi & 15)*256 + t;
    int jj = idx & 7;
    int lane = (idx >> 3) & 63;
    int frag = idx >> 9;
    int ks = frag >> 2, nt = frag & 3;
    int q = lane >> 4, cr = lane & 15;
    int k = ks*32 + q*8 + jj;
    int n = nt*16 + cr;
    dst[idx] = bf16bits(src[k*64 + n]);
  } else if (bi < 848){
    int rb = bi - 48;
    const float* src = (rb < 400) ? conv1_w : conv2_w;
    unsigned short* dst = (rb < 400) ? wp1 : wp2;
    int idx = (rb % 400)*256 + t;
    int j = idx & 7;
    int l = (idx >> 3) & 63;
    int frag = idx >> 9;
    int nt = frag & 3;
    int ks = (frag >> 2) % 10;
    int dy = frag / 40;
    int q = l >> 4, cr = l & 15;
    int k = ks*32 + q*8 + j;
    int kx = k >> 6, ch = k & 63;
    int n = nt*16 + cr;
    dst[idx] = bf16bits(src[((n*64 + ch)*5 + dy)*5 + kx]);
  } else if (bi < 960){
    if (t >= 64) return;
    int row = bi - 848;           // 112 rows
    int e = t;
    int s = row % 7;
    float qv = mu[e] + expf(logsig[e]) * noise[row*64 + e];
    queries[row*64 + e] = qv;
    upd[row*128 + e] = 0.f;
    upd[row*128 + 64 + e] = 0.f;
    if (e < 4) accF[row*4 + e] = 0.f;
    float pv = 0.f;
    if (e < 3){
      float pr = prand[row*3 + e];
      if (s < 2)       pv = pr - 0.5f;
      else if (s == 6) pv = (RLOW_F - RHIGH_F)*pr + RHIGH_F;
      else             pv = pr;
      ps[row*3 + e] = pv;
    }
    float px = rdlane(pv, 0), py = rdlane(pv, 1), sc = rdlane(pv, 2);
    pp_core(row, e, qv, px, py, sc, qg_, qb_, dw, db, mlp2w, mlp2b, absc, w2qc);
  } else {
    // ---- conv0: 1->64 channels, 5x5 same, relu, NHWC bf16 out ----
    int ci = bi - 960; int b = ci >> 6; int y = ci & 63;
    int lane = t & 63; int xg = t >> 6;
    for (int i = t; i < 1600; i += 256) s_w[i] = c0w[i];
    for (int i = t; i < 340; i += 256){
      int r = i / 68, cx = i % 68;
      int yy = y + r - 2, gx = cx - 2;
      float v = 0.f;
      if (yy >= 0 && yy < 64 && gx >= 0 && gx < 64) v = cin[(b*64 + yy)*64 + gx];
      s_in[r*68 + cx] = v;
    }
    __syncthreads();
    int o = lane;
    float bvv = c0b[o];
    float acc[16];
    #pragma unroll
    for (int k = 0; k < 16; k++) acc[k] = bvv;
    #pragma unroll
    for (int ky = 0; ky < 5; ky++){
      float rv[20];
      const float4* p = reinterpret_cast<const float4*>(&s_in[ky*68 + xg*16]);
      #pragma unroll
      for (int q = 0; q < 5; q++){ float4 f = p[q]; rv[q*4]=f.x; rv[q*4+1]=f.y; rv[q*4+2]=f.z; rv[q*4+3]=f.w; }
      #pragma unroll
      for (int kx = 0; kx < 5; kx++){
        float wv = s_w[o*25 + ky*5 + kx];
        #pragma unroll
        for (int k = 0; k < 16; k++) acc[k] = fmaf(rv[k+kx], wv, acc[k]);
      }
    }
    #pragma unroll
    for (int k = 0; k < 16; k++) s_out[o*65 + xg*16 + k] = fmaxf(acc[k], 0.f);
    __syncthreads();
    for (int i = t; i < 4096; i += 256){
      int px = i >> 6, ch = i & 63;
      c0out[((size_t)(b*64 + y)*64 + px)*64 + ch] = bf16bits(s_out[ch*65 + px]);
    }
  }
}

// ---------------- conv1/conv2 bf16 MFMA implicit GEMM (512 blocks) ---------
// mode 0: relu -> bf16 NHWC. mode 1: relu -> LN -> LDS tile -> fused K/V
// projection MFMA -> encK/encV (enc never touches global).
__global__ __launch_bounds__(256) void k_convm(const unsigned short* __restrict__ in_bf,
                        const unsigned short* __restrict__ wpack,
                        const float* __restrict__ bias,
                        const float* __restrict__ lng, const float* __restrict__ lnb,
                        unsigned short* __restrict__ out_bf, int mode,
                        const unsigned short* __restrict__ kpack, const float* __restrict__ bk,
                        const unsigned short* __restrict__ vpack, const float* __restrict__ bvp,
                        unsigned short* __restrict__ K, unsigned short* __restrict__ V){
  int bi = blockIdx.x;                  // 512 = 16 b * 16 yg * 2 xh
  int b = bi >> 5; int yg = (bi >> 1) & 15; int xh = bi & 1;
  int t = threadIdx.x; int wv = t >> 6; int l = t & 63;
  int q = l >> 4, cr = l & 15;
  int yr = wv >> 1, ph = wv & 1;
  int p0 = ph*16;

  __shared__ char lds[8*36*144];

  for (int ri = 0; ri < 8; ri++){
    int yy = yg*4 + ri - 2;
    bool rok = (yy >= 0 && yy < 64);
    const uint4* src = reinterpret_cast<const uint4*>(in_bf + (size_t)(b*64 + yy)*64*64);
    for (int i = t; i < 288; i += 256){
      int px = i >> 3, c8 = i & 7;
      uint4 v = {0u,0u,0u,0u};
      int gx = xh*32 + px - 2;
      if (rok && gx >= 0 && gx < 64) v = src[gx*8 + c8];
      *reinterpret_cast<uint4*>(&lds[ri*5184 + px*144 + c8*16]) = v;
    }
  }
  __syncthreads();

  f32x4 acc[2][4];
  #pragma unroll
  for (int r = 0; r < 2; r++)
    #pragma unroll
    for (int nt = 0; nt < 4; nt++) acc[r][nt] = (f32x4){0.f,0.f,0.f,0.f};

  const bf16x8* wp = reinterpret_cast<const bf16x8*>(wpack);
  for (int dy = 0; dy < 5; dy++){
    for (int ks = 0; ks < 10; ks++){
      bf16x8 Bf[4];
      int fbase = (dy*10 + ks)*4;
      #pragma unroll
      for (int nt = 0; nt < 4; nt++) Bf[nt] = wp[(fbase + nt)*64 + l];
      int aoff = (p0 + cr + (ks >> 1))*144 + (ks & 1)*64 + q*16;
      #pragma unroll
      for (int r = 0; r < 2; r++){
        int ri = yr*2 + r + dy;
        bf16x8 a = *reinterpret_cast<const bf16x8*>(&lds[ri*5184 + aoff]);
        #pragma unroll
        for (int nt = 0; nt < 4; nt++)
          acc[r][nt] = __builtin_amdgcn_mfma_f32_16x16x32_bf16(a, Bf[nt], acc[r][nt], 0, 0, 0);
      }
    }
  }

  float bvv[4];
  #pragma unroll
  for (int nt = 0; nt < 4; nt++) bvv[nt] = bias[nt*16 + cr];

  if (mode == 0){
    #pragma unroll
    for (int r = 0; r < 2; r++){
      int y = yg*4 + yr*2 + r;
      #pragma unroll
      for (int reg = 0; reg < 4; reg++){
        int p = xh*32 + p0 + q*4 + reg;
        size_t base = ((size_t)(b*64 + y)*64 + p)*64;
        #pragma unroll
        for (int nt = 0; nt < 4; nt++)
          out_bf[base + nt*16 + cr] = bf16bits(fmaxf(acc[r][nt][reg] + bvv[nt], 0.f));
      }
    }
  } else {
    float gv[4], bb[4];
    #pragma unroll
    for (int nt = 0; nt < 4; nt++){ gv[nt] = lng[nt*16 + cr]; bb[nt] = lnb[nt*16 + cr]; }
    __syncthreads();                       // conv lds reads complete; reuse buffer
    unsigned short* lds16 = (unsigned short*)lds;   // [128][72] bf16 tile
    #pragma unroll
    for (int r = 0; r < 2; r++){
      #pragma unroll
      for (int reg = 0; reg < 4; reg++){
        float v[4]; float s1 = 0.f, s2 = 0.f;
        #pragma unroll
        for (int nt = 0; nt < 4; nt++){
          v[nt] = fmaxf(acc[r][nt][reg] + bvv[nt], 0.f);
          s1 += v[nt]; s2 += v[nt]*v[nt];
        }
        #pragma unroll
        for (int m = 1; m < 16; m <<= 1){ s1 += __shfl_xor(s1, m, 64); s2 += __shfl_xor(s2, m, 64); }
        float mean = s1 * (1.f/64.f);
        float var  = s2 * (1.f/64.f) - mean*mean;
        float rstd = 1.0f/sqrtf(var + 1e-5f);
        int lrow = (yr*2 + r)*32 + p0 + q*4 + reg;
        #pragma unroll
        for (int nt = 0; nt < 4; nt++)
          lds16[lrow*72 + nt*16 + cr] = bf16bits((v[nt] - mean)*rstd*gv[nt] + bb[nt]);
      }
    }
    __syncthreads();
    // ---- fused K/V projection: 2 groups of 16 rows per wave ----
    const bf16x8* kp = reinterpret_cast<const bf16x8*>(kpack);
    const bf16x8* vp = reinterpret_cast<const bf16x8*>(vpack);
    bf16x8 KB[8], VB[8];
    #pragma unroll
    for (int f = 0; f < 8; f++){ KB[f] = kp[f*64 + l]; VB[f] = vp[f*64 + l]; }
    f32x4 zero = {0.f,0.f,0.f,0.f};
    #pragma unroll
    for (int it = 0; it < 2; it++){
      int base = it*64 + wv*16;
      const unsigned short* er = lds16 + (base + cr)*72;
      bf16x8 a0 = *reinterpret_cast<const bf16x8*>(er + q*8);
      bf16x8 a1 = *reinterpret_cast<const bf16x8*>(er + 32 + q*8);
      f32x4 aK[4], aV[4];
      #pragma unroll
      for (int nt = 0; nt < 4; nt++){
        aK[nt] = __builtin_amdgcn_mfma_f32_16x16x32_bf16(a0, KB[nt],     zero,   0, 0, 0);
        aK[nt] = __builtin_amdgcn_mfma_f32_16x16x32_bf16(a1, KB[4 + nt], aK[nt], 0, 0, 0);
        aV[nt] = __builtin_amdgcn_mfma_f32_16x16x32_bf16(a0, VB[nt],     zero,   0, 0, 0);
        aV[nt] = __builtin_amdgcn_mfma_f32_16x16x32_bf16(a1, VB[4 + nt], aV[nt], 0, 0, 0);
      }
      #pragma unroll
      for (int nt = 0; nt < 4; nt++){
        float bkv = bk[nt*16 + cr], bvp_ = bvp[nt*16 + cr];
        #pragma unroll
        for (int reg = 0; reg < 4; reg++){
          int lr = base + q*4 + reg;
          int drow = (yg*4 + (lr >> 5))*64 + xh*32 + (lr & 31);
          size_t idx = ((size_t)b*4096 + drow)*64 + nt*16 + cr;
          K[idx] = bf16bits(aK[nt][reg] + bkv);
          V[idx] = bf16bits(aV[nt][reg] + bvp_);
        }
      }
    }
  }
}

// ---------------- fused attention: K logits + softmax + frames + V reduce --
// mode 0 (iters 0-2): att stays in LDS; V path accumulates U1=sum att*relu(h)
//   and U2=sum relu(h) into upd[112][128] (normalization deferred to k_gru).
// mode 1 (iter 3): write att to global, skip V.
__global__ __launch_bounds__(256) void k_attn(const unsigned short* __restrict__ encK,
     const unsigned short* __restrict__ encV,
     const unsigned short* __restrict__ w1pack, const float* __restrict__ mlp1b,
     const float* __restrict__ absc, const float* __restrict__ qg_,
     const float* __restrict__ qb_, const float* __restrict__ w2qc,
     float* __restrict__ attOut, float* __restrict__ accF,
     float* __restrict__ upd, int mode){
  int bi = blockIdx.x;                 // 1024 = 16 b * 64 tiles
  int b = bi >> 6, tile = bi & 63;
  int t = threadIdx.x; int wv = t >> 6; int l = t & 63;
  int q = l >> 4, cr = l & 15;
  int m0 = tile*64 + wv*16;
  int drow = m0 + cr;

  __shared__ float s_log[7*64];
  __shared__ float s_absc[7*192];
  __shared__ float s_wq[7*68];
  __shared__ float s_upd[7*128];
  __shared__ unsigned short s_w1[4096];
  for (int i = t; i < 1344; i += 256) s_absc[i] = absc[b*7*192 + i];
  for (int i = t; i < 476;  i += 256) s_wq[i]   = w2qc[b*7*68 + i];
  if (mode == 0)
    for (int i = t; i < 896; i += 256) s_upd[i] = 0.f;
  {
    const uint4* g = reinterpret_cast<const uint4*>(w1pack);
    uint4* d = reinterpret_cast<uint4*>(s_w1);
    for (int i = t; i < 512; i += 256) d[i] = g[i];
  }

  const unsigned short* er = encK + (size_t)(b*4096 + drow)*64;
  float gx = -0.5f + (float)(drow & 63) * (1.f/63.f);
  float gy = -0.5f + (float)((drow >> 6) & 63) * (1.f/63.f);
  float xb[16], gq[16], bq[16];
  {
    bf16x8 ea = *reinterpret_cast<const bf16x8*>(er + q*8);
    bf16x8 eb = *reinterpret_cast<const bf16x8*>(er + 32 + q*8);
    #pragma unroll
    for (int i = 0; i < 8; i++){ xb[i] = (float)ea[i]; xb[8+i] = (float)eb[i]; }
  }
  bf16x8 vb0, vb1;                     // encV row held bf16 until V loop
  if (mode == 0){
    const unsigned short* ev = encV + (size_t)(b*4096 + drow)*64;
    vb0 = *reinterpret_cast<const bf16x8*>(ev + q*8);
    vb1 = *reinterpret_cast<const bf16x8*>(ev + 32 + q*8);
  }
  #pragma unroll
  for (int h = 0; h < 2; h++){
    int fb = h ? (32 + q*8) : (q*8);
    const float4* g4 = reinterpret_cast<const float4*>(qg_ + fb);
    const float4* b4 = reinterpret_cast<const float4*>(qb_ + fb);
    #pragma unroll
    for (int p = 0; p < 2; p++){
      float4 gg = g4[p], bb = b4[p];
      int o = h*8 + p*4;
      gq[o+0]=gg.x; gq[o+1]=gg.y; gq[o+2]=gg.z; gq[o+3]=gg.w;
      bq[o+0]=bb.x; bq[o+1]=bb.y; bq[o+2]=bb.z; bq[o+3]=bb.w;
    }
  }
  float b1v[4];
  #pragma unroll
  for (int nt = 0; nt < 4; nt++) b1v[nt] = mlp1b[nt*16 + cr];
  __syncthreads();

  const bf16x8* wl = reinterpret_cast<const bf16x8*>(s_w1);
  f32x4 zero = {0.f, 0.f, 0.f, 0.f};

  // ---- K loop: logits for all 7 slots (slot-paired) ----
  for (int sp = 0; sp < 4; sp++){
    int s0 = sp*2;
    int np = (sp == 3) ? 1 : 2;
    int sB = (np == 2) ? s0 + 1 : s0;
    float x0[16], x1[16];
    float s1a = 0.f, s2a = 0.f, s1b = 0.f, s2b = 0.f;
    {
      const float* Ac = s_absc + s0*192;
      #pragma unroll
      for (int h = 0; h < 2; h++){
        int fb = h ? (32 + q*8) : (q*8);
        const float4* A4 = reinterpret_cast<const float4*>(Ac + fb);
        const float4* B4 = reinterpret_cast<const float4*>(Ac + 64 + fb);
        const float4* C4 = reinterpret_cast<const float4*>(Ac + 128 + fb);
        #pragma unroll
        for (int pp = 0; pp < 2; pp++){
          float4 Av = A4[pp], Bv = B4[pp], Cv = C4[pp];
          int o = h*8 + pp*4;
          x0[o+0] = xb[o+0] + gx*Av.x + gy*Bv.x + Cv.x;
          x0[o+1] = xb[o+1] + gx*Av.y + gy*Bv.y + Cv.y;
          x0[o+2] = xb[o+2] + gx*Av.z + gy*Bv.z + Cv.z;
          x0[o+3] = xb[o+3] + gx*Av.w + gy*Bv.w + Cv.w;
        }
      }
      #pragma unroll
      for (int k = 0; k < 16; k++){ s1a += x0[k]; s2a = fmaf(x0[k], x0[k], s2a); }
    }
    {
      const float* Ac = s_absc + sB*192;
      #pragma unroll
      for (int h = 0; h < 2; h++){
        int fb = h ? (32 + q*8) : (q*8);
        const float4* A4 = reinterpret_cast<const float4*>(Ac + fb);
        const float4* B4 = reinterpret_cast<const float4*>(Ac + 64 + fb);
        const float4* C4 = reinterpret_cast<const float4*>(Ac + 128 + fb);
        #pragma unroll
        for (int pp = 0; pp < 2; pp++){
          float4 Av = A4[pp], Bv = B4[pp], Cv = C4[pp];
          int o = h*8 + pp*4;
          x1[o+0] = xb[o+0] + gx*Av.x + gy*Bv.x + Cv.x;
          x1[o+1] = xb[o+1] + gx*Av.y + gy*Bv.y + Cv.y;
          x1[o+2] = xb[o+2] + gx*Av.z + gy*Bv.z + Cv.z;
          x1[o+3] = xb[o+3] + gx*Av.w + gy*Bv.w + Cv.w;
        }
      }
      #pragma unroll
      for (int k = 0; k < 16; k++){ s1b += x1[k]; s2b = fmaf(x1[k], x1[k], s2b); }
    }
    s1a += __shfl_xor(s1a, 16, 64); s2a += __shfl_xor(s2a, 16, 64);
    s1b += __shfl_xor(s1b, 16, 64); s2b += __shfl_xor(s2b, 16, 64);
    s1a += __shfl_xor(s1a, 32, 64); s2a += __shfl_xor(s2a, 32, 64);
    s1b += __shfl_xor(s1b, 32, 64); s2b += __shfl_xor(s2b, 32, 64);
    float mA = s1a*(1.f/64.f);
    float rA = 1.0f/sqrtf(s2a*(1.f/64.f) - mA*mA + 1e-5f);
    float mB = s1b*(1.f/64.f);
    float rB = 1.0f/sqrtf(s2b*(1.f/64.f) - mB*mB + 1e-5f);

    bf16x8 a00, a01, a10, a11;
    #pragma unroll
    for (int k = 0; k < 8; k++){
      a00[k] = (__bf16)((x0[k]    - mA)*rA*gq[k]   + bq[k]);
      a01[k] = (__bf16)((x0[8+k]  - mA)*rA*gq[8+k] + bq[8+k]);
      a10[k] = (__bf16)((x1[k]    - mB)*rB*gq[k]   + bq[k]);
      a11[k] = (__bf16)((x1[8+k]  - mB)*rB*gq[8+k] + bq[8+k]);
    }

    f32x4 acc0[4], acc1[4];
    #pragma unroll
    for (int nt = 0; nt < 4; nt++){
      bf16x8 w0 = wl[nt*64 + l];
      bf16x8 w1f = wl[(4 + nt)*64 + l];
      acc0[nt] = __builtin_amdgcn_mfma_f32_16x16x32_bf16(a00, w0,  zero,     0, 0, 0);
      acc0[nt] = __builtin_amdgcn_mfma_f32_16x16x32_bf16(a01, w1f, acc0[nt], 0, 0, 0);
      acc1[nt] = __builtin_amdgcn_mfma_f32_16x16x32_bf16(a10, w0,  zero,     0, 0, 0);
      acc1[nt] = __builtin_amdgcn_mfma_f32_16x16x32_bf16(a11, w1f, acc1[nt], 0, 0, 0);
    }

    float p0[4] = {0.f,0.f,0.f,0.f}, p1[4] = {0.f,0.f,0.f,0.f};
    #pragma unroll
    for (int nt = 0; nt < 4; nt++){
      float wq0 = s_wq[s0*68 + nt*16 + cr];
      float wq1 = s_wq[sB*68 + nt*16 + cr];
      #pragma unroll
      for (int reg = 0; reg < 4; reg++){
        p0[reg] = fmaf(fmaxf(acc0[nt][reg] + b1v[nt], 0.f), wq0, p0[reg]);
        p1[reg] = fmaf(fmaxf(acc1[nt][reg] + b1v[nt], 0.f), wq1, p1[reg]);
      }
    }
    #pragma unroll
    for (int off = 1; off < 16; off <<= 1){
      #pragma unroll
      for (int reg = 0; reg < 4; reg++){
        p0[reg] += __shfl_xor(p0[reg], off, 64);
        p1[reg] += __shfl_xor(p1[reg], off, 64);
      }
    }
    if (cr == 0){
      float c20 = s_wq[s0*68 + 64];
      float c21 = s_wq[sB*68 + 64];
      #pragma unroll
      for (int reg = 0; reg < 4; reg++){
        s_log[s0*64 + wv*16 + q*4 + reg] = (p0[reg] + c20) * 0.125f;
        if (np == 2) s_log[sB*64 + wv*16 + q*4 + reg] = (p1[reg] + c21) * 0.125f;
      }
    }
  }
  __syncthreads();

  // softmax over slots (per d column); att stays in s_log
  if (t < 64){
    float lv[7];
    #pragma unroll
    for (int s = 0; s < 7; s++) lv[s] = s_log[s*64 + t];
    float mx = lv[0];
    #pragma unroll
    for (int s = 1; s < 7; s++) mx = fmaxf(mx, lv[s]);
    float sm = 0.f;
    #pragma unroll
    for (int s = 0; s < 7; s++){ lv[s] = expf(lv[s] - mx); sm += lv[s]; }
    float inv = 1.0f / sm;
    #pragma unroll
    for (int s = 0; s < 7; s++){
      float a = lv[s] * inv;
      s_log[s*64 + t] = a;
      if (mode == 1) attOut[(size_t)(b*7+s)*4096 + tile*64 + t] = a;
    }
  }
  __syncthreads();

  // frames partials: thread (s, r) covers columns r and r+32
  if (t < 224){
    int s = t >> 5, r = t & 31;
    float a1 = s_log[s*64 + r];
    float a2 = s_log[s*64 + r + 32];
    float gx1 = -0.5f + (float)r * (1.f/63.f);
    float gx2 = -0.5f + (float)(r + 32) * (1.f/63.f);
    float gyc = -0.5f + (float)tile * (1.f/63.f);
    float gy2c = gyc*gyc;
    float w0 = a1 + a2;
    float w1 = a1*gx1 + a2*gx2;
    float w2 = w0*gyc;
    float w3 = a1*(gx1*gx1 + gy2c) + a2*(gx2*gx2 + gy2c);
    #pragma unroll
    for (int m = 1; m < 32; m <<= 1){
      w0 += __shfl_xor(w0, m, 64);
      w1 += __shfl_xor(w1, m, 64);
      w2 += __shfl_xor(w2, m, 64);
      w3 += __shfl_xor(w3, m, 64);
    }
    if (r == 0){
      atomicAdd(&accF[(b*7+s)*4 + 0], w0);
      atomicAdd(&accF[(b*7+s)*4 + 1], w1);
      atomicAdd(&accF[(b*7+s)*4 + 2], w2);
      atomicAdd(&accF[(b*7+s)*4 + 3], w3);
    }
  }

  // ---- V loop: weighted reduce into s_upd (U1, U2) ----
  if (mode == 0){
    float xbv[16];
    #pragma unroll
    for (int i = 0; i < 8; i++){ xbv[i] = (float)vb0[i]; xbv[8+i] = (float)vb1[i]; }
    for (int sp = 0; sp < 4; sp++){
      int s0 = sp*2;
      int np = (sp == 3) ? 1 : 2;
      int sB = (np == 2) ? s0 + 1 : s0;
      float x0[16], x1[16];
      float s1a = 0.f, s2a = 0.f, s1b = 0.f, s2b = 0.f;
      {
        const float* Ac = s_absc + s0*192;
        #pragma unroll
        for (int h = 0; h < 2; h++){
          int fb = h ? (32 + q*8) : (q*8);
          const float4* A4 = reinterpret_cast<const float4*>(Ac + fb);
          const float4* B4 = reinterpret_cast<const float4*>(Ac + 64 + fb);
          const float4* C4 = reinterpret_cast<const float4*>(Ac + 128 + fb);
          #pragma unroll
          for (int pp = 0; pp < 2; pp++){
            float4 Av = A4[pp], Bv = B4[pp], Cv = C4[pp];
            int o = h*8 + pp*4;
            x0[o+0] = xbv[o+0] + gx*Av.x + gy*Bv.x + Cv.x;
            x0[o+1] = xbv[o+1] + gx*Av.y + gy*Bv.y + Cv.y;
            x0[o+2] = xbv[o+2] + gx*Av.z + gy*Bv.z + Cv.z;
            x0[o+3] = xbv[o+3] + gx*Av.w + gy*Bv.w + Cv.w;
          }
        }
        #pragma unroll
        for (int k = 0; k < 16; k++){ s1a += x0[k]; s2a = fmaf(x0[k], x0[k], s2a); }
      }
      {
        const float* Ac = s_absc + sB*192;
        #pragma unroll
        for (int h = 0; h < 2; h++){
          int fb = h ? (32 + q*8) : (q*8);
          const float4* A4 = reinterpret_cast<const float4*>(Ac + fb);
          const float4* B4 = reinterpret_cast<const float4*>(Ac + 64 + fb);
          const float4* C4 = reinterpret_cast<const float4*>(Ac + 128 + fb);
          #pragma unroll
          for (int pp = 0; pp < 2; pp++){
            float4 Av = A4[pp], Bv = B4[pp], Cv = C4[pp];
            int o = h*8 + pp*4;
            x1[o+0] = xbv[o+0] + gx*Av.x + gy*Bv.x + Cv.x;
            x1[o+1] = xbv[o+1] + gx*Av.y + gy*Bv.y + Cv.y;
            x1[o+2] = xbv[o+2] + gx*Av.z + gy*Bv.z + Cv.z;
            x1[o+3] = xbv[o+3] + gx*Av.w + gy*Bv.w + Cv.w;
          }
        }
        #pragma unroll
        for (int k = 0; k < 16; k++){ s1b += x1[k]; s2b = fmaf(x1[k], x1[k], s2b); }
      }
      s1a += __shfl_xor(s1a, 16, 64); s2a += __shfl_xor(s2a, 16, 64);
      s1b += __shfl_xor(s1b, 16, 64); s2b += __shfl_xor(s2b, 16, 64);
      s1a += __shfl_xor(s1a, 32, 64); s2a += __shfl_xor(s2a, 32, 64);
      s1b += __shfl_xor(s1b, 32, 64); s2b += __shfl_xor(s2b, 32, 64);
      float mA = s1a*(1.f/64.f);
      float rA = 1.0f/sqrtf(s2a*(1.f/64.f) - mA*mA + 1e-5f);
      float mB = s1b*(1.f/64.f);
      float rB = 1.0f/sqrtf(s2b*(1.f/64.f) - mB*mB + 1e-5f);

      bf16x8 a00, a01, a10, a11;
      #pragma unroll
      for (int k = 0; k < 8; k++){
        a00[k] = (__bf16)((x0[k]    - mA)*rA*gq[k]   + bq[k]);
        a01[k] = (__bf16)((x0[8+k]  - mA)*rA*gq[8+k] + bq[8+k]);
        a10[k] = (__bf16)((x1[k]    - mB)*rB*gq[k]   + bq[k]);
        a11[k] = (__bf16)((x1[8+k]  - mB)*rB*gq[8+k] + bq[8+k]);
      }

      f32x4 acc0[4], acc1[4];
      #pragma unroll
      for (int nt = 0; nt < 4; nt++){
        bf16x8 w0 = wl[nt*64 + l];
        bf16x8 w1f = wl[(4 + nt)*64 + l];
        acc0[nt] = __builtin_amdgcn_mfma_f32_16x16x32_bf16(a00, w0,  zero,     0, 0, 0);
        acc0[nt] = __builtin_amdgcn_mfma_f32_16x16x32_bf16(a01, w1f, acc0[nt], 0, 0, 0);
        acc1[nt] = __builtin_amdgcn_mfma_f32_16x16x32_bf16(a10, w0,  zero,     0, 0, 0);
        acc1[nt] = __builtin_amdgcn_mfma_f32_16x16x32_bf16(a11, w1f, acc1[nt], 0, 0, 0);
      }

      float wr0[4], wr1[4];
      #pragma unroll
      for (int reg = 0; reg < 4; reg++){
        wr0[reg] = s_log[s0*64 + wv*16 + q*4 + reg];
        wr1[reg] = s_log[sB*64 + wv*16 + q*4 + reg];
      }
      float pa0[4], pa1[4], pu0[4], pu1[4];
      #pragma unroll
      for (int nt = 0; nt < 4; nt++){
        pa0[nt] = 0.f; pa1[nt] = 0.f; pu0[nt] = 0.f; pu1[nt] = 0.f;
        #pragma unroll
        for (int reg = 0; reg < 4; reg++){
          float v0 = fmaxf(acc0[nt][reg] + b1v[nt], 0.f);
          float v1 = fmaxf(acc1[nt][reg] + b1v[nt], 0.f);
          pa0[nt] = fmaf(wr0[reg], v0, pa0[nt]); pu0[nt] += v0;
          pa1[nt] = fmaf(wr1[reg], v1, pa1[nt]); pu1[nt] += v1;
        }
      }
      #pragma unroll
      for (int nt = 0; nt < 4; nt++){
        pa0[nt] += __shfl_xor(pa0[nt], 16, 64); pa0[nt] += __shfl_xor(pa0[nt], 32, 64);
        pu0[nt] += __shfl_xor(pu0[nt], 16, 64); pu0[nt] += __shfl_xor(pu0[nt], 32, 64);
        pa1[nt] += __shfl_xor(pa1[nt], 16, 64); pa1[nt] += __shfl_xor(pa1[nt], 32, 64);
        pu1[nt] += __shfl_xor(pu1[nt], 16, 64); pu1[nt] += __shfl_xor(pu1[nt], 32, 64);
      }
      if (q == 0){
        #pragma unroll
        for (int nt = 0; nt < 4; nt++){
          atomicAdd(&s_upd[s0*128 + nt*16 + cr], pa0[nt]);
          atomicAdd(&s_upd[s0*128 + 64 + nt*16 + cr], pu0[nt]);
          if (np == 2){
            atomicAdd(&s_upd[sB*128 + nt*16 + cr], pa1[nt]);
            atomicAdd(&s_upd[sB*128 + 64 + nt*16 + cr], pu1[nt]);
          }
        }
      }
    }
    __syncthreads();
    for (int i = t; i < 896; i += 256)
      atomicAdd(&upd[b*896 + i], s_upd[i]);
  }
}

// ---------------- GRU cell + frames finalize + next-phase prep -------------
// float4 weight loads (wih/whh rows contiguous) + 4-way split accumulators.
__global__ void k_gru(float* __restrict__ upd, float* __restrict__ queries,
                      const float* __restrict__ wih, const float* __restrict__ whh,
                      const float* __restrict__ bih, const float* __restrict__ bhh,
                      const float* __restrict__ mlp2w, const float* __restrict__ mlp2b,
                      float* __restrict__ accF, float* __restrict__ ps,
                      const float* __restrict__ qg_, const float* __restrict__ qb_,
                      const float* __restrict__ dw, const float* __restrict__ db,
                      float* __restrict__ absc, float* __restrict__ w2qc){
  int row = blockIdx.x; int t = threadIdx.x;   // 112 x 192
  __shared__ __align__(16) float us[64], hs[64], xs[64];
  __shared__ float gis[192], ghs[192];
  __shared__ float s_ps3[3];
  if (t < 64){
    float isa0 = 1.0f/accF[row*4];
    us[t] = upd[row*128 + t]*isa0 + 1e-8f*upd[row*128 + 64 + t];
    hs[t] = queries[row*64 + t];
  }
  if (t == 64){
    float sa = accF[row*4+0];
    float ax = accF[row*4+1], ay = accF[row*4+2], ar2 = accF[row*4+3];
    float isa = 1.0f/sa;
    float Wx = ax*isa, Wy = ay*isa;
    float Wg = ar2*isa + 1e-8f*SR2;
    float s2 = Wg - (Wx*Wx + Wy*Wy)*(2.f - W0CONST);
    s_ps3[0] = Wx; s_ps3[1] = Wy; s_ps3[2] = sqrtf(fmaxf(s2, 0.f));
  }
  __syncthreads();
  if (t < 64){
    float a0 = W0CONST * mlp2b[t], a1 = 0.f, a2 = 0.f, a3 = 0.f;
    for (int i = 0; i < 64; i += 4){
      a0 = fmaf(us[i],     mlp2w[i*64 + t],       a0);
      a1 = fmaf(us[i + 1], mlp2w[(i + 1)*64 + t], a1);
      a2 = fmaf(us[i + 2], mlp2w[(i + 2)*64 + t], a2);
      a3 = fmaf(us[i + 3], mlp2w[(i + 3)*64 + t], a3);
    }
    xs[t] = (a0 + a1) + (a2 + a3);
  }
  __syncthreads();
  {
    const float4* wi4 = reinterpret_cast<const float4*>(wih + t*64);
    const float4* wh4 = reinterpret_cast<const float4*>(whh + t*64);
    float gi0 = bih[t], gi1 = 0.f, gi2 = 0.f, gi3 = 0.f;
    float gh0 = bhh[t], gh1 = 0.f, gh2 = 0.f, gh3 = 0.f;
    for (int e4 = 0; e4 < 16; e4++){
      float4 wi = wi4[e4], wh = wh4[e4];
      int e = e4*4;
      gi0 = fmaf(wi.x, xs[e],     gi0);
      gi1 = fmaf(wi.y, xs[e + 1], gi1);
      gi2 = fmaf(wi.z, xs[e + 2], gi2);
      gi3 = fmaf(wi.w, xs[e + 3], gi3);
      gh0 = fmaf(wh.x, hs[e],     gh0);
      gh1 = fmaf(wh.y, hs[e + 1], gh1);
      gh2 = fmaf(wh.z, hs[e + 2], gh2);
      gh3 = fmaf(wh.w, hs[e + 3], gh3);
    }
    gis[t] = (gi0 + gi1) + (gi2 + gi3);
    ghs[t] = (gh0 + gh1) + (gh2 + gh3);
  }
  __syncthreads();
  if (t < 64){
    float r = 1.0f/(1.0f + expf(-(gis[t]      + ghs[t])));
    float z = 1.0f/(1.0f + expf(-(gis[64+t]   + ghs[64+t])));
    float n = tanhf(gis[128+t] + r*ghs[128+t]);
    float newq = (1.0f - z)*n + z*hs[t];
    queries[row*64 + t] = newq;
    upd[row*128 + t] = 0.f;
    upd[row*128 + 64 + t] = 0.f;
    if (t < 4) accF[row*4 + t] = 0.f;
    if (t < 3) ps[row*3 + t] = s_ps3[t];
    pp_core(row, t, newq, s_ps3[0], s_ps3[1], s_ps3[2],
            qg_, qb_, dw, db, mlp2w, mlp2b, absc, w2qc);
  }
}

// ---------------- heads: alpha, slot_feat(+frames), copy queries -----------
__global__ void k_final(const float* __restrict__ queries, const float* __restrict__ accF,
                        const float* __restrict__ a1w, const float* __restrict__ a1b,
                        const float* __restrict__ a2w, const float* __restrict__ a2b,
                        const float* __restrict__ f1w, const float* __restrict__ f1b,
                        const float* __restrict__ f2w, const float* __restrict__ f2b,
                        float* __restrict__ out){
  int bs = blockIdx.x; int e = threadIdx.x;    // 112 x 64
  __shared__ float qs[64], hf[64], ha[32];
  float q = queries[bs*64 + e];
  qs[e] = q;
  out[bs*64 + e] = q;
  __syncthreads();
  float accf = f1b[e];
  for (int i = 0; i < 64; i++) accf = fmaf(qs[i], f1w[i*64 + e], accf);
  hf[e] = fmaxf(accf, 0.f);
  if (e < 32){
    float acca = a1b[e];
    for (int i = 0; i < 64; i++) acca = fmaf(qs[i], a1w[i*32 + e], acca);
    ha[e] = fmaxf(acca, 0.f);
  }
  __syncthreads();
  if (e < 3){
    float sf = f2b[e];
    for (int o = 0; o < 64; o++) sf = fmaf(hf[o], f2w[o*3 + e], sf);
    float sa = accF[bs*4+0], ax = accF[bs*4+1], ay = accF[bs*4+2], ar2 = accF[bs*4+3];
    float isa = 1.0f/sa;
    float Wx = ax*isa, Wy = ay*isa;
    float Wg = ar2*isa + 1e-8f*SR2;
    float s2 = Wg - (Wx*Wx + Wy*Wy)*(2.f - W0CONST);
    float nv = (e == 0) ? Wx : ((e == 1) ? Wy : sqrtf(fmaxf(s2, 0.f)));
    out[465920 + bs*3 + e] = sf + nv;
  }
  if (e == 32){
    float al = a2b[0];
    for (int o = 0; o < 32; o++) al = fmaf(ha[o], a2w[o], al);
    out[466256 + bs] = 1.0f/(1.0f + expf(-al));
  }
}

// ---------------------------------------------------------------------------
extern "C" void kernel_launch(void* const* d_in, const int* in_sizes, int n_in,
                              void* d_out, int out_size, void* d_ws, size_t ws_size,
                              hipStream_t stream){
  const float* data        = (const float*)d_in[0];
  const float* slot_noise  = (const float*)d_in[1];
  const float* pos_rand    = (const float*)d_in[2];
  const float* conv0_w     = (const float*)d_in[3];
  const float* conv0_b     = (const float*)d_in[4];
  const float* conv1_w     = (const float*)d_in[5];
  const float* conv1_b     = (const float*)d_in[6];
  const float* conv2_w     = (const float*)d_in[7];
  const float* conv2_b     = (const float*)d_in[8];
  const float* dataN_g     = (const float*)d_in[9];
  const float* dataN_b     = (const float*)d_in[10];
  const float* queryN_g    = (const float*)d_in[11];
  const float* queryN_b    = (const float*)d_in[12];
  const float* toK_w       = (const float*)d_in[13];
  const float* toK_b       = (const float*)d_in[14];
  const float* toV_w       = (const float*)d_in[15];
  const float* toV_b       = (const float*)d_in[16];
  const float* dense_w     = (const float*)d_in[17];
  const float* dense_b     = (const float*)d_in[18];
  const float* mlp1_w      = (const float*)d_in[19];
  const float* mlp1_b      = (const float*)d_in[20];
  const float* mlp2_w      = (const float*)d_in[21];
  const float* mlp2_b      = (const float*)d_in[22];
  const float* gru_wih     = (const float*)d_in[23];
  const float* gru_whh     = (const float*)d_in[24];
  const float* gru_bih     = (const float*)d_in[25];
  const float* gru_bhh     = (const float*)d_in[26];
  const float* alpha1_w    = (const float*)d_in[27];
  const float* alpha1_b    = (const float*)d_in[28];
  const float* alpha2_w    = (const float*)d_in[29];
  const float* alpha2_b    = (const float*)d_in[30];
  const float* final1_w    = (const float*)d_in[31];
  const float* final1_b    = (const float*)d_in[32];
  const float* final2_w    = (const float*)d_in[33];
  const float* final2_b    = (const float*)d_in[34];
  const float* slots_mu    = (const float*)d_in[35];
  const float* slots_lsig  = (const float*)d_in[36];

  float* ws   = (float*)d_ws;
  float* bufA = ws;                    // c0_bf (bf16) then encK (bf16)
  float* bufB = bufA + 4194304;        // encV (bf16)
  float* bufC = bufB + 4194304;        // c1_bf (bf16)
  float* queries = bufC + 4194304;     // 7,168
  float* ps   = queries + 7168;        // 512 ([112][3], 336 used)
  float* absc = ps + 512;              // 21,504 (A/B/cc per (b,s))
  float* accF = absc + 21504;          // 512 ([112][4]: sa, ax, ay, ar2)
  float* upd  = accF + 512;            // 14,336 ([112][128]: U1 | U2)
  float* w2qc = upd + 14336;           // 7,616 ([112][68])
  unsigned short* w1pack = (unsigned short*)(w2qc + 7616);   // 4096 bf16
  unsigned short* kpack  = w1pack + 4096;                    // 4096
  unsigned short* vpack  = kpack + 4096;                     // 4096
  unsigned short* wp1    = vpack + 4096;                     // 102,400
  unsigned short* wp2    = wp1 + 102400;                     // 102,400

  unsigned short* c0_bf = (unsigned short*)bufA;   // conv0 out, NHWC bf16
  unsigned short* c1_bf = (unsigned short*)bufC;   // conv1 out, NHWC bf16
  unsigned short* encK  = (unsigned short*)bufA;   // overwrites c0_bf (consumed)
  unsigned short* encV  = (unsigned short*)bufB;   // fresh buffer (enc eliminated)

  float* outq   = (float*)d_out;       // queries [7168]
  float* outatt = outq + 7168;         // att [458752]

  k_front<<<1984, 256, 0, stream>>>(mlp1_w, toK_w, toV_w, conv1_w, conv2_w,
                                    w1pack, kpack, vpack, wp1, wp2,
                                    slot_noise, pos_rand, slots_mu, slots_lsig,
                                    queryN_g, queryN_b, dense_w, dense_b, mlp2_w, mlp2_b,
                                    queries, ps, absc, w2qc, accF, upd,
                                    data, conv0_w, conv0_b, c0_bf);
  k_convm<<<512, 256, 0, stream>>>(c0_bf, wp1, conv1_b, nullptr, nullptr, c1_bf, 0,
                                   nullptr, nullptr, nullptr, nullptr, nullptr, nullptr);
  k_convm<<<512, 256, 0, stream>>>(c1_bf, wp2, conv2_b, dataN_g, dataN_b, nullptr, 1,
                                   kpack, toK_b, vpack, toV_b, encK, encV);

  for (int p = 0; p < 4; p++){
    k_attn<<<1024, 256, 0, stream>>>(encK, encV, w1pack, mlp1_b, absc,
                                     queryN_g, queryN_b, w2qc, outatt, accF, upd,
                                     (p < 3) ? 0 : 1);
    if (p < 3){
      k_gru<<<112, 192, 0, stream>>>(upd, queries, gru_wih, gru_whh, gru_bih, gru_bhh,
                                     mlp2_w, mlp2_b, accF, ps, queryN_g, queryN_b,
                                     dense_w, dense_b, absc, w2qc);
    }
  }
  k_final<<<112, 64, 0, stream>>>(queries, accF,
                                  alpha1_w, alpha1_b, alpha2_w, alpha2_b,
                                  final1_w, final1_b, final2_w, final2_b, outq);
}